// Round 1
// baseline (6005.127 us; speedup 1.0000x reference)
//
#include <hip/hip_runtime.h>

#define HH 128   // hidden size (both layers, and F_IN)

// ---------------- degree / norm ----------------
__global__ void fill_deg_k(float* __restrict__ deg, int n) {
  int i = blockIdx.x * blockDim.x + threadIdx.x;
  if (i < n) deg[i] = 1.0f;  // self-loop contributes 1
}

__global__ void accum_deg_k(const int* __restrict__ dst, float* __restrict__ deg, int e) {
  int i = blockIdx.x * blockDim.x + threadIdx.x;
  if (i < e) atomicAdd(&deg[dst[i]], 1.0f);
}

__global__ void dinv_k(float* __restrict__ deg, int n) {
  int i = blockIdx.x * blockDim.x + threadIdx.x;
  if (i < n) deg[i] = rsqrtf(deg[i]);  // deg >= 1 always (self-loops)
}

// ---------------- dense GEMM: out[n,128] = A[n,128] @ W[128,128] ----------------
// block = 256 threads = 8 groups of 32; each group: 8 rows x 128 cols (float4/lane)
__global__ __launch_bounds__(256) void gemm128_k(const float* __restrict__ A,
                                                 const float* __restrict__ W,
                                                 float* __restrict__ out, int n) {
  __shared__ float4 Wl[128][32];   // 64 KB
  const float4* W4 = (const float4*)W;
  for (int i = threadIdx.x; i < 128 * 32; i += 256) Wl[i >> 5][i & 31] = W4[i];
  __syncthreads();

  const int c4 = threadIdx.x & 31;      // float4 column index
  const int rg = threadIdx.x >> 5;      // row group 0..7
  const int rbase = blockIdx.x * 64 + rg * 8;
  if (rbase >= n) return;

  const float* Ar[8];
  #pragma unroll
  for (int r = 0; r < 8; ++r) {
    int rr = rbase + r; if (rr > n - 1) rr = n - 1;  // clamp; write is guarded
    Ar[r] = A + (size_t)rr * HH;
  }

  float4 acc[8];
  #pragma unroll
  for (int r = 0; r < 8; ++r) acc[r] = make_float4(0.f, 0.f, 0.f, 0.f);

  for (int k = 0; k < 128; ++k) {
    float4 w = Wl[k][c4];
    #pragma unroll
    for (int r = 0; r < 8; ++r) {
      float xv = Ar[r][k];
      acc[r].x += xv * w.x; acc[r].y += xv * w.y;
      acc[r].z += xv * w.z; acc[r].w += xv * w.w;
    }
  }

  #pragma unroll
  for (int r = 0; r < 8; ++r) {
    int rr = rbase + r;
    if (rr < n) ((float4*)(out + (size_t)rr * HH))[c4] = acc[r];
  }
}

// ---------------- h = bias + dinv^2 * xw  (self-loop term + bias init) ----------------
__global__ void init_h_k(const float* __restrict__ xw, const float* __restrict__ bias,
                         const float* __restrict__ dinv, float* __restrict__ h, int n) {
  int gid = blockIdx.x * blockDim.x + threadIdx.x;
  int node = gid >> 5, c4 = gid & 31;
  if (node >= n) return;
  float di = dinv[node];
  float nm = di * di;
  float4 v = ((const float4*)(xw + (size_t)node * HH))[c4];
  float4 b = ((const float4*)bias)[c4];
  float4 o = make_float4(b.x + nm * v.x, b.y + nm * v.y, b.z + nm * v.z, b.w + nm * v.w);
  ((float4*)(h + (size_t)node * HH))[c4] = o;
}

// ---------------- edge scatter: h[dst] += dinv[src]*dinv[dst] * xw[src] ----------------
__global__ void scatter_k(const float* __restrict__ xw, float* __restrict__ h,
                          const float* __restrict__ dinv, const int* __restrict__ src,
                          const int* __restrict__ dst, int e) {
  int gid = blockIdx.x * blockDim.x + threadIdx.x;
  int edge = gid >> 5, lane = gid & 31;
  if (edge >= e) return;
  int s = src[edge], d = dst[edge];
  float norm = dinv[s] * dinv[d];
  float4 v = ((const float4*)(xw + (size_t)s * HH))[lane];
  float* o = h + (size_t)d * HH + lane * 4;
  atomicAdd(o + 0, norm * v.x);
  atomicAdd(o + 1, norm * v.y);
  atomicAdd(o + 2, norm * v.z);
  atomicAdd(o + 3, norm * v.w);
}

// ---------------- relu in place ----------------
__global__ void relu_k(float4* __restrict__ h, int n4) {
  int i = blockIdx.x * blockDim.x + threadIdx.x;
  if (i < n4) {
    float4 v = h[i];
    v.x = fmaxf(v.x, 0.f); v.y = fmaxf(v.y, 0.f);
    v.z = fmaxf(v.z, 0.f); v.w = fmaxf(v.w, 0.f);
    h[i] = v;
  }
}

// ---------------- mean pool: z[dict[i]] += h[i]; cnt[dict[i]] += 1 ----------------
__global__ void pool_accum_k(const float* __restrict__ h, const int* __restrict__ dict,
                             float* __restrict__ z, float* __restrict__ cnt, int n) {
  int gid = blockIdx.x * blockDim.x + threadIdx.x;
  int node = gid >> 5, lane = gid & 31;
  if (node >= n) return;
  int d = dict[node];
  float4 v = ((const float4*)(h + (size_t)node * HH))[lane];
  float* o = z + (size_t)d * HH + lane * 4;
  atomicAdd(o + 0, v.x); atomicAdd(o + 1, v.y);
  atomicAdd(o + 2, v.z); atomicAdd(o + 3, v.w);
  if (lane == 0) atomicAdd(&cnt[d], 1.0f);
}

__global__ void pool_div_k(float* __restrict__ z, const float* __restrict__ cnt, int n) {
  int gid = blockIdx.x * blockDim.x + threadIdx.x;
  int node = gid >> 5, lane = gid & 31;
  if (node >= n) return;
  float inv = 1.0f / fmaxf(cnt[node], 1.0f);
  float4* p = (float4*)(z + (size_t)node * HH) + lane;
  float4 v = *p;
  v.x *= inv; v.y *= inv; v.z *= inv; v.w *= inv;
  *p = v;
}

// ---------------- decode: logits[e] = dot(z[a], z[b]) over 128 ----------------
__global__ void decode_k(const float* __restrict__ z, const int* __restrict__ pos,
                         const int* __restrict__ neg, float* __restrict__ out, int ep) {
  int gid = blockIdx.x * blockDim.x + threadIdx.x;
  int edge = gid >> 5, lane = gid & 31;
  if (edge >= 2 * ep) return;
  int a, b;
  if (edge < ep) { a = pos[edge];      b = pos[ep + edge]; }
  else           { a = neg[edge - ep]; b = neg[edge]; }   // neg[ep + (edge-ep)]
  const float4* za = (const float4*)(z + (size_t)a * HH);
  const float4* zb = (const float4*)(z + (size_t)b * HH);
  float4 va = za[lane], vb = zb[lane];
  float dot = va.x * vb.x + va.y * vb.y + va.z * vb.z + va.w * vb.w;
  #pragma unroll
  for (int off = 16; off > 0; off >>= 1) dot += __shfl_xor(dot, off);
  if (lane == 0) out[edge] = dot;
}

extern "C" void kernel_launch(void* const* d_in, const int* in_sizes, int n_in,
                              void* d_out, int out_size, void* d_ws, size_t ws_size,
                              hipStream_t stream) {
  const float* x  = (const float*)d_in[0];
  const float* W1 = (const float*)d_in[1];
  const float* b1 = (const float*)d_in[2];
  const float* W2 = (const float*)d_in[3];
  const float* b2 = (const float*)d_in[4];
  const int* ei   = (const int*)d_in[5];
  const int* dict = (const int*)d_in[6];
  const int* pe   = (const int*)d_in[7];
  const int* ne   = (const int*)d_in[8];

  const int n  = in_sizes[0] / HH;   // 100000
  const int e  = in_sizes[5] / 2;    // 1.6M
  const int ep = in_sizes[7] / 2;    // 200000
  const int* src = ei;
  const int* dst = ei + e;

  // workspace: bufA (n*128), bufB (n*128), dinv (n), cnt (n)  ~104 MB
  float* bufA = (float*)d_ws;
  float* bufB = bufA + (size_t)n * HH;
  float* dinv = bufB + (size_t)n * HH;
  float* cnt  = dinv + n;

  const int nb   = (n + 255) / 256;
  const int nb32 = (int)(((size_t)n * 32 + 255) / 256);
  const int eb32 = (int)(((size_t)e * 32 + 255) / 256);

  // degree -> dinv
  fill_deg_k<<<nb, 256, 0, stream>>>(dinv, n);
  accum_deg_k<<<(e + 255) / 256, 256, 0, stream>>>(dst, dinv, e);
  dinv_k<<<nb, 256, 0, stream>>>(dinv, n);

  // ---- conv1 ----
  gemm128_k<<<(n + 63) / 64, 256, 0, stream>>>(x, W1, bufA, n);            // xw -> A
  init_h_k<<<nb32, 256, 0, stream>>>(bufA, b1, dinv, bufB, n);             // h1 = b1 + selfloop
  scatter_k<<<eb32, 256, 0, stream>>>(bufA, bufB, dinv, src, dst, e);      // h1 += msgs
  relu_k<<<nb32, 256, 0, stream>>>((float4*)bufB, n * 32);                 // relu(h1)

  // ---- conv2 ----
  gemm128_k<<<(n + 63) / 64, 256, 0, stream>>>(bufB, W2, bufA, n);         // h1w -> A
  init_h_k<<<nb32, 256, 0, stream>>>(bufA, b2, dinv, bufB, n);             // h2 = b2 + selfloop
  scatter_k<<<eb32, 256, 0, stream>>>(bufA, bufB, dinv, src, dst, e);      // h2 += msgs
  relu_k<<<nb32, 256, 0, stream>>>((float4*)bufB, n * 32);                 // relu(h2)

  // ---- mean pool -> z in bufA ----
  hipMemsetAsync(bufA, 0, (size_t)n * HH * sizeof(float), stream);
  hipMemsetAsync(cnt, 0, (size_t)n * sizeof(float), stream);
  pool_accum_k<<<nb32, 256, 0, stream>>>(bufB, dict, bufA, cnt, n);
  pool_div_k<<<nb32, 256, 0, stream>>>(bufA, cnt, n);

  // ---- decode ----
  decode_k<<<(int)(((size_t)2 * ep * 32 + 255) / 256), 256, 0, stream>>>(
      bufA, pe, ne, (float*)d_out, ep);
}

// Round 2
// 832.749 us; speedup vs baseline: 7.2112x; 7.2112x over previous
//
#include <hip/hip_runtime.h>

#define HH 128   // hidden size (both layers, and F_IN)
#define SCAN_T 256
#define SCAN_C 2048  // elements per scan block (256 threads x 8)

// ================= CSR build: histogram / scan / bucket-fill =================

__global__ void hist_k(const int* __restrict__ key, int* __restrict__ hist, int e) {
  int i = blockIdx.x * blockDim.x + threadIdx.x;
  if (i < e) atomicAdd(&hist[key[i]], 1);
}

__global__ __launch_bounds__(SCAN_T) void scan_pass1_k(const int* __restrict__ hist,
                                                       int* __restrict__ bsum, int n) {
  __shared__ int lds[SCAN_T];
  int base = blockIdx.x * SCAN_C + threadIdx.x * 8;
  int s = 0;
  #pragma unroll
  for (int k = 0; k < 8; ++k) { int i = base + k; if (i < n) s += hist[i]; }
  lds[threadIdx.x] = s;
  __syncthreads();
  for (int off = 128; off > 0; off >>= 1) {
    if (threadIdx.x < off) lds[threadIdx.x] += lds[threadIdx.x + off];
    __syncthreads();
  }
  if (threadIdx.x == 0) bsum[blockIdx.x] = lds[0];
}

// single block; nb <= SCAN_T; also writes rowptr[n] = total
__global__ __launch_bounds__(SCAN_T) void scan_pass2_k(int* __restrict__ bsum, int nb,
                                                       int* __restrict__ rowptr_n, int total) {
  __shared__ int lds[SCAN_T];
  int v = (threadIdx.x < nb) ? bsum[threadIdx.x] : 0;
  lds[threadIdx.x] = v;
  __syncthreads();
  for (int off = 1; off < SCAN_T; off <<= 1) {
    int t = (threadIdx.x >= off) ? lds[threadIdx.x - off] : 0;
    __syncthreads();
    lds[threadIdx.x] += t;
    __syncthreads();
  }
  if (threadIdx.x < nb) bsum[threadIdx.x] = (threadIdx.x == 0) ? 0 : lds[threadIdx.x - 1];
  if (threadIdx.x == 0) *rowptr_n = total;
}

// tmp: hist in -> cursor out; also rowptr (exclusive scan) and dinv = rsqrt(cnt+1)
__global__ __launch_bounds__(SCAN_T) void scan_pass3_k(int* __restrict__ tmp,
                                                       const int* __restrict__ bsum,
                                                       int* __restrict__ rowptr,
                                                       float* __restrict__ dinv, int n) {
  __shared__ int lds[SCAN_T];
  int base = blockIdx.x * SCAN_C + threadIdx.x * 8;
  int v[8]; int s = 0;
  #pragma unroll
  for (int k = 0; k < 8; ++k) { int i = base + k; v[k] = (i < n) ? tmp[i] : 0; s += v[k]; }
  lds[threadIdx.x] = s;
  __syncthreads();
  for (int off = 1; off < SCAN_T; off <<= 1) {
    int t = (threadIdx.x >= off) ? lds[threadIdx.x - off] : 0;
    __syncthreads();
    lds[threadIdx.x] += t;
    __syncthreads();
  }
  int run = bsum[blockIdx.x] + ((threadIdx.x == 0) ? 0 : lds[threadIdx.x - 1]);
  #pragma unroll
  for (int k = 0; k < 8; ++k) {
    int i = base + k;
    if (i < n) {
      rowptr[i] = run;
      tmp[i] = run;                        // cursor for bucket fill
      if (dinv) dinv[i] = rsqrtf((float)v[k] + 1.0f);
      run += v[k];
    }
  }
}

__global__ void build_edges_k(const int* __restrict__ src, const int* __restrict__ dst,
                              int* __restrict__ cursor, int* __restrict__ esrc, int e) {
  int i = blockIdx.x * blockDim.x + threadIdx.x;
  if (i < e) {
    int pos = atomicAdd(&cursor[dst[i]], 1);
    esrc[pos] = src[i];
  }
}

__global__ void build_nodes_k(const int* __restrict__ dict, int* __restrict__ cursor,
                              int* __restrict__ nodelist, int n) {
  int i = blockIdx.x * blockDim.x + threadIdx.x;
  if (i < n) {
    int pos = atomicAdd(&cursor[dict[i]], 1);
    nodelist[pos] = i;
  }
}

// ================= dense GEMM: out[n,128] = A[n,128] @ W[128,128] =================
__global__ __launch_bounds__(256) void gemm128_k(const float* __restrict__ A,
                                                 const float* __restrict__ W,
                                                 float* __restrict__ out, int n) {
  __shared__ float4 Wl[128][32];   // 64 KB
  const float4* W4 = (const float4*)W;
  for (int i = threadIdx.x; i < 128 * 32; i += 256) Wl[i >> 5][i & 31] = W4[i];
  __syncthreads();

  const int c4 = threadIdx.x & 31;
  const int rg = threadIdx.x >> 5;
  const int rbase = blockIdx.x * 64 + rg * 8;
  if (rbase >= n) return;

  const float* Ar[8];
  #pragma unroll
  for (int r = 0; r < 8; ++r) {
    int rr = rbase + r; if (rr > n - 1) rr = n - 1;
    Ar[r] = A + (size_t)rr * HH;
  }

  float4 acc[8];
  #pragma unroll
  for (int r = 0; r < 8; ++r) acc[r] = make_float4(0.f, 0.f, 0.f, 0.f);

  for (int k = 0; k < 128; ++k) {
    float4 w = Wl[k][c4];
    #pragma unroll
    for (int r = 0; r < 8; ++r) {
      float xv = Ar[r][k];
      acc[r].x += xv * w.x; acc[r].y += xv * w.y;
      acc[r].z += xv * w.z; acc[r].w += xv * w.w;
    }
  }

  #pragma unroll
  for (int r = 0; r < 8; ++r) {
    int rr = rbase + r;
    if (rr < n) ((float4*)(out + (size_t)rr * HH))[c4] = acc[r];
  }
}

// ======== gather conv: h[d] = relu(bias + dinv[d]^2*xw[d] + sum_in dinv[s]dinv[d]*xw[s]) ========
__global__ __launch_bounds__(256) void gather_k(const float* __restrict__ xw,
                                                const int* __restrict__ rowptr,
                                                const int* __restrict__ esrc,
                                                const float* __restrict__ dinv,
                                                const float* __restrict__ bias,
                                                float* __restrict__ h, int n) {
  int wid = (int)((blockIdx.x * (size_t)blockDim.x + threadIdx.x) >> 6);
  int lane = threadIdx.x & 63;
  if (wid >= n) return;
  int beg = rowptr[wid], end = rowptr[wid + 1];
  float di = dinv[wid];
  const float2* xw2 = (const float2*)xw;
  float2 acc = xw2[((size_t)wid << 6) + lane];
  float sn = di * di;
  float2 bb = ((const float2*)bias)[lane];
  acc.x = bb.x + sn * acc.x;
  acc.y = bb.y + sn * acc.y;

  for (int j0 = beg; j0 < end; j0 += 64) {
    int myj = j0 + lane;
    int sv = 0; float nv = 0.f;
    if (myj < end) { sv = esrc[myj]; nv = dinv[sv] * di; }
    int cnt = end - j0; if (cnt > 64) cnt = 64;
    for (int k = 0; k < cnt; ++k) {
      int s = __builtin_amdgcn_readlane(sv, k);
      float nm = __int_as_float(__builtin_amdgcn_readlane(__float_as_int(nv), k));
      float2 v = xw2[((size_t)s << 6) + lane];
      acc.x += nm * v.x;
      acc.y += nm * v.y;
    }
  }
  acc.x = fmaxf(acc.x, 0.f);
  acc.y = fmaxf(acc.y, 0.f);
  ((float2*)h)[((size_t)wid << 6) + lane] = acc;
}

// ======== gather pool: z[d] = mean over nodes i with dict[i]==d of h[i] (0 if empty) ========
__global__ __launch_bounds__(256) void gatherpool_k(const float* __restrict__ h,
                                                    const int* __restrict__ rowptr,
                                                    const int* __restrict__ nodelist,
                                                    float* __restrict__ z, int n) {
  int wid = (int)((blockIdx.x * (size_t)blockDim.x + threadIdx.x) >> 6);
  int lane = threadIdx.x & 63;
  if (wid >= n) return;
  int beg = rowptr[wid], end = rowptr[wid + 1];
  float inv = 1.0f / fmaxf((float)(end - beg), 1.0f);
  const float2* h2 = (const float2*)h;
  float2 acc = make_float2(0.f, 0.f);
  for (int j0 = beg; j0 < end; j0 += 64) {
    int myj = j0 + lane;
    int sv = (myj < end) ? nodelist[myj] : 0;
    int cnt = end - j0; if (cnt > 64) cnt = 64;
    for (int k = 0; k < cnt; ++k) {
      int s = __builtin_amdgcn_readlane(sv, k);
      float2 v = h2[((size_t)s << 6) + lane];
      acc.x += v.x; acc.y += v.y;
    }
  }
  acc.x *= inv; acc.y *= inv;
  ((float2*)z)[((size_t)wid << 6) + lane] = acc;
}

// ================= decode: logits[e] = dot(z[a], z[b]) over 128 =================
__global__ void decode_k(const float* __restrict__ z, const int* __restrict__ pos,
                         const int* __restrict__ neg, float* __restrict__ out, int ep) {
  int gid = blockIdx.x * blockDim.x + threadIdx.x;
  int edge = gid >> 5, lane = gid & 31;
  if (edge >= 2 * ep) return;
  int a, b;
  if (edge < ep) { a = pos[edge];      b = pos[ep + edge]; }
  else           { a = neg[edge - ep]; b = neg[edge]; }
  const float4* za = (const float4*)(z + (size_t)a * HH);
  const float4* zb = (const float4*)(z + (size_t)b * HH);
  float4 va = za[lane], vb = zb[lane];
  float dot = va.x * vb.x + va.y * vb.y + va.z * vb.z + va.w * vb.w;
  #pragma unroll
  for (int off = 16; off > 0; off >>= 1) dot += __shfl_xor(dot, off);
  if (lane == 0) out[edge] = dot;
}

// ================= fallback path (small ws): R1 atomic version =================
__global__ void fill_deg_k(float* __restrict__ deg, int n) {
  int i = blockIdx.x * blockDim.x + threadIdx.x;
  if (i < n) deg[i] = 1.0f;
}
__global__ void accum_deg_k(const int* __restrict__ dst, float* __restrict__ deg, int e) {
  int i = blockIdx.x * blockDim.x + threadIdx.x;
  if (i < e) atomicAdd(&deg[dst[i]], 1.0f);
}
__global__ void dinv_k(float* __restrict__ deg, int n) {
  int i = blockIdx.x * blockDim.x + threadIdx.x;
  if (i < n) deg[i] = rsqrtf(deg[i]);
}
__global__ void init_h_k(const float* __restrict__ xw, const float* __restrict__ bias,
                         const float* __restrict__ dinv, float* __restrict__ h, int n) {
  int gid = blockIdx.x * blockDim.x + threadIdx.x;
  int node = gid >> 5, c4 = gid & 31;
  if (node >= n) return;
  float di = dinv[node];
  float nm = di * di;
  float4 v = ((const float4*)(xw + (size_t)node * HH))[c4];
  float4 b = ((const float4*)bias)[c4];
  ((float4*)(h + (size_t)node * HH))[c4] =
      make_float4(b.x + nm * v.x, b.y + nm * v.y, b.z + nm * v.z, b.w + nm * v.w);
}
__global__ void scatter_k(const float* __restrict__ xw, float* __restrict__ h,
                          const float* __restrict__ dinv, const int* __restrict__ src,
                          const int* __restrict__ dst, int e) {
  int gid = blockIdx.x * blockDim.x + threadIdx.x;
  int edge = gid >> 5, lane = gid & 31;
  if (edge >= e) return;
  int s = src[edge], d = dst[edge];
  float norm = dinv[s] * dinv[d];
  float4 v = ((const float4*)(xw + (size_t)s * HH))[lane];
  float* o = h + (size_t)d * HH + lane * 4;
  atomicAdd(o + 0, norm * v.x);
  atomicAdd(o + 1, norm * v.y);
  atomicAdd(o + 2, norm * v.z);
  atomicAdd(o + 3, norm * v.w);
}
__global__ void relu_k(float4* __restrict__ h, int n4) {
  int i = blockIdx.x * blockDim.x + threadIdx.x;
  if (i < n4) {
    float4 v = h[i];
    v.x = fmaxf(v.x, 0.f); v.y = fmaxf(v.y, 0.f);
    v.z = fmaxf(v.z, 0.f); v.w = fmaxf(v.w, 0.f);
    h[i] = v;
  }
}
__global__ void pool_accum_k(const float* __restrict__ h, const int* __restrict__ dict,
                             float* __restrict__ z, float* __restrict__ cnt, int n) {
  int gid = blockIdx.x * blockDim.x + threadIdx.x;
  int node = gid >> 5, lane = gid & 31;
  if (node >= n) return;
  int d = dict[node];
  float4 v = ((const float4*)(h + (size_t)node * HH))[lane];
  float* o = z + (size_t)d * HH + lane * 4;
  atomicAdd(o + 0, v.x); atomicAdd(o + 1, v.y);
  atomicAdd(o + 2, v.z); atomicAdd(o + 3, v.w);
  if (lane == 0) atomicAdd(&cnt[d], 1.0f);
}
__global__ void pool_div_k(float* __restrict__ z, const float* __restrict__ cnt, int n) {
  int gid = blockIdx.x * blockDim.x + threadIdx.x;
  int node = gid >> 5, lane = gid & 31;
  if (node >= n) return;
  float inv = 1.0f / fmaxf(cnt[node], 1.0f);
  float4* p = (float4*)(z + (size_t)node * HH) + lane;
  float4 v = *p;
  v.x *= inv; v.y *= inv; v.z *= inv; v.w *= inv;
  *p = v;
}

// ================= host launch =================
extern "C" void kernel_launch(void* const* d_in, const int* in_sizes, int n_in,
                              void* d_out, int out_size, void* d_ws, size_t ws_size,
                              hipStream_t stream) {
  const float* x  = (const float*)d_in[0];
  const float* W1 = (const float*)d_in[1];
  const float* b1 = (const float*)d_in[2];
  const float* W2 = (const float*)d_in[3];
  const float* b2 = (const float*)d_in[4];
  const int* ei   = (const int*)d_in[5];
  const int* dict = (const int*)d_in[6];
  const int* pe   = (const int*)d_in[7];
  const int* ne   = (const int*)d_in[8];

  const int n  = in_sizes[0] / HH;   // 100000
  const int e  = in_sizes[5] / 2;    // 1.6M
  const int ep = in_sizes[7] / 2;    // 200000
  const int* src = ei;
  const int* dst = ei + e;

  const size_t nf = (size_t)n * HH;

  // CSR layout: bufA, bufB, dinv[n], rowptr[n+1], tmp[n], esrc[e], bsum[256]
  float* bufA   = (float*)d_ws;
  float* bufB   = bufA + nf;
  float* dinv   = bufB + nf;
  int*   rowptr = (int*)(dinv + n);
  int*   tmp    = rowptr + (n + 1);
  int*   esrc   = tmp + n;
  int*   bsum   = esrc + e;
  size_t need = (2 * nf + n) * sizeof(float) + (size_t)(3 * n + 1 + e + 256) * sizeof(int);

  const int nb    = (n + 255) / 256;
  const int eb    = (e + 255) / 256;
  const int nb32  = (int)(((size_t)n * 32 + 255) / 256);
  const int nb64  = (int)(((size_t)n * 64 + 255) / 256);
  const int NBS   = (n + SCAN_C - 1) / SCAN_C;   // scan blocks (49)

  if (ws_size >= need) {
    // ---- build edge CSR (by dst) + dinv ----
    hipMemsetAsync(tmp, 0, (size_t)n * sizeof(int), stream);
    hist_k<<<eb, 256, 0, stream>>>(dst, tmp, e);
    scan_pass1_k<<<NBS, SCAN_T, 0, stream>>>(tmp, bsum, n);
    scan_pass2_k<<<1, SCAN_T, 0, stream>>>(bsum, NBS, rowptr + n, e);
    scan_pass3_k<<<NBS, SCAN_T, 0, stream>>>(tmp, bsum, rowptr, dinv, n);
    build_edges_k<<<eb, 256, 0, stream>>>(src, dst, tmp, esrc, e);

    // ---- conv1 ----
    gemm128_k<<<(n + 63) / 64, 256, 0, stream>>>(x, W1, bufA, n);
    gather_k<<<nb64, 256, 0, stream>>>(bufA, rowptr, esrc, dinv, b1, bufB, n);
    // ---- conv2 ----
    gemm128_k<<<(n + 63) / 64, 256, 0, stream>>>(bufB, W2, bufA, n);
    gather_k<<<nb64, 256, 0, stream>>>(bufA, rowptr, esrc, dinv, b2, bufB, n);
    // bufB = h2 (relu'd)

    // ---- build node CSR (by dict) ----
    hipMemsetAsync(tmp, 0, (size_t)n * sizeof(int), stream);
    hist_k<<<nb, 256, 0, stream>>>(dict, tmp, n);
    scan_pass1_k<<<NBS, SCAN_T, 0, stream>>>(tmp, bsum, n);
    scan_pass2_k<<<1, SCAN_T, 0, stream>>>(bsum, NBS, rowptr + n, n);
    scan_pass3_k<<<NBS, SCAN_T, 0, stream>>>(tmp, bsum, rowptr, dinv, n);  // dinv = scratch here
    build_nodes_k<<<nb, 256, 0, stream>>>(dict, tmp, esrc, n);             // esrc = nodelist

    // ---- pool (gather) -> z in bufA ----
    gatherpool_k<<<nb64, 256, 0, stream>>>(bufB, rowptr, esrc, bufA, n);
  } else {
    // ---- fallback: R1 atomic path (bufA, bufB, dinv, cnt) ----
    float* cnt = dinv + n;
    fill_deg_k<<<nb, 256, 0, stream>>>(dinv, n);
    accum_deg_k<<<eb, 256, 0, stream>>>(dst, dinv, e);
    dinv_k<<<nb, 256, 0, stream>>>(dinv, n);

    gemm128_k<<<(n + 63) / 64, 256, 0, stream>>>(x, W1, bufA, n);
    init_h_k<<<nb32, 256, 0, stream>>>(bufA, b1, dinv, bufB, n);
    scatter_k<<<(int)(((size_t)e * 32 + 255) / 256), 256, 0, stream>>>(bufA, bufB, dinv, src, dst, e);
    relu_k<<<nb32, 256, 0, stream>>>((float4*)bufB, n * 32);

    gemm128_k<<<(n + 63) / 64, 256, 0, stream>>>(bufB, W2, bufA, n);
    init_h_k<<<nb32, 256, 0, stream>>>(bufA, b2, dinv, bufB, n);
    scatter_k<<<(int)(((size_t)e * 32 + 255) / 256), 256, 0, stream>>>(bufA, bufB, dinv, src, dst, e);
    relu_k<<<nb32, 256, 0, stream>>>((float4*)bufB, n * 32);

    hipMemsetAsync(bufA, 0, nf * sizeof(float), stream);
    hipMemsetAsync(cnt, 0, (size_t)n * sizeof(float), stream);
    pool_accum_k<<<nb32, 256, 0, stream>>>(bufB, dict, bufA, cnt, n);
    pool_div_k<<<nb32, 256, 0, stream>>>(bufA, cnt, n);
  }

  // ---- decode ----
  decode_k<<<(int)(((size_t)2 * ep * 32 + 255) / 256), 256, 0, stream>>>(
      bufA, pe, ne, (float*)d_out, ep);
}

// Round 3
// 766.962 us; speedup vs baseline: 7.8298x; 1.0858x over previous
//
#include <hip/hip_runtime.h>

#define HH 128   // hidden size (both layers, and F_IN)
#define SCAN_T 256
#define SCAN_C 2048  // elements per scan block (256 threads x 8)

// ================= CSR build: histogram / scan / bucket-fill =================

__global__ void hist_k(const int* __restrict__ key, int* __restrict__ hist, int e) {
  int i = blockIdx.x * blockDim.x + threadIdx.x;
  if (i < e) atomicAdd(&hist[key[i]], 1);
}

__global__ __launch_bounds__(SCAN_T) void scan_pass1_k(const int* __restrict__ hist,
                                                       int* __restrict__ bsum, int n) {
  __shared__ int lds[SCAN_T];
  int base = blockIdx.x * SCAN_C + threadIdx.x * 8;
  int s = 0;
  #pragma unroll
  for (int k = 0; k < 8; ++k) { int i = base + k; if (i < n) s += hist[i]; }
  lds[threadIdx.x] = s;
  __syncthreads();
  for (int off = 128; off > 0; off >>= 1) {
    if (threadIdx.x < off) lds[threadIdx.x] += lds[threadIdx.x + off];
    __syncthreads();
  }
  if (threadIdx.x == 0) bsum[blockIdx.x] = lds[0];
}

// single block; nb <= SCAN_T; also writes rowptr[n] = total
__global__ __launch_bounds__(SCAN_T) void scan_pass2_k(int* __restrict__ bsum, int nb,
                                                       int* __restrict__ rowptr_n, int total) {
  __shared__ int lds[SCAN_T];
  int v = (threadIdx.x < nb) ? bsum[threadIdx.x] : 0;
  lds[threadIdx.x] = v;
  __syncthreads();
  for (int off = 1; off < SCAN_T; off <<= 1) {
    int t = (threadIdx.x >= off) ? lds[threadIdx.x - off] : 0;
    __syncthreads();
    lds[threadIdx.x] += t;
    __syncthreads();
  }
  if (threadIdx.x < nb) bsum[threadIdx.x] = (threadIdx.x == 0) ? 0 : lds[threadIdx.x - 1];
  if (threadIdx.x == 0) *rowptr_n = total;
}

// tmp: hist in -> cursor out; also rowptr (exclusive scan) and dinv = rsqrt(cnt+1)
__global__ __launch_bounds__(SCAN_T) void scan_pass3_k(int* __restrict__ tmp,
                                                       const int* __restrict__ bsum,
                                                       int* __restrict__ rowptr,
                                                       float* __restrict__ dinv, int n) {
  __shared__ int lds[SCAN_T];
  int base = blockIdx.x * SCAN_C + threadIdx.x * 8;
  int v[8]; int s = 0;
  #pragma unroll
  for (int k = 0; k < 8; ++k) { int i = base + k; v[k] = (i < n) ? tmp[i] : 0; s += v[k]; }
  lds[threadIdx.x] = s;
  __syncthreads();
  for (int off = 1; off < SCAN_T; off <<= 1) {
    int t = (threadIdx.x >= off) ? lds[threadIdx.x - off] : 0;
    __syncthreads();
    lds[threadIdx.x] += t;
    __syncthreads();
  }
  int run = bsum[blockIdx.x] + ((threadIdx.x == 0) ? 0 : lds[threadIdx.x - 1]);
  #pragma unroll
  for (int k = 0; k < 8; ++k) {
    int i = base + k;
    if (i < n) {
      rowptr[i] = run;
      tmp[i] = run;                        // cursor for bucket fill
      if (dinv) dinv[i] = rsqrtf((float)v[k] + 1.0f);
      run += v[k];
    }
  }
}

__global__ void build_edges_k(const int* __restrict__ src, const int* __restrict__ dst,
                              int* __restrict__ cursor, int* __restrict__ esrc, int e) {
  int i = blockIdx.x * blockDim.x + threadIdx.x;
  if (i < e) {
    int pos = atomicAdd(&cursor[dst[i]], 1);
    esrc[pos] = src[i];
  }
}

__global__ void build_nodes_k(const int* __restrict__ dict, int* __restrict__ cursor,
                              int* __restrict__ nodelist, int n) {
  int i = blockIdx.x * blockDim.x + threadIdx.x;
  if (i < n) {
    int pos = atomicAdd(&cursor[dict[i]], 1);
    nodelist[pos] = i;
  }
}

// ========== GEMM v2: out[i,:] = scale(i) * (A[i,:] @ W);  1 thread = 1 row ==========
// W loads are uniform -> compiler scalarizes to s_load; inner body is pure v_fmac.
__global__ __launch_bounds__(256) void gemm128_v2(const float* __restrict__ A,
                                                  const float* __restrict__ W,
                                                  const float* __restrict__ dscale,
                                                  float* __restrict__ out, int n) {
  int row = blockIdx.x * 256 + threadIdx.x;
  bool live = (row < n);
  if (!live) row = n - 1;
  const float4* A4 = (const float4*)(A + (size_t)row * HH);

  float4 acc[32];
  #pragma unroll
  for (int c = 0; c < 32; ++c) acc[c] = make_float4(0.f, 0.f, 0.f, 0.f);

  for (int k0 = 0; k0 < HH; k0 += 4) {
    float4 a = A4[k0 >> 2];
    float av[4] = {a.x, a.y, a.z, a.w};
    #pragma unroll
    for (int kk = 0; kk < 4; ++kk) {
      const float4* Wr = (const float4*)(W + (size_t)(k0 + kk) * HH);
      #pragma unroll
      for (int c = 0; c < 32; ++c) {
        float4 w = Wr[c];
        acc[c].x += av[kk] * w.x; acc[c].y += av[kk] * w.y;
        acc[c].z += av[kk] * w.z; acc[c].w += av[kk] * w.w;
      }
    }
  }

  if (!live) return;
  float s = dscale ? dscale[row] : 1.0f;
  float4* o = (float4*)(out + (size_t)row * HH);
  #pragma unroll
  for (int c = 0; c < 32; ++c) {
    acc[c].x *= s; acc[c].y *= s; acc[c].z *= s; acc[c].w *= s;
    o[c] = acc[c];
  }
}

// ==== gather conv (pre-scaled xw'): h[d] = relu(bias + dinv[d]*(xw'[d] + sum xw'[s])) ====
__global__ __launch_bounds__(256) void gather_k(const float* __restrict__ xwp,
                                                const int* __restrict__ rowptr,
                                                const int* __restrict__ esrc,
                                                const float* __restrict__ dinv,
                                                const float* __restrict__ bias,
                                                float* __restrict__ h, int n) {
  int wid = (int)((blockIdx.x * (size_t)blockDim.x + threadIdx.x) >> 6);
  int lane = threadIdx.x & 63;
  if (wid >= n) return;
  int beg = rowptr[wid], end = rowptr[wid + 1];
  const float2* xw2 = (const float2*)xwp;
  float2 acc = xw2[((size_t)wid << 6) + lane];   // self term (pre-scaled by dinv[wid])

  for (int j0 = beg; j0 < end; j0 += 64) {
    int myj = j0 + lane;
    int sv = (myj < end) ? esrc[myj] : 0;
    int cnt = end - j0; if (cnt > 64) cnt = 64;
    for (int k = 0; k < cnt; ++k) {
      int s = __builtin_amdgcn_readlane(sv, k);
      float2 v = xw2[((size_t)s << 6) + lane];
      acc.x += v.x;
      acc.y += v.y;
    }
  }
  float di = dinv[wid];
  float2 bb = ((const float2*)bias)[lane];
  acc.x = fmaxf(bb.x + di * acc.x, 0.f);
  acc.y = fmaxf(bb.y + di * acc.y, 0.f);
  ((float2*)h)[((size_t)wid << 6) + lane] = acc;
}

// ======== gather pool: z[d] = mean over nodes i with dict[i]==d of h[i] (0 if empty) ========
__global__ __launch_bounds__(256) void gatherpool_k(const float* __restrict__ h,
                                                    const int* __restrict__ rowptr,
                                                    const int* __restrict__ nodelist,
                                                    float* __restrict__ z, int n) {
  int wid = (int)((blockIdx.x * (size_t)blockDim.x + threadIdx.x) >> 6);
  int lane = threadIdx.x & 63;
  if (wid >= n) return;
  int beg = rowptr[wid], end = rowptr[wid + 1];
  float inv = 1.0f / fmaxf((float)(end - beg), 1.0f);
  const float2* h2 = (const float2*)h;
  float2 acc = make_float2(0.f, 0.f);
  for (int j0 = beg; j0 < end; j0 += 64) {
    int myj = j0 + lane;
    int sv = (myj < end) ? nodelist[myj] : 0;
    int cnt = end - j0; if (cnt > 64) cnt = 64;
    for (int k = 0; k < cnt; ++k) {
      int s = __builtin_amdgcn_readlane(sv, k);
      float2 v = h2[((size_t)s << 6) + lane];
      acc.x += v.x; acc.y += v.y;
    }
  }
  acc.x *= inv; acc.y *= inv;
  ((float2*)z)[((size_t)wid << 6) + lane] = acc;
}

// ================= decode: logits[e] = dot(z[a], z[b]) over 128 =================
__global__ void decode_k(const float* __restrict__ z, const int* __restrict__ pos,
                         const int* __restrict__ neg, float* __restrict__ out, int ep) {
  int gid = blockIdx.x * blockDim.x + threadIdx.x;
  int edge = gid >> 5, lane = gid & 31;
  if (edge >= 2 * ep) return;
  int a, b;
  if (edge < ep) { a = pos[edge];      b = pos[ep + edge]; }
  else           { a = neg[edge - ep]; b = neg[edge]; }
  const float4* za = (const float4*)(z + (size_t)a * HH);
  const float4* zb = (const float4*)(z + (size_t)b * HH);
  float4 va = za[lane], vb = zb[lane];
  float dot = va.x * vb.x + va.y * vb.y + va.z * vb.z + va.w * vb.w;
  #pragma unroll
  for (int off = 16; off > 0; off >>= 1) dot += __shfl_xor(dot, off);
  if (lane == 0) out[edge] = dot;
}

// ================= fallback path (small ws): atomic version =================
__global__ void fill_deg_k(float* __restrict__ deg, int n) {
  int i = blockIdx.x * blockDim.x + threadIdx.x;
  if (i < n) deg[i] = 1.0f;
}
__global__ void accum_deg_k(const int* __restrict__ dst, float* __restrict__ deg, int e) {
  int i = blockIdx.x * blockDim.x + threadIdx.x;
  if (i < e) atomicAdd(&deg[dst[i]], 1.0f);
}
__global__ void dinv_k(float* __restrict__ deg, int n) {
  int i = blockIdx.x * blockDim.x + threadIdx.x;
  if (i < n) deg[i] = rsqrtf(deg[i]);
}
__global__ void init_h_k(const float* __restrict__ xw, const float* __restrict__ bias,
                         const float* __restrict__ dinv, float* __restrict__ h, int n) {
  int gid = blockIdx.x * blockDim.x + threadIdx.x;
  int node = gid >> 5, c4 = gid & 31;
  if (node >= n) return;
  float di = dinv[node];
  float nm = di * di;
  float4 v = ((const float4*)(xw + (size_t)node * HH))[c4];
  float4 b = ((const float4*)bias)[c4];
  ((float4*)(h + (size_t)node * HH))[c4] =
      make_float4(b.x + nm * v.x, b.y + nm * v.y, b.z + nm * v.z, b.w + nm * v.w);
}
__global__ void scatter_k(const float* __restrict__ xw, float* __restrict__ h,
                          const float* __restrict__ dinv, const int* __restrict__ src,
                          const int* __restrict__ dst, int e) {
  int gid = blockIdx.x * blockDim.x + threadIdx.x;
  int edge = gid >> 5, lane = gid & 5;
  lane = gid & 31;
  if (edge >= e) return;
  int s = src[edge], d = dst[edge];
  float norm = dinv[s] * dinv[d];
  float4 v = ((const float4*)(xw + (size_t)s * HH))[lane];
  float* o = h + (size_t)d * HH + lane * 4;
  atomicAdd(o + 0, norm * v.x);
  atomicAdd(o + 1, norm * v.y);
  atomicAdd(o + 2, norm * v.z);
  atomicAdd(o + 3, norm * v.w);
}
__global__ void relu_k(float4* __restrict__ h, int n4) {
  int i = blockIdx.x * blockDim.x + threadIdx.x;
  if (i < n4) {
    float4 v = h[i];
    v.x = fmaxf(v.x, 0.f); v.y = fmaxf(v.y, 0.f);
    v.z = fmaxf(v.z, 0.f); v.w = fmaxf(v.w, 0.f);
    h[i] = v;
  }
}
__global__ void pool_accum_k(const float* __restrict__ h, const int* __restrict__ dict,
                             float* __restrict__ z, float* __restrict__ cnt, int n) {
  int gid = blockIdx.x * blockDim.x + threadIdx.x;
  int node = gid >> 5, lane = gid & 31;
  if (node >= n) return;
  int d = dict[node];
  float4 v = ((const float4*)(h + (size_t)node * HH))[lane];
  float* o = z + (size_t)d * HH + lane * 4;
  atomicAdd(o + 0, v.x); atomicAdd(o + 1, v.y);
  atomicAdd(o + 2, v.z); atomicAdd(o + 3, v.w);
  if (lane == 0) atomicAdd(&cnt[d], 1.0f);
}
__global__ void pool_div_k(float* __restrict__ z, const float* __restrict__ cnt, int n) {
  int gid = blockIdx.x * blockDim.x + threadIdx.x;
  int node = gid >> 5, lane = gid & 31;
  if (node >= n) return;
  float inv = 1.0f / fmaxf(cnt[node], 1.0f);
  float4* p = (float4*)(z + (size_t)node * HH) + lane;
  float4 v = *p;
  v.x *= inv; v.y *= inv; v.z *= inv; v.w *= inv;
  *p = v;
}

// ================= host launch =================
extern "C" void kernel_launch(void* const* d_in, const int* in_sizes, int n_in,
                              void* d_out, int out_size, void* d_ws, size_t ws_size,
                              hipStream_t stream) {
  const float* x  = (const float*)d_in[0];
  const float* W1 = (const float*)d_in[1];
  const float* b1 = (const float*)d_in[2];
  const float* W2 = (const float*)d_in[3];
  const float* b2 = (const float*)d_in[4];
  const int* ei   = (const int*)d_in[5];
  const int* dict = (const int*)d_in[6];
  const int* pe   = (const int*)d_in[7];
  const int* ne   = (const int*)d_in[8];

  const int n  = in_sizes[0] / HH;   // 100000
  const int e  = in_sizes[5] / 2;    // 1.6M
  const int ep = in_sizes[7] / 2;    // 200000
  const int* src = ei;
  const int* dst = ei + e;

  const size_t nf = (size_t)n * HH;

  // CSR layout: bufA, bufB, dinv[n], rowptr[n+1], tmp[n], esrc[e], bsum[256]
  float* bufA   = (float*)d_ws;
  float* bufB   = bufA + nf;
  float* dinv   = bufB + nf;
  int*   rowptr = (int*)(dinv + n);
  int*   tmp    = rowptr + (n + 1);
  int*   esrc   = tmp + n;
  int*   bsum   = esrc + e;
  size_t need = (2 * nf + n) * sizeof(float) + (size_t)(3 * n + 1 + e + 256) * sizeof(int);

  const int nb    = (n + 255) / 256;
  const int eb    = (e + 255) / 256;
  const int nb32  = (int)(((size_t)n * 32 + 255) / 256);
  const int nb64  = (int)(((size_t)n * 64 + 255) / 256);
  const int NBS   = (n + SCAN_C - 1) / SCAN_C;

  if (ws_size >= need) {
    // ---- build edge CSR (by dst) + dinv ----
    hipMemsetAsync(tmp, 0, (size_t)n * sizeof(int), stream);
    hist_k<<<eb, 256, 0, stream>>>(dst, tmp, e);
    scan_pass1_k<<<NBS, SCAN_T, 0, stream>>>(tmp, bsum, n);
    scan_pass2_k<<<1, SCAN_T, 0, stream>>>(bsum, NBS, rowptr + n, e);
    scan_pass3_k<<<NBS, SCAN_T, 0, stream>>>(tmp, bsum, rowptr, dinv, n);
    build_edges_k<<<eb, 256, 0, stream>>>(src, dst, tmp, esrc, e);

    // ---- conv1 ----
    gemm128_v2<<<nb, 256, 0, stream>>>(x, W1, dinv, bufA, n);      // xw' = dinv * xW1
    gather_k<<<nb64, 256, 0, stream>>>(bufA, rowptr, esrc, dinv, b1, bufB, n);
    // ---- conv2 ----
    gemm128_v2<<<nb, 256, 0, stream>>>(bufB, W2, dinv, bufA, n);   // h1w' = dinv * h1W2
    gather_k<<<nb64, 256, 0, stream>>>(bufA, rowptr, esrc, dinv, b2, bufB, n);
    // bufB = h2 (relu'd)

    // ---- build node CSR (by dict) ----
    hipMemsetAsync(tmp, 0, (size_t)n * sizeof(int), stream);
    hist_k<<<nb, 256, 0, stream>>>(dict, tmp, n);
    scan_pass1_k<<<NBS, SCAN_T, 0, stream>>>(tmp, bsum, n);
    scan_pass2_k<<<1, SCAN_T, 0, stream>>>(bsum, NBS, rowptr + n, n);
    scan_pass3_k<<<NBS, SCAN_T, 0, stream>>>(tmp, bsum, rowptr, nullptr, n);
    build_nodes_k<<<nb, 256, 0, stream>>>(dict, tmp, esrc, n);     // esrc = nodelist

    // ---- pool (gather) -> z in bufA ----
    gatherpool_k<<<nb64, 256, 0, stream>>>(bufB, rowptr, esrc, bufA, n);
  } else {
    // ---- fallback: atomic path (bufA, bufB, dinv, cnt) ----
    float* cnt = dinv + n;
    fill_deg_k<<<nb, 256, 0, stream>>>(dinv, n);
    accum_deg_k<<<eb, 256, 0, stream>>>(dst, dinv, e);
    dinv_k<<<nb, 256, 0, stream>>>(dinv, n);

    gemm128_v2<<<nb, 256, 0, stream>>>(x, W1, nullptr, bufA, n);
    init_h_k<<<nb32, 256, 0, stream>>>(bufA, b1, dinv, bufB, n);
    scatter_k<<<(int)(((size_t)e * 32 + 255) / 256), 256, 0, stream>>>(bufA, bufB, dinv, src, dst, e);
    relu_k<<<nb32, 256, 0, stream>>>((float4*)bufB, n * 32);

    gemm128_v2<<<nb, 256, 0, stream>>>(bufB, W2, nullptr, bufA, n);
    init_h_k<<<nb32, 256, 0, stream>>>(bufA, b2, dinv, bufB, n);
    scatter_k<<<(int)(((size_t)e * 32 + 255) / 256), 256, 0, stream>>>(bufA, bufB, dinv, src, dst, e);
    relu_k<<<nb32, 256, 0, stream>>>((float4*)bufB, n * 32);

    hipMemsetAsync(bufA, 0, nf * sizeof(float), stream);
    hipMemsetAsync(cnt, 0, (size_t)n * sizeof(float), stream);
    pool_accum_k<<<nb32, 256, 0, stream>>>(bufB, dict, bufA, cnt, n);
    pool_div_k<<<nb32, 256, 0, stream>>>(bufA, cnt, n);
  }

  // ---- decode ----
  decode_k<<<(int)(((size_t)2 * ep * 32 + 255) / 256), 256, 0, stream>>>(
      bufA, pe, ne, (float*)d_out, ep);
}

// Round 4
// 671.180 us; speedup vs baseline: 8.9471x; 1.1427x over previous
//
#include <hip/hip_runtime.h>

#define HH 128   // hidden size (both layers, and F_IN)
#define SCAN_T 256
#define SCAN_C 2048  // elements per scan block (256 threads x 8)

// ================= CSR build: histogram / scan / bucket-fill =================

__global__ void hist_k(const int* __restrict__ key, int* __restrict__ hist, int e) {
  int i = blockIdx.x * blockDim.x + threadIdx.x;
  if (i < e) atomicAdd(&hist[key[i]], 1);
}

__global__ __launch_bounds__(SCAN_T) void scan_pass1_k(const int* __restrict__ hist,
                                                       int* __restrict__ bsum, int n) {
  __shared__ int lds[SCAN_T];
  int base = blockIdx.x * SCAN_C + threadIdx.x * 8;
  int s = 0;
  #pragma unroll
  for (int k = 0; k < 8; ++k) { int i = base + k; if (i < n) s += hist[i]; }
  lds[threadIdx.x] = s;
  __syncthreads();
  for (int off = 128; off > 0; off >>= 1) {
    if (threadIdx.x < off) lds[threadIdx.x] += lds[threadIdx.x + off];
    __syncthreads();
  }
  if (threadIdx.x == 0) bsum[blockIdx.x] = lds[0];
}

// single block; nb <= SCAN_T; also writes rowptr[n] = total
__global__ __launch_bounds__(SCAN_T) void scan_pass2_k(int* __restrict__ bsum, int nb,
                                                       int* __restrict__ rowptr_n, int total) {
  __shared__ int lds[SCAN_T];
  int v = (threadIdx.x < nb) ? bsum[threadIdx.x] : 0;
  lds[threadIdx.x] = v;
  __syncthreads();
  for (int off = 1; off < SCAN_T; off <<= 1) {
    int t = (threadIdx.x >= off) ? lds[threadIdx.x - off] : 0;
    __syncthreads();
    lds[threadIdx.x] += t;
    __syncthreads();
  }
  if (threadIdx.x < nb) bsum[threadIdx.x] = (threadIdx.x == 0) ? 0 : lds[threadIdx.x - 1];
  if (threadIdx.x == 0) *rowptr_n = total;
}

// tmp: hist in -> cursor out; also rowptr (exclusive scan) and dinv = rsqrt(cnt+1)
__global__ __launch_bounds__(SCAN_T) void scan_pass3_k(int* __restrict__ tmp,
                                                       const int* __restrict__ bsum,
                                                       int* __restrict__ rowptr,
                                                       float* __restrict__ dinv, int n) {
  __shared__ int lds[SCAN_T];
  int base = blockIdx.x * SCAN_C + threadIdx.x * 8;
  int v[8]; int s = 0;
  #pragma unroll
  for (int k = 0; k < 8; ++k) { int i = base + k; v[k] = (i < n) ? tmp[i] : 0; s += v[k]; }
  lds[threadIdx.x] = s;
  __syncthreads();
  for (int off = 1; off < SCAN_T; off <<= 1) {
    int t = (threadIdx.x >= off) ? lds[threadIdx.x - off] : 0;
    __syncthreads();
    lds[threadIdx.x] += t;
    __syncthreads();
  }
  int run = bsum[blockIdx.x] + ((threadIdx.x == 0) ? 0 : lds[threadIdx.x - 1]);
  #pragma unroll
  for (int k = 0; k < 8; ++k) {
    int i = base + k;
    if (i < n) {
      rowptr[i] = run;
      tmp[i] = run;                        // cursor for bucket fill
      if (dinv) dinv[i] = rsqrtf((float)v[k] + 1.0f);
      run += v[k];
    }
  }
}

__global__ void build_edges_k(const int* __restrict__ src, const int* __restrict__ dst,
                              int* __restrict__ cursor, int* __restrict__ esrc, int e) {
  int i = blockIdx.x * blockDim.x + threadIdx.x;
  if (i < e) {
    int pos = atomicAdd(&cursor[dst[i]], 1);
    esrc[pos] = src[i];
  }
}

__global__ void build_nodes_k(const int* __restrict__ dict, int* __restrict__ cursor,
                              int* __restrict__ nodelist, int n) {
  int i = blockIdx.x * blockDim.x + threadIdx.x;
  if (i < n) {
    int pos = atomicAdd(&cursor[dict[i]], 1);
    nodelist[pos] = i;
  }
}

// ========== GEMM v3: LDS-staged A tile (64 rows), thread = quarter row ==========
// out[i,:] = scale(i) * (A[i,:] @ W).  W loads are wave-uniform (readfirstlane'd q)
// -> s_load through SMEM; A read from padded LDS (2-way, free).
__global__ __launch_bounds__(256) void gemm128_v3(const float* __restrict__ A,
                                                  const float* __restrict__ W,
                                                  const float* __restrict__ dscale,
                                                  float* __restrict__ out, int n) {
  __shared__ float As[64][129];   // +1 pad: As[r][k] reads are 2-way (free)
  const int tid = threadIdx.x;
  const int rbase = blockIdx.x * 64;

  // stage 64x128 A tile, coalesced float4 loads, scalar LDS writes
  const int vrows = (n - rbase) < 64 ? (n - rbase) : 64;
  const int maxf4 = vrows * 32;
  const float4* Ag = (const float4*)(A + (size_t)rbase * HH);
  #pragma unroll
  for (int j = 0; j < 8; ++j) {
    int f = tid + 256 * j;               // float4 index in tile
    int r = f >> 5, c4 = f & 31;
    float4 v = (f < maxf4) ? Ag[f] : make_float4(0.f, 0.f, 0.f, 0.f);
    As[r][c4 * 4 + 0] = v.x;
    As[r][c4 * 4 + 1] = v.y;
    As[r][c4 * 4 + 2] = v.z;
    As[r][c4 * 4 + 3] = v.w;
  }
  __syncthreads();

  const int r = tid & 63;
  const int q = __builtin_amdgcn_readfirstlane(tid >> 6);  // wave-uniform quarter
  const float* Asr = &As[r][0];
  const float* Wq = W + q * 32;

  float4 acc[8];
  #pragma unroll
  for (int c = 0; c < 8; ++c) acc[c] = make_float4(0.f, 0.f, 0.f, 0.f);

  #pragma unroll 4
  for (int k = 0; k < HH; ++k) {
    float a = Asr[k];
    const float4* Wr = (const float4*)(Wq + (size_t)k * HH);
    #pragma unroll
    for (int c = 0; c < 8; ++c) {
      float4 w = Wr[c];
      acc[c].x += a * w.x; acc[c].y += a * w.y;
      acc[c].z += a * w.z; acc[c].w += a * w.w;
    }
  }

  int row = rbase + r;
  if (row < n) {
    float s = dscale ? dscale[row] : 1.0f;
    float4* o = (float4*)(out + (size_t)row * HH + q * 32);
    #pragma unroll
    for (int c = 0; c < 8; ++c) {
      acc[c].x *= s; acc[c].y *= s; acc[c].z *= s; acc[c].w *= s;
      o[c] = acc[c];
    }
  }
}

// ==== gather conv (pre-scaled xw'): h[d] = relu(bias + dinv[d]*(xw'[d] + sum xw'[s])) ====
__global__ __launch_bounds__(256) void gather_k(const float* __restrict__ xwp,
                                                const int* __restrict__ rowptr,
                                                const int* __restrict__ esrc,
                                                const float* __restrict__ dinv,
                                                const float* __restrict__ bias,
                                                float* __restrict__ h, int n) {
  int wid = (int)((blockIdx.x * (size_t)blockDim.x + threadIdx.x) >> 6);
  int lane = threadIdx.x & 63;
  if (wid >= n) return;
  int beg = rowptr[wid], end = rowptr[wid + 1];
  const float2* base = (const float2*)xwp + lane;   // lane-fixed column pair
  float2 acc = base[(unsigned)wid << 6];            // self term (pre-scaled)

  for (int j0 = beg; j0 < end; j0 += 64) {
    int myj = j0 + lane;
    int sv = (myj < end) ? esrc[myj] : 0;
    int cnt = end - j0; if (cnt > 64) cnt = 64;
    int k = 0;
    for (; k + 4 <= cnt; k += 4) {
      unsigned o0 = (unsigned)__builtin_amdgcn_readlane(sv, k + 0) << 6;
      unsigned o1 = (unsigned)__builtin_amdgcn_readlane(sv, k + 1) << 6;
      unsigned o2 = (unsigned)__builtin_amdgcn_readlane(sv, k + 2) << 6;
      unsigned o3 = (unsigned)__builtin_amdgcn_readlane(sv, k + 3) << 6;
      float2 v0 = base[o0], v1 = base[o1], v2 = base[o2], v3 = base[o3];
      acc.x += (v0.x + v1.x) + (v2.x + v3.x);
      acc.y += (v0.y + v1.y) + (v2.y + v3.y);
    }
    for (; k < cnt; ++k) {
      unsigned o = (unsigned)__builtin_amdgcn_readlane(sv, k) << 6;
      float2 v = base[o];
      acc.x += v.x; acc.y += v.y;
    }
  }
  float di = dinv[wid];
  float2 bb = ((const float2*)bias)[lane];
  acc.x = fmaxf(bb.x + di * acc.x, 0.f);
  acc.y = fmaxf(bb.y + di * acc.y, 0.f);
  ((float2*)h)[((size_t)wid << 6) + lane] = acc;
}

// ======== gather pool: z[d] = mean over nodes i with dict[i]==d of h[i] (0 if empty) ========
__global__ __launch_bounds__(256) void gatherpool_k(const float* __restrict__ h,
                                                    const int* __restrict__ rowptr,
                                                    const int* __restrict__ nodelist,
                                                    float* __restrict__ z, int n) {
  int wid = (int)((blockIdx.x * (size_t)blockDim.x + threadIdx.x) >> 6);
  int lane = threadIdx.x & 63;
  if (wid >= n) return;
  int beg = rowptr[wid], end = rowptr[wid + 1];
  float inv = 1.0f / fmaxf((float)(end - beg), 1.0f);
  const float2* base = (const float2*)h + lane;
  float2 acc = make_float2(0.f, 0.f);
  for (int j0 = beg; j0 < end; j0 += 64) {
    int myj = j0 + lane;
    int sv = (myj < end) ? nodelist[myj] : 0;
    int cnt = end - j0; if (cnt > 64) cnt = 64;
    int k = 0;
    for (; k + 4 <= cnt; k += 4) {
      unsigned o0 = (unsigned)__builtin_amdgcn_readlane(sv, k + 0) << 6;
      unsigned o1 = (unsigned)__builtin_amdgcn_readlane(sv, k + 1) << 6;
      unsigned o2 = (unsigned)__builtin_amdgcn_readlane(sv, k + 2) << 6;
      unsigned o3 = (unsigned)__builtin_amdgcn_readlane(sv, k + 3) << 6;
      float2 v0 = base[o0], v1 = base[o1], v2 = base[o2], v3 = base[o3];
      acc.x += (v0.x + v1.x) + (v2.x + v3.x);
      acc.y += (v0.y + v1.y) + (v2.y + v3.y);
    }
    for (; k < cnt; ++k) {
      unsigned o = (unsigned)__builtin_amdgcn_readlane(sv, k) << 6;
      float2 v = base[o];
      acc.x += v.x; acc.y += v.y;
    }
  }
  acc.x *= inv; acc.y *= inv;
  ((float2*)z)[((size_t)wid << 6) + lane] = acc;
}

// ================= decode: logits[e] = dot(z[a], z[b]) over 128 =================
__global__ void decode_k(const float* __restrict__ z, const int* __restrict__ pos,
                         const int* __restrict__ neg, float* __restrict__ out, int ep) {
  int gid = blockIdx.x * blockDim.x + threadIdx.x;
  int edge = gid >> 5, lane = gid & 31;
  if (edge >= 2 * ep) return;
  int a, b;
  if (edge < ep) { a = pos[edge];      b = pos[ep + edge]; }
  else           { a = neg[edge - ep]; b = neg[edge]; }
  const float4* za = (const float4*)(z + (size_t)a * HH);
  const float4* zb = (const float4*)(z + (size_t)b * HH);
  float4 va = za[lane], vb = zb[lane];
  float dot = va.x * vb.x + va.y * vb.y + va.z * vb.z + va.w * vb.w;
  #pragma unroll
  for (int off = 16; off > 0; off >>= 1) dot += __shfl_xor(dot, off);
  if (lane == 0) out[edge] = dot;
}

// ================= fallback path (small ws): atomic version =================
__global__ void fill_deg_k(float* __restrict__ deg, int n) {
  int i = blockIdx.x * blockDim.x + threadIdx.x;
  if (i < n) deg[i] = 1.0f;
}
__global__ void accum_deg_k(const int* __restrict__ dst, float* __restrict__ deg, int e) {
  int i = blockIdx.x * blockDim.x + threadIdx.x;
  if (i < e) atomicAdd(&deg[dst[i]], 1.0f);
}
__global__ void dinv_k(float* __restrict__ deg, int n) {
  int i = blockIdx.x * blockDim.x + threadIdx.x;
  if (i < n) deg[i] = rsqrtf(deg[i]);
}
__global__ void init_h_k(const float* __restrict__ xw, const float* __restrict__ bias,
                         const float* __restrict__ dinv, float* __restrict__ h, int n) {
  int gid = blockIdx.x * blockDim.x + threadIdx.x;
  int node = gid >> 5, c4 = gid & 31;
  if (node >= n) return;
  float di = dinv[node];
  float nm = di * di;
  float4 v = ((const float4*)(xw + (size_t)node * HH))[c4];
  float4 b = ((const float4*)bias)[c4];
  ((float4*)(h + (size_t)node * HH))[c4] =
      make_float4(b.x + nm * v.x, b.y + nm * v.y, b.z + nm * v.z, b.w + nm * v.w);
}
__global__ void scatter_k(const float* __restrict__ xw, float* __restrict__ h,
                          const float* __restrict__ dinv, const int* __restrict__ src,
                          const int* __restrict__ dst, int e) {
  int gid = blockIdx.x * blockDim.x + threadIdx.x;
  int edge = gid >> 5, lane = gid & 31;
  if (edge >= e) return;
  int s = src[edge], d = dst[edge];
  float norm = dinv[s] * dinv[d];
  float4 v = ((const float4*)(xw + (size_t)s * HH))[lane];
  float* o = h + (size_t)d * HH + lane * 4;
  atomicAdd(o + 0, norm * v.x);
  atomicAdd(o + 1, norm * v.y);
  atomicAdd(o + 2, norm * v.z);
  atomicAdd(o + 3, norm * v.w);
}
__global__ void relu_k(float4* __restrict__ h, int n4) {
  int i = blockIdx.x * blockDim.x + threadIdx.x;
  if (i < n4) {
    float4 v = h[i];
    v.x = fmaxf(v.x, 0.f); v.y = fmaxf(v.y, 0.f);
    v.z = fmaxf(v.z, 0.f); v.w = fmaxf(v.w, 0.f);
    h[i] = v;
  }
}
__global__ void pool_accum_k(const float* __restrict__ h, const int* __restrict__ dict,
                             float* __restrict__ z, float* __restrict__ cnt, int n) {
  int gid = blockIdx.x * blockDim.x + threadIdx.x;
  int node = gid >> 5, lane = gid & 31;
  if (node >= n) return;
  int d = dict[node];
  float4 v = ((const float4*)(h + (size_t)node * HH))[lane];
  float* o = z + (size_t)d * HH + lane * 4;
  atomicAdd(o + 0, v.x); atomicAdd(o + 1, v.y);
  atomicAdd(o + 2, v.z); atomicAdd(o + 3, v.w);
  if (lane == 0) atomicAdd(&cnt[d], 1.0f);
}
__global__ void pool_div_k(float* __restrict__ z, const float* __restrict__ cnt, int n) {
  int gid = blockIdx.x * blockDim.x + threadIdx.x;
  int node = gid >> 5, lane = gid & 31;
  if (node >= n) return;
  float inv = 1.0f / fmaxf(cnt[node], 1.0f);
  float4* p = (float4*)(z + (size_t)node * HH) + lane;
  float4 v = *p;
  v.x *= inv; v.y *= inv; v.z *= inv; v.w *= inv;
  *p = v;
}

// ================= host launch =================
extern "C" void kernel_launch(void* const* d_in, const int* in_sizes, int n_in,
                              void* d_out, int out_size, void* d_ws, size_t ws_size,
                              hipStream_t stream) {
  const float* x  = (const float*)d_in[0];
  const float* W1 = (const float*)d_in[1];
  const float* b1 = (const float*)d_in[2];
  const float* W2 = (const float*)d_in[3];
  const float* b2 = (const float*)d_in[4];
  const int* ei   = (const int*)d_in[5];
  const int* dict = (const int*)d_in[6];
  const int* pe   = (const int*)d_in[7];
  const int* ne   = (const int*)d_in[8];

  const int n  = in_sizes[0] / HH;   // 100000
  const int e  = in_sizes[5] / 2;    // 1.6M
  const int ep = in_sizes[7] / 2;    // 200000
  const int* src = ei;
  const int* dst = ei + e;

  const size_t nf = (size_t)n * HH;

  // CSR layout: bufA, bufB, dinv[n], rowptr[n+1], tmp[n], esrc[e], bsum[256]
  float* bufA   = (float*)d_ws;
  float* bufB   = bufA + nf;
  float* dinv   = bufB + nf;
  int*   rowptr = (int*)(dinv + n);
  int*   tmp    = rowptr + (n + 1);
  int*   esrc   = tmp + n;
  int*   bsum   = esrc + e;
  size_t need = (2 * nf + n) * sizeof(float) + (size_t)(3 * n + 1 + e + 256) * sizeof(int);

  const int nb    = (n + 255) / 256;
  const int eb    = (e + 255) / 256;
  const int nb32  = (int)(((size_t)n * 32 + 255) / 256);
  const int nb64  = (int)(((size_t)n * 64 + 255) / 256);
  const int gemb  = (n + 63) / 64;
  const int NBS   = (n + SCAN_C - 1) / SCAN_C;

  if (ws_size >= need) {
    // ---- build edge CSR (by dst) + dinv ----
    hipMemsetAsync(tmp, 0, (size_t)n * sizeof(int), stream);
    hist_k<<<eb, 256, 0, stream>>>(dst, tmp, e);
    scan_pass1_k<<<NBS, SCAN_T, 0, stream>>>(tmp, bsum, n);
    scan_pass2_k<<<1, SCAN_T, 0, stream>>>(bsum, NBS, rowptr + n, e);
    scan_pass3_k<<<NBS, SCAN_T, 0, stream>>>(tmp, bsum, rowptr, dinv, n);
    build_edges_k<<<eb, 256, 0, stream>>>(src, dst, tmp, esrc, e);

    // ---- conv1 ----
    gemm128_v3<<<gemb, 256, 0, stream>>>(x, W1, dinv, bufA, n);      // xw' = dinv * xW1
    gather_k<<<nb64, 256, 0, stream>>>(bufA, rowptr, esrc, dinv, b1, bufB, n);
    // ---- conv2 ----
    gemm128_v3<<<gemb, 256, 0, stream>>>(bufB, W2, dinv, bufA, n);   // h1w' = dinv * h1W2
    gather_k<<<nb64, 256, 0, stream>>>(bufA, rowptr, esrc, dinv, b2, bufB, n);
    // bufB = h2 (relu'd)

    // ---- build node CSR (by dict) ----
    hipMemsetAsync(tmp, 0, (size_t)n * sizeof(int), stream);
    hist_k<<<nb, 256, 0, stream>>>(dict, tmp, n);
    scan_pass1_k<<<NBS, SCAN_T, 0, stream>>>(tmp, bsum, n);
    scan_pass2_k<<<1, SCAN_T, 0, stream>>>(bsum, NBS, rowptr + n, n);
    scan_pass3_k<<<NBS, SCAN_T, 0, stream>>>(tmp, bsum, rowptr, nullptr, n);
    build_nodes_k<<<nb, 256, 0, stream>>>(dict, tmp, esrc, n);       // esrc = nodelist

    // ---- pool (gather) -> z in bufA ----
    gatherpool_k<<<nb64, 256, 0, stream>>>(bufB, rowptr, esrc, bufA, n);
  } else {
    // ---- fallback: atomic path (bufA, bufB, dinv, cnt) ----
    float* cnt = dinv + n;
    fill_deg_k<<<nb, 256, 0, stream>>>(dinv, n);
    accum_deg_k<<<eb, 256, 0, stream>>>(dst, dinv, e);
    dinv_k<<<nb, 256, 0, stream>>>(dinv, n);

    gemm128_v3<<<gemb, 256, 0, stream>>>(x, W1, nullptr, bufA, n);
    init_h_k<<<nb32, 256, 0, stream>>>(bufA, b1, dinv, bufB, n);
    scatter_k<<<(int)(((size_t)e * 32 + 255) / 256), 256, 0, stream>>>(bufA, bufB, dinv, src, dst, e);
    relu_k<<<nb32, 256, 0, stream>>>((float4*)bufB, n * 32);

    gemm128_v3<<<gemb, 256, 0, stream>>>(bufB, W2, nullptr, bufA, n);
    init_h_k<<<nb32, 256, 0, stream>>>(bufA, b2, dinv, bufB, n);
    scatter_k<<<(int)(((size_t)e * 32 + 255) / 256), 256, 0, stream>>>(bufA, bufB, dinv, src, dst, e);
    relu_k<<<nb32, 256, 0, stream>>>((float4*)bufB, n * 32);

    hipMemsetAsync(bufA, 0, nf * sizeof(float), stream);
    hipMemsetAsync(cnt, 0, (size_t)n * sizeof(float), stream);
    pool_accum_k<<<nb32, 256, 0, stream>>>(bufB, dict, bufA, cnt, n);
    pool_div_k<<<nb32, 256, 0, stream>>>(bufA, cnt, n);
  }

  // ---- decode ----
  decode_k<<<(int)(((size_t)2 * ep * 32 + 255) / 256), 256, 0, stream>>>(
      bufA, pe, ne, (float*)d_out, ep);
}

// Round 5
// 544.684 us; speedup vs baseline: 11.0250x; 1.2322x over previous
//
#include <hip/hip_runtime.h>

#define HH 128   // hidden size (both layers, and F_IN)
#define SCAN_T 256
#define SCAN_C 2048   // elements per scan block (256 threads x 8)
#define PCHUNK 16384  // edges per partition block

// ================= node-CSR build (for pooling): histogram / scan / fill =================

__global__ void hist_k(const int* __restrict__ key, int* __restrict__ hist, int e) {
  int i = blockIdx.x * blockDim.x + threadIdx.x;
  if (i < e) atomicAdd(&hist[key[i]], 1);
}

__global__ __launch_bounds__(SCAN_T) void scan_pass1_k(const int* __restrict__ hist,
                                                       int* __restrict__ bsum, int n) {
  __shared__ int lds[SCAN_T];
  int base = blockIdx.x * SCAN_C + threadIdx.x * 8;
  int s = 0;
  #pragma unroll
  for (int k = 0; k < 8; ++k) { int i = base + k; if (i < n) s += hist[i]; }
  lds[threadIdx.x] = s;
  __syncthreads();
  for (int off = 128; off > 0; off >>= 1) {
    if (threadIdx.x < off) lds[threadIdx.x] += lds[threadIdx.x + off];
    __syncthreads();
  }
  if (threadIdx.x == 0) bsum[blockIdx.x] = lds[0];
}

__global__ __launch_bounds__(SCAN_T) void scan_pass2_k(int* __restrict__ bsum, int nb,
                                                       int* __restrict__ rowptr_n, int total) {
  __shared__ int lds[SCAN_T];
  int v = (threadIdx.x < nb) ? bsum[threadIdx.x] : 0;
  lds[threadIdx.x] = v;
  __syncthreads();
  for (int off = 1; off < SCAN_T; off <<= 1) {
    int t = (threadIdx.x >= off) ? lds[threadIdx.x - off] : 0;
    __syncthreads();
    lds[threadIdx.x] += t;
    __syncthreads();
  }
  if (threadIdx.x < nb) bsum[threadIdx.x] = (threadIdx.x == 0) ? 0 : lds[threadIdx.x - 1];
  if (threadIdx.x == 0) *rowptr_n = total;
}

__global__ __launch_bounds__(SCAN_T) void scan_pass3_k(int* __restrict__ tmp,
                                                       const int* __restrict__ bsum,
                                                       int* __restrict__ rowptr,
                                                       float* __restrict__ dinv, int n) {
  __shared__ int lds[SCAN_T];
  int base = blockIdx.x * SCAN_C + threadIdx.x * 8;
  int v[8]; int s = 0;
  #pragma unroll
  for (int k = 0; k < 8; ++k) { int i = base + k; v[k] = (i < n) ? tmp[i] : 0; s += v[k]; }
  lds[threadIdx.x] = s;
  __syncthreads();
  for (int off = 1; off < SCAN_T; off <<= 1) {
    int t = (threadIdx.x >= off) ? lds[threadIdx.x - off] : 0;
    __syncthreads();
    lds[threadIdx.x] += t;
    __syncthreads();
  }
  int run = bsum[blockIdx.x] + ((threadIdx.x == 0) ? 0 : lds[threadIdx.x - 1]);
  #pragma unroll
  for (int k = 0; k < 8; ++k) {
    int i = base + k;
    if (i < n) {
      rowptr[i] = run;
      tmp[i] = run;
      if (dinv) dinv[i] = rsqrtf((float)v[k] + 1.0f);
      run += v[k];
    }
  }
}

__global__ void build_nodes_k(const int* __restrict__ dict, int* __restrict__ cursor,
                              int* __restrict__ nodelist, int n) {
  int i = blockIdx.x * blockDim.x + threadIdx.x;
  if (i < n) {
    int pos = atomicAdd(&cursor[dict[i]], 1);
    nodelist[pos] = i;
  }
}

// ================= edge-CSR build: bucketed 2-phase counting sort =================
// bucket = dst >> 8 (256 dst per bucket).  nbkt <= 512 required.

// Phase A1: per-block LDS histogram over PCHUNK edges; claim per-(bucket,block) base.
__global__ __launch_bounds__(256) void part_count_k(const int* __restrict__ dst, int e,
                                                    int nbkt, int nblk,
                                                    int* __restrict__ gcnt,
                                                    int* __restrict__ blkoff) {
  __shared__ int h[512];
  for (int i = threadIdx.x; i < nbkt; i += 256) h[i] = 0;
  __syncthreads();
  int start = blockIdx.x * PCHUNK;
  int cnt = e - start; if (cnt > PCHUNK) cnt = PCHUNK;
  for (int i = threadIdx.x; i < cnt; i += 256)
    atomicAdd(&h[dst[start + i] >> 8], 1);
  __syncthreads();
  for (int i = threadIdx.x; i < nbkt; i += 256) {
    int c = h[i];
    if (c) blkoff[(size_t)i * nblk + blockIdx.x] = atomicAdd(&gcnt[i], c);
  }
}

// exclusive scan of gcnt[nbkt] -> bktbase; bktbase[nbkt] = e.  single block.
__global__ __launch_bounds__(512) void scan_bkt_k(const int* __restrict__ gcnt,
                                                  int* __restrict__ bktbase, int nbkt, int e) {
  __shared__ int sc[512];
  int tid = threadIdx.x;
  int v = (tid < nbkt) ? gcnt[tid] : 0;
  sc[tid] = v;
  __syncthreads();
  for (int off = 1; off < 512; off <<= 1) {
    int t = (tid >= off) ? sc[tid - off] : 0;
    __syncthreads();
    sc[tid] += t;
    __syncthreads();
  }
  if (tid < nbkt) bktbase[tid] = sc[tid] - v;
  if (tid == 0) bktbase[nbkt] = e;
}

// Phase A2: scatter (src,dst) pairs into bucket-partitioned array.
__global__ __launch_bounds__(256) void part_scatter_k(const int* __restrict__ src,
                                                      const int* __restrict__ dst, int e,
                                                      int nbkt, int nblk,
                                                      const int* __restrict__ bktbase,
                                                      const int* __restrict__ blkoff,
                                                      int2* __restrict__ part) {
  __shared__ int cur[512];
  for (int i = threadIdx.x; i < nbkt; i += 256)
    cur[i] = bktbase[i] + blkoff[(size_t)i * nblk + blockIdx.x];
  __syncthreads();
  int start = blockIdx.x * PCHUNK;
  int cnt = e - start; if (cnt > PCHUNK) cnt = PCHUNK;
  for (int i = threadIdx.x; i < cnt; i += 256) {
    int d = dst[start + i], s = src[start + i];
    int pos = atomicAdd(&cur[d >> 8], 1);
    part[pos] = make_int2(s, d);
  }
}

// Phase B: per bucket (256 dst), LDS hist + scan -> rowptr, dinv, esrc.
__global__ __launch_bounds__(256) void bucket_csr_k(const int2* __restrict__ part,
                                                    const int* __restrict__ bktbase,
                                                    int* __restrict__ rowptr,
                                                    float* __restrict__ dinv,
                                                    int* __restrict__ esrc,
                                                    int n, int e, int nbkt) {
  __shared__ int hist[256];
  __shared__ int sc[256];
  __shared__ int cur[256];
  int tid = threadIdx.x;
  int b = blockIdx.x;
  int dstbase = b << 8;
  int nloc = n - dstbase; if (nloc > 256) nloc = 256;
  int beg = bktbase[b], bend = bktbase[b + 1];

  hist[tid] = 0;
  __syncthreads();
  for (int j = beg + tid; j < bend; j += 256)
    atomicAdd(&hist[part[j].y & 255], 1);
  __syncthreads();
  int v = hist[tid];
  sc[tid] = v;
  __syncthreads();
  for (int off = 1; off < 256; off <<= 1) {
    int t = (tid >= off) ? sc[tid - off] : 0;
    __syncthreads();
    sc[tid] += t;
    __syncthreads();
  }
  int excl = sc[tid] - v;
  if (tid < nloc) {
    rowptr[dstbase + tid] = beg + excl;
    cur[tid] = beg + excl;
    dinv[dstbase + tid] = rsqrtf((float)v + 1.0f);
  }
  __syncthreads();
  for (int j = beg + tid; j < bend; j += 256) {
    int2 p = part[j];
    int pos = atomicAdd(&cur[p.y & 255], 1);
    esrc[pos] = p.x;
  }
  if (b == nbkt - 1 && tid == 0) rowptr[n] = e;
}

// ========== GEMM v3: LDS-staged A tile (64 rows), thread = quarter row ==========
__global__ __launch_bounds__(256) void gemm128_v3(const float* __restrict__ A,
                                                  const float* __restrict__ W,
                                                  const float* __restrict__ dscale,
                                                  float* __restrict__ out, int n) {
  __shared__ float As[64][129];
  const int tid = threadIdx.x;
  const int rbase = blockIdx.x * 64;

  const int vrows = (n - rbase) < 64 ? (n - rbase) : 64;
  const int maxf4 = vrows * 32;
  const float4* Ag = (const float4*)(A + (size_t)rbase * HH);
  #pragma unroll
  for (int j = 0; j < 8; ++j) {
    int f = tid + 256 * j;
    int r = f >> 5, c4 = f & 31;
    float4 v = (f < maxf4) ? Ag[f] : make_float4(0.f, 0.f, 0.f, 0.f);
    As[r][c4 * 4 + 0] = v.x;
    As[r][c4 * 4 + 1] = v.y;
    As[r][c4 * 4 + 2] = v.z;
    As[r][c4 * 4 + 3] = v.w;
  }
  __syncthreads();

  const int r = tid & 63;
  const int q = __builtin_amdgcn_readfirstlane(tid >> 6);
  const float* Asr = &As[r][0];
  const float* Wq = W + q * 32;

  float4 acc[8];
  #pragma unroll
  for (int c = 0; c < 8; ++c) acc[c] = make_float4(0.f, 0.f, 0.f, 0.f);

  #pragma unroll 4
  for (int k = 0; k < HH; ++k) {
    float a = Asr[k];
    const float4* Wr = (const float4*)(Wq + (size_t)k * HH);
    #pragma unroll
    for (int c = 0; c < 8; ++c) {
      float4 w = Wr[c];
      acc[c].x += a * w.x; acc[c].y += a * w.y;
      acc[c].z += a * w.z; acc[c].w += a * w.w;
    }
  }

  int row = rbase + r;
  if (row < n) {
    float s = dscale ? dscale[row] : 1.0f;
    float4* o = (float4*)(out + (size_t)row * HH + q * 32);
    #pragma unroll
    for (int c = 0; c < 8; ++c) {
      acc[c].x *= s; acc[c].y *= s; acc[c].z *= s; acc[c].w *= s;
      o[c] = acc[c];
    }
  }
}

// ==== gather conv: 2 edges per wave, float4/lane.  h[d]=relu(b+dinv[d]*(self'+sum xw'[s])) ====
__global__ __launch_bounds__(256) void gather_k(const float* __restrict__ xwp,
                                                const int* __restrict__ rowptr,
                                                const int* __restrict__ esrc,
                                                const float* __restrict__ dinv,
                                                const float* __restrict__ bias,
                                                float* __restrict__ h, int n) {
  int wid = (int)((blockIdx.x * (size_t)blockDim.x + threadIdx.x) >> 6);
  int lane = threadIdx.x & 63;
  if (wid >= n) return;
  int beg = rowptr[wid], end = rowptr[wid + 1];
  int half = lane >> 5, l32 = lane & 31;
  const float4* base4 = (const float4*)xwp + l32;
  float4 acc = make_float4(0.f, 0.f, 0.f, 0.f);

  for (int j0 = beg; j0 < end; j0 += 64) {
    int myj = j0 + lane;
    int sv = (myj < end) ? esrc[myj] : 0;
    int cnt = end - j0; if (cnt > 64) cnt = 64;
    int k = 0;
    for (; k + 8 <= cnt; k += 8) {
      #pragma unroll
      for (int p = 0; p < 4; ++p) {
        int sa = __builtin_amdgcn_readlane(sv, k + 2 * p);
        int sb = __builtin_amdgcn_readlane(sv, k + 2 * p + 1);
        unsigned off = (unsigned)(half ? sb : sa) << 5;
        float4 v = base4[off];
        acc.x += v.x; acc.y += v.y; acc.z += v.z; acc.w += v.w;
      }
    }
    for (; k + 2 <= cnt; k += 2) {
      int sa = __builtin_amdgcn_readlane(sv, k);
      int sb = __builtin_amdgcn_readlane(sv, k + 1);
      unsigned off = (unsigned)(half ? sb : sa) << 5;
      float4 v = base4[off];
      acc.x += v.x; acc.y += v.y; acc.z += v.z; acc.w += v.w;
    }
    if (k < cnt) {
      int sa = __builtin_amdgcn_readlane(sv, k);
      if (half == 0) {
        float4 v = base4[(unsigned)sa << 5];
        acc.x += v.x; acc.y += v.y; acc.z += v.z; acc.w += v.w;
      }
    }
  }
  acc.x += __shfl_xor(acc.x, 32);
  acc.y += __shfl_xor(acc.y, 32);
  acc.z += __shfl_xor(acc.z, 32);
  acc.w += __shfl_xor(acc.w, 32);
  if (half == 0) {
    float4 self = ((const float4*)xwp)[((size_t)wid << 5) + l32];
    float di = dinv[wid];
    float4 bb = ((const float4*)bias)[l32];
    float4 o;
    o.x = fmaxf(bb.x + di * (acc.x + self.x), 0.f);
    o.y = fmaxf(bb.y + di * (acc.y + self.y), 0.f);
    o.z = fmaxf(bb.z + di * (acc.z + self.z), 0.f);
    o.w = fmaxf(bb.w + di * (acc.w + self.w), 0.f);
    ((float4*)h)[((size_t)wid << 5) + l32] = o;
  }
}

// ======== gather pool: z[d] = mean over nodes i with dict[i]==d of h[i] (0 if empty) ========
__global__ __launch_bounds__(256) void gatherpool_k(const float* __restrict__ h,
                                                    const int* __restrict__ rowptr,
                                                    const int* __restrict__ nodelist,
                                                    float* __restrict__ z, int n) {
  int wid = (int)((blockIdx.x * (size_t)blockDim.x + threadIdx.x) >> 6);
  int lane = threadIdx.x & 63;
  if (wid >= n) return;
  int beg = rowptr[wid], end = rowptr[wid + 1];
  float inv = 1.0f / fmaxf((float)(end - beg), 1.0f);
  const float2* base = (const float2*)h + lane;
  float2 acc = make_float2(0.f, 0.f);
  for (int j0 = beg; j0 < end; j0 += 64) {
    int myj = j0 + lane;
    int sv = (myj < end) ? nodelist[myj] : 0;
    int cnt = end - j0; if (cnt > 64) cnt = 64;
    for (int k = 0; k < cnt; ++k) {
      unsigned o = (unsigned)__builtin_amdgcn_readlane(sv, k) << 6;
      float2 v = base[o];
      acc.x += v.x; acc.y += v.y;
    }
  }
  acc.x *= inv; acc.y *= inv;
  ((float2*)z)[((size_t)wid << 6) + lane] = acc;
}

// ================= decode: logits[e] = dot(z[a], z[b]) over 128 =================
__global__ void decode_k(const float* __restrict__ z, const int* __restrict__ pos,
                         const int* __restrict__ neg, float* __restrict__ out, int ep) {
  int gid = blockIdx.x * blockDim.x + threadIdx.x;
  int edge = gid >> 5, lane = gid & 31;
  if (edge >= 2 * ep) return;
  int a, b;
  if (edge < ep) { a = pos[edge];      b = pos[ep + edge]; }
  else           { a = neg[edge - ep]; b = neg[edge]; }
  const float4* za = (const float4*)(z + (size_t)a * HH);
  const float4* zb = (const float4*)(z + (size_t)b * HH);
  float4 va = za[lane], vb = zb[lane];
  float dot = va.x * vb.x + va.y * vb.y + va.z * vb.z + va.w * vb.w;
  #pragma unroll
  for (int off = 16; off > 0; off >>= 1) dot += __shfl_xor(dot, off);
  if (lane == 0) out[edge] = dot;
}

// ================= fallback path (small ws): atomic version =================
__global__ void fill_deg_k(float* __restrict__ deg, int n) {
  int i = blockIdx.x * blockDim.x + threadIdx.x;
  if (i < n) deg[i] = 1.0f;
}
__global__ void accum_deg_k(const int* __restrict__ dst, float* __restrict__ deg, int e) {
  int i = blockIdx.x * blockDim.x + threadIdx.x;
  if (i < e) atomicAdd(&deg[dst[i]], 1.0f);
}
__global__ void dinv_k(float* __restrict__ deg, int n) {
  int i = blockIdx.x * blockDim.x + threadIdx.x;
  if (i < n) deg[i] = rsqrtf(deg[i]);
}
__global__ void init_h_k(const float* __restrict__ xw, const float* __restrict__ bias,
                         const float* __restrict__ dinv, float* __restrict__ h, int n) {
  int gid = blockIdx.x * blockDim.x + threadIdx.x;
  int node = gid >> 5, c4 = gid & 31;
  if (node >= n) return;
  float di = dinv[node];
  float nm = di * di;
  float4 v = ((const float4*)(xw + (size_t)node * HH))[c4];
  float4 b = ((const float4*)bias)[c4];
  ((float4*)(h + (size_t)node * HH))[c4] =
      make_float4(b.x + nm * v.x, b.y + nm * v.y, b.z + nm * v.z, b.w + nm * v.w);
}
__global__ void scatter_k(const float* __restrict__ xw, float* __restrict__ h,
                          const float* __restrict__ dinv, const int* __restrict__ src,
                          const int* __restrict__ dst, int e) {
  int gid = blockIdx.x * blockDim.x + threadIdx.x;
  int edge = gid >> 5, lane = gid & 31;
  if (edge >= e) return;
  int s = src[edge], d = dst[edge];
  float norm = dinv[s] * dinv[d];
  float4 v = ((const float4*)(xw + (size_t)s * HH))[lane];
  float* o = h + (size_t)d * HH + lane * 4;
  atomicAdd(o + 0, norm * v.x);
  atomicAdd(o + 1, norm * v.y);
  atomicAdd(o + 2, norm * v.z);
  atomicAdd(o + 3, norm * v.w);
}
__global__ void relu_k(float4* __restrict__ h, int n4) {
  int i = blockIdx.x * blockDim.x + threadIdx.x;
  if (i < n4) {
    float4 v = h[i];
    v.x = fmaxf(v.x, 0.f); v.y = fmaxf(v.y, 0.f);
    v.z = fmaxf(v.z, 0.f); v.w = fmaxf(v.w, 0.f);
    h[i] = v;
  }
}
__global__ void pool_accum_k(const float* __restrict__ h, const int* __restrict__ dict,
                             float* __restrict__ z, float* __restrict__ cnt, int n) {
  int gid = blockIdx.x * blockDim.x + threadIdx.x;
  int node = gid >> 5, lane = gid & 31;
  if (node >= n) return;
  int d = dict[node];
  float4 v = ((const float4*)(h + (size_t)node * HH))[lane];
  float* o = z + (size_t)d * HH + lane * 4;
  atomicAdd(o + 0, v.x); atomicAdd(o + 1, v.y);
  atomicAdd(o + 2, v.z); atomicAdd(o + 3, v.w);
  if (lane == 0) atomicAdd(&cnt[d], 1.0f);
}
__global__ void pool_div_k(float* __restrict__ z, const float* __restrict__ cnt, int n) {
  int gid = blockIdx.x * blockDim.x + threadIdx.x;
  int node = gid >> 5, lane = gid & 31;
  if (node >= n) return;
  float inv = 1.0f / fmaxf(cnt[node], 1.0f);
  float4* p = (float4*)(z + (size_t)node * HH) + lane;
  float4 v = *p;
  v.x *= inv; v.y *= inv; v.z *= inv; v.w *= inv;
  *p = v;
}

// ================= host launch =================
extern "C" void kernel_launch(void* const* d_in, const int* in_sizes, int n_in,
                              void* d_out, int out_size, void* d_ws, size_t ws_size,
                              hipStream_t stream) {
  const float* x  = (const float*)d_in[0];
  const float* W1 = (const float*)d_in[1];
  const float* b1 = (const float*)d_in[2];
  const float* W2 = (const float*)d_in[3];
  const float* b2 = (const float*)d_in[4];
  const int* ei   = (const int*)d_in[5];
  const int* dict = (const int*)d_in[6];
  const int* pe   = (const int*)d_in[7];
  const int* ne   = (const int*)d_in[8];

  const int n  = in_sizes[0] / HH;   // 100000
  const int e  = in_sizes[5] / 2;    // 1.6M
  const int ep = in_sizes[7] / 2;    // 200000
  const int* src = ei;
  const int* dst = ei + e;

  const size_t nf = (size_t)n * HH;
  const int nbkt = (n + 255) >> 8;                 // 391
  const int nblk = (e + PCHUNK - 1) / PCHUNK;      // 98

  // ws layout: bufA, bufB, dinv[n], rowptr[n+1], tmp[n], esrc[e], bsum[256], gcnt[nbkt], bktbase[nbkt+1]
  float* bufA   = (float*)d_ws;
  float* bufB   = bufA + nf;
  float* dinv   = bufB + nf;
  int*   rowptr = (int*)(dinv + n);
  int*   tmp    = rowptr + (n + 1);
  int*   esrc   = tmp + n;
  int*   bsum   = esrc + e;
  int*   gcnt   = bsum + 256;
  int*   bktbase = gcnt + nbkt;
  size_t need = (2 * nf + n) * sizeof(float) +
                (size_t)(3 * n + 1 + e + 256 + 2 * nbkt + 1) * sizeof(int);

  // aliases used only during edge-CSR build (before bufA/bufB first written):
  int2* part   = (int2*)bufB;       // e pairs = 12.8 MB <= nf floats
  int*  blkoff = (int*)bufA;        // nbkt*nblk ints ~ 153 KB <= nf floats

  const int nb    = (n + 255) / 256;
  const int nb32  = (int)(((size_t)n * 32 + 255) / 256);
  const int nb64  = (int)(((size_t)n * 64 + 255) / 256);
  const int gemb  = (n + 63) / 64;
  const int NBS   = (n + SCAN_C - 1) / SCAN_C;

  bool fast = (ws_size >= need) && (nbkt <= 512) &&
              ((size_t)nbkt * nblk <= nf) && ((size_t)e * 2 <= nf);

  if (fast) {
    // ---- edge CSR (by dst) + dinv: bucketed 2-phase sort ----
    hipMemsetAsync(gcnt, 0, (size_t)nbkt * sizeof(int), stream);
    part_count_k<<<nblk, 256, 0, stream>>>(dst, e, nbkt, nblk, gcnt, blkoff);
    scan_bkt_k<<<1, 512, 0, stream>>>(gcnt, bktbase, nbkt, e);
    part_scatter_k<<<nblk, 256, 0, stream>>>(src, dst, e, nbkt, nblk, bktbase, blkoff, part);
    bucket_csr_k<<<nbkt, 256, 0, stream>>>(part, bktbase, rowptr, dinv, esrc, n, e, nbkt);

    // ---- conv1 ----
    gemm128_v3<<<gemb, 256, 0, stream>>>(x, W1, dinv, bufA, n);      // xw' = dinv * xW1
    gather_k<<<nb64, 256, 0, stream>>>(bufA, rowptr, esrc, dinv, b1, bufB, n);
    // ---- conv2 ----
    gemm128_v3<<<gemb, 256, 0, stream>>>(bufB, W2, dinv, bufA, n);   // h1w' = dinv * h1W2
    gather_k<<<nb64, 256, 0, stream>>>(bufA, rowptr, esrc, dinv, b2, bufB, n);
    // bufB = h2 (relu'd)

    // ---- node CSR (by dict) for pooling ----
    hipMemsetAsync(tmp, 0, (size_t)n * sizeof(int), stream);
    hist_k<<<nb, 256, 0, stream>>>(dict, tmp, n);
    scan_pass1_k<<<NBS, SCAN_T, 0, stream>>>(tmp, bsum, n);
    scan_pass2_k<<<1, SCAN_T, 0, stream>>>(bsum, NBS, rowptr + n, n);
    scan_pass3_k<<<NBS, SCAN_T, 0, stream>>>(tmp, bsum, rowptr, nullptr, n);
    build_nodes_k<<<nb, 256, 0, stream>>>(dict, tmp, esrc, n);       // esrc = nodelist

    // ---- pool (gather) -> z in bufA ----
    gatherpool_k<<<nb64, 256, 0, stream>>>(bufB, rowptr, esrc, bufA, n);
  } else {
    // ---- fallback: atomic path (bufA, bufB, dinv, cnt) ----
    float* cnt = dinv + n;
    fill_deg_k<<<nb, 256, 0, stream>>>(dinv, n);
    accum_deg_k<<<(e + 255) / 256, 256, 0, stream>>>(dst, dinv, e);
    dinv_k<<<nb, 256, 0, stream>>>(dinv, n);

    gemm128_v3<<<gemb, 256, 0, stream>>>(x, W1, nullptr, bufA, n);
    init_h_k<<<nb32, 256, 0, stream>>>(bufA, b1, dinv, bufB, n);
    scatter_k<<<(int)(((size_t)e * 32 + 255) / 256), 256, 0, stream>>>(bufA, bufB, dinv, src, dst, e);
    relu_k<<<nb32, 256, 0, stream>>>((float4*)bufB, n * 32);

    gemm128_v3<<<gemb, 256, 0, stream>>>(bufB, W2, nullptr, bufA, n);
    init_h_k<<<nb32, 256, 0, stream>>>(bufA, b2, dinv, bufB, n);
    scatter_k<<<(int)(((size_t)e * 32 + 255) / 256), 256, 0, stream>>>(bufA, bufB, dinv, src, dst, e);
    relu_k<<<nb32, 256, 0, stream>>>((float4*)bufB, n * 32);

    hipMemsetAsync(bufA, 0, nf * sizeof(float), stream);
    hipMemsetAsync(cnt, 0, (size_t)n * sizeof(float), stream);
    pool_accum_k<<<nb32, 256, 0, stream>>>(bufB, dict, bufA, cnt, n);
    pool_div_k<<<nb32, 256, 0, stream>>>(bufA, cnt, n);
  }

  // ---- decode ----
  decode_k<<<(int)(((size_t)2 * ep * 32 + 255) / 256), 256, 0, stream>>>(
      bufA, pe, ne, (float*)d_out, ep);
}

// Round 6
// 432.833 us; speedup vs baseline: 13.8740x; 1.2584x over previous
//
#include <hip/hip_runtime.h>
#include <hip/hip_fp16.h>

#define HH 128   // hidden size (both layers, and F_IN)
#define SCAN_T 256
#define SCAN_C 2048   // elements per scan block (256 threads x 8)
#define PCHUNK 16384  // edges per partition block

// ================= node-CSR build (for pooling): histogram / scan / fill =================

__global__ void hist_k(const int* __restrict__ key, int* __restrict__ hist, int e) {
  int i = blockIdx.x * blockDim.x + threadIdx.x;
  if (i < e) atomicAdd(&hist[key[i]], 1);
}

__global__ __launch_bounds__(SCAN_T) void scan_pass1_k(const int* __restrict__ hist,
                                                       int* __restrict__ bsum, int n) {
  __shared__ int lds[SCAN_T];
  int base = blockIdx.x * SCAN_C + threadIdx.x * 8;
  int s = 0;
  #pragma unroll
  for (int k = 0; k < 8; ++k) { int i = base + k; if (i < n) s += hist[i]; }
  lds[threadIdx.x] = s;
  __syncthreads();
  for (int off = 128; off > 0; off >>= 1) {
    if (threadIdx.x < off) lds[threadIdx.x] += lds[threadIdx.x + off];
    __syncthreads();
  }
  if (threadIdx.x == 0) bsum[blockIdx.x] = lds[0];
}

__global__ __launch_bounds__(SCAN_T) void scan_pass2_k(int* __restrict__ bsum, int nb,
                                                       int* __restrict__ rowptr_n, int total) {
  __shared__ int lds[SCAN_T];
  int v = (threadIdx.x < nb) ? bsum[threadIdx.x] : 0;
  lds[threadIdx.x] = v;
  __syncthreads();
  for (int off = 1; off < SCAN_T; off <<= 1) {
    int t = (threadIdx.x >= off) ? lds[threadIdx.x - off] : 0;
    __syncthreads();
    lds[threadIdx.x] += t;
    __syncthreads();
  }
  if (threadIdx.x < nb) bsum[threadIdx.x] = (threadIdx.x == 0) ? 0 : lds[threadIdx.x - 1];
  if (threadIdx.x == 0) *rowptr_n = total;
}

__global__ __launch_bounds__(SCAN_T) void scan_pass3_k(int* __restrict__ tmp,
                                                       const int* __restrict__ bsum,
                                                       int* __restrict__ rowptr,
                                                       float* __restrict__ dinv, int n) {
  __shared__ int lds[SCAN_T];
  int base = blockIdx.x * SCAN_C + threadIdx.x * 8;
  int v[8]; int s = 0;
  #pragma unroll
  for (int k = 0; k < 8; ++k) { int i = base + k; v[k] = (i < n) ? tmp[i] : 0; s += v[k]; }
  lds[threadIdx.x] = s;
  __syncthreads();
  for (int off = 1; off < SCAN_T; off <<= 1) {
    int t = (threadIdx.x >= off) ? lds[threadIdx.x - off] : 0;
    __syncthreads();
    lds[threadIdx.x] += t;
    __syncthreads();
  }
  int run = bsum[blockIdx.x] + ((threadIdx.x == 0) ? 0 : lds[threadIdx.x - 1]);
  #pragma unroll
  for (int k = 0; k < 8; ++k) {
    int i = base + k;
    if (i < n) {
      rowptr[i] = run;
      tmp[i] = run;
      if (dinv) dinv[i] = rsqrtf((float)v[k] + 1.0f);
      run += v[k];
    }
  }
}

__global__ void build_nodes_k(const int* __restrict__ dict, int* __restrict__ cursor,
                              int* __restrict__ nodelist, int n) {
  int i = blockIdx.x * blockDim.x + threadIdx.x;
  if (i < n) {
    int pos = atomicAdd(&cursor[dict[i]], 1);
    nodelist[pos] = i;
  }
}

// ================= edge-CSR build: bucketed 2-phase counting sort =================
// bucket = dst >> 8 (256 dst per bucket).  nbkt <= 512 required.

__global__ __launch_bounds__(256) void part_count_k(const int* __restrict__ dst, int e,
                                                    int nbkt, int nblk,
                                                    int* __restrict__ gcnt,
                                                    int* __restrict__ blkoff) {
  __shared__ int h[512];
  for (int i = threadIdx.x; i < nbkt; i += 256) h[i] = 0;
  __syncthreads();
  int start = blockIdx.x * PCHUNK;
  int cnt = e - start; if (cnt > PCHUNK) cnt = PCHUNK;
  for (int i = threadIdx.x; i < cnt; i += 256)
    atomicAdd(&h[dst[start + i] >> 8], 1);
  __syncthreads();
  for (int i = threadIdx.x; i < nbkt; i += 256) {
    int c = h[i];
    if (c) blkoff[(size_t)i * nblk + blockIdx.x] = atomicAdd(&gcnt[i], c);
  }
}

__global__ __launch_bounds__(512) void scan_bkt_k(const int* __restrict__ gcnt,
                                                  int* __restrict__ bktbase, int nbkt, int e) {
  __shared__ int sc[512];
  int tid = threadIdx.x;
  int v = (tid < nbkt) ? gcnt[tid] : 0;
  sc[tid] = v;
  __syncthreads();
  for (int off = 1; off < 512; off <<= 1) {
    int t = (tid >= off) ? sc[tid - off] : 0;
    __syncthreads();
    sc[tid] += t;
    __syncthreads();
  }
  if (tid < nbkt) bktbase[tid] = sc[tid] - v;
  if (tid == 0) bktbase[nbkt] = e;
}

__global__ __launch_bounds__(256) void part_scatter_k(const int* __restrict__ src,
                                                      const int* __restrict__ dst, int e,
                                                      int nbkt, int nblk,
                                                      const int* __restrict__ bktbase,
                                                      const int* __restrict__ blkoff,
                                                      int2* __restrict__ part) {
  __shared__ int cur[512];
  for (int i = threadIdx.x; i < nbkt; i += 256)
    cur[i] = bktbase[i] + blkoff[(size_t)i * nblk + blockIdx.x];
  __syncthreads();
  int start = blockIdx.x * PCHUNK;
  int cnt = e - start; if (cnt > PCHUNK) cnt = PCHUNK;
  for (int i = threadIdx.x; i < cnt; i += 256) {
    int d = dst[start + i], s = src[start + i];
    int pos = atomicAdd(&cur[d >> 8], 1);
    part[pos] = make_int2(s, d);
  }
}

__global__ __launch_bounds__(256) void bucket_csr_k(const int2* __restrict__ part,
                                                    const int* __restrict__ bktbase,
                                                    int* __restrict__ rowptr,
                                                    float* __restrict__ dinv,
                                                    int* __restrict__ esrc,
                                                    int n, int e, int nbkt) {
  __shared__ int hist[256];
  __shared__ int sc[256];
  __shared__ int cur[256];
  int tid = threadIdx.x;
  int b = blockIdx.x;
  int dstbase = b << 8;
  int nloc = n - dstbase; if (nloc > 256) nloc = 256;
  int beg = bktbase[b], bend = bktbase[b + 1];

  hist[tid] = 0;
  __syncthreads();
  for (int j = beg + tid; j < bend; j += 256)
    atomicAdd(&hist[part[j].y & 255], 1);
  __syncthreads();
  int v = hist[tid];
  sc[tid] = v;
  __syncthreads();
  for (int off = 1; off < 256; off <<= 1) {
    int t = (tid >= off) ? sc[tid - off] : 0;
    __syncthreads();
    sc[tid] += t;
    __syncthreads();
  }
  int excl = sc[tid] - v;
  if (tid < nloc) {
    rowptr[dstbase + tid] = beg + excl;
    cur[tid] = beg + excl;
    dinv[dstbase + tid] = rsqrtf((float)v + 1.0f);
  }
  __syncthreads();
  for (int j = beg + tid; j < bend; j += 256) {
    int2 p = part[j];
    int pos = atomicAdd(&cur[p.y & 255], 1);
    esrc[pos] = p.x;
  }
  if (b == nbkt - 1 && tid == 0) rowptr[n] = e;
}

// ========== GEMM v3: LDS-staged A tile (64 rows), thread = quarter row ==========
// OUT16: write scale(i)*(A@W) as fp16 (half2-packed); else fp32.
template <bool OUT16>
__global__ __launch_bounds__(256) void gemm128_v3(const float* __restrict__ A,
                                                  const float* __restrict__ W,
                                                  const float* __restrict__ dscale,
                                                  void* __restrict__ out, int n) {
  __shared__ float As[64][129];
  const int tid = threadIdx.x;
  const int rbase = blockIdx.x * 64;

  const int vrows = (n - rbase) < 64 ? (n - rbase) : 64;
  const int maxf4 = vrows * 32;
  const float4* Ag = (const float4*)(A + (size_t)rbase * HH);
  #pragma unroll
  for (int j = 0; j < 8; ++j) {
    int f = tid + 256 * j;
    int r = f >> 5, c4 = f & 31;
    float4 v = (f < maxf4) ? Ag[f] : make_float4(0.f, 0.f, 0.f, 0.f);
    As[r][c4 * 4 + 0] = v.x;
    As[r][c4 * 4 + 1] = v.y;
    As[r][c4 * 4 + 2] = v.z;
    As[r][c4 * 4 + 3] = v.w;
  }
  __syncthreads();

  const int r = tid & 63;
  const int q = __builtin_amdgcn_readfirstlane(tid >> 6);
  const float* Asr = &As[r][0];
  const float* Wq = W + q * 32;

  float4 acc[8];
  #pragma unroll
  for (int c = 0; c < 8; ++c) acc[c] = make_float4(0.f, 0.f, 0.f, 0.f);

  #pragma unroll 4
  for (int k = 0; k < HH; ++k) {
    float a = Asr[k];
    const float4* Wr = (const float4*)(Wq + (size_t)k * HH);
    #pragma unroll
    for (int c = 0; c < 8; ++c) {
      float4 w = Wr[c];
      acc[c].x += a * w.x; acc[c].y += a * w.y;
      acc[c].z += a * w.z; acc[c].w += a * w.w;
    }
  }

  int row = rbase + r;
  if (row < n) {
    float s = dscale ? dscale[row] : 1.0f;
    if (OUT16) {
      uint2* o = (uint2*)((__half*)out + (size_t)row * HH) + q * 8;
      #pragma unroll
      for (int c = 0; c < 8; ++c) {
        __half2 h0 = __float22half2_rn(make_float2(acc[c].x * s, acc[c].y * s));
        __half2 h1 = __float22half2_rn(make_float2(acc[c].z * s, acc[c].w * s));
        uint2 u;
        u.x = *reinterpret_cast<unsigned*>(&h0);
        u.y = *reinterpret_cast<unsigned*>(&h1);
        o[c] = u;
      }
    } else {
      float4* o = (float4*)((float*)out + (size_t)row * HH + q * 32);
      #pragma unroll
      for (int c = 0; c < 8; ++c) {
        acc[c].x *= s; acc[c].y *= s; acc[c].z *= s; acc[c].w *= s;
        o[c] = acc[c];
      }
    }
  }
}

// ==== gather conv (fp16 messages): h[d]=relu(b+dinv[d]*(self'+sum xw16[s])), h fp32 ====
// 2 edges per wave; each lane reads 4 cols (uint2 = 4 halves).
__global__ __launch_bounds__(256) void gather16_k(const __half* __restrict__ xw16,
                                                  const int* __restrict__ rowptr,
                                                  const int* __restrict__ esrc,
                                                  const float* __restrict__ dinv,
                                                  const float* __restrict__ bias,
                                                  float* __restrict__ h, int n) {
  int wid = (int)((blockIdx.x * (size_t)blockDim.x + threadIdx.x) >> 6);
  int lane = threadIdx.x & 63;
  if (wid >= n) return;
  int beg = rowptr[wid], end = rowptr[wid + 1];
  int half = lane >> 5, l32 = lane & 31;
  const uint2* base = (const uint2*)xw16 + l32;   // row = 32 uint2
  float4 acc = make_float4(0.f, 0.f, 0.f, 0.f);

  for (int j0 = beg; j0 < end; j0 += 64) {
    int myj = j0 + lane;
    int sv = (myj < end) ? esrc[myj] : 0;
    int cnt = end - j0; if (cnt > 64) cnt = 64;
    int k = 0;
    for (; k + 8 <= cnt; k += 8) {
      #pragma unroll
      for (int p = 0; p < 4; ++p) {
        int sa = __builtin_amdgcn_readlane(sv, k + 2 * p);
        int sb = __builtin_amdgcn_readlane(sv, k + 2 * p + 1);
        unsigned off = (unsigned)(half ? sb : sa) << 5;
        uint2 u = base[off];
        float2 f0 = __half22float2(*reinterpret_cast<__half2*>(&u.x));
        float2 f1 = __half22float2(*reinterpret_cast<__half2*>(&u.y));
        acc.x += f0.x; acc.y += f0.y; acc.z += f1.x; acc.w += f1.y;
      }
    }
    for (; k + 2 <= cnt; k += 2) {
      int sa = __builtin_amdgcn_readlane(sv, k);
      int sb = __builtin_amdgcn_readlane(sv, k + 1);
      unsigned off = (unsigned)(half ? sb : sa) << 5;
      uint2 u = base[off];
      float2 f0 = __half22float2(*reinterpret_cast<__half2*>(&u.x));
      float2 f1 = __half22float2(*reinterpret_cast<__half2*>(&u.y));
      acc.x += f0.x; acc.y += f0.y; acc.z += f1.x; acc.w += f1.y;
    }
    if (k < cnt) {
      int sa = __builtin_amdgcn_readlane(sv, k);
      if (half == 0) {
        uint2 u = base[(unsigned)sa << 5];
        float2 f0 = __half22float2(*reinterpret_cast<__half2*>(&u.x));
        float2 f1 = __half22float2(*reinterpret_cast<__half2*>(&u.y));
        acc.x += f0.x; acc.y += f0.y; acc.z += f1.x; acc.w += f1.y;
      }
    }
  }
  acc.x += __shfl_xor(acc.x, 32);
  acc.y += __shfl_xor(acc.y, 32);
  acc.z += __shfl_xor(acc.z, 32);
  acc.w += __shfl_xor(acc.w, 32);
  if (half == 0) {
    uint2 u = base[(unsigned)wid << 5];
    float2 s0 = __half22float2(*reinterpret_cast<__half2*>(&u.x));
    float2 s1 = __half22float2(*reinterpret_cast<__half2*>(&u.y));
    float di = dinv[wid];
    float4 bb = ((const float4*)bias)[l32];
    float4 o;
    o.x = fmaxf(bb.x + di * (acc.x + s0.x), 0.f);
    o.y = fmaxf(bb.y + di * (acc.y + s0.y), 0.f);
    o.z = fmaxf(bb.z + di * (acc.z + s1.x), 0.f);
    o.w = fmaxf(bb.w + di * (acc.w + s1.y), 0.f);
    ((float4*)h)[((size_t)wid << 5) + l32] = o;
  }
}

// ====== fused pool+decode: logits[e] = dot(mean(h2[Ga]), mean(h2[Gb])) over 128 ======
__global__ __launch_bounds__(256) void decode_fused_k(const float* __restrict__ h2,
                                                      const int* __restrict__ rowptr,
                                                      const int* __restrict__ nodelist,
                                                      const int* __restrict__ pos,
                                                      const int* __restrict__ neg,
                                                      float* __restrict__ out, int ep) {
  int gid = blockIdx.x * blockDim.x + threadIdx.x;
  int edge = gid >> 5, l32 = gid & 31;
  if (edge >= 2 * ep) return;
  int a, b;
  if (edge < ep) { a = pos[edge];      b = pos[ep + edge]; }
  else           { a = neg[edge - ep]; b = neg[edge]; }
  const float4* h4 = (const float4*)h2 + l32;
  int abeg = rowptr[a], aend = rowptr[a + 1];
  int bbeg = rowptr[b], bend = rowptr[b + 1];

  float4 za = make_float4(0.f, 0.f, 0.f, 0.f);
  for (int j = abeg; j < aend; ++j) {
    int m = nodelist[j];
    float4 v = h4[(unsigned)m << 5];
    za.x += v.x; za.y += v.y; za.z += v.z; za.w += v.w;
  }
  float4 zb = make_float4(0.f, 0.f, 0.f, 0.f);
  for (int j = bbeg; j < bend; ++j) {
    int m = nodelist[j];
    float4 v = h4[(unsigned)m << 5];
    zb.x += v.x; zb.y += v.y; zb.z += v.z; zb.w += v.w;
  }
  float inv = 1.0f / (fmaxf((float)(aend - abeg), 1.0f) * fmaxf((float)(bend - bbeg), 1.0f));
  float dot = (za.x * zb.x + za.y * zb.y + za.z * zb.z + za.w * zb.w) * inv;
  #pragma unroll
  for (int off = 16; off > 0; off >>= 1) dot += __shfl_xor(dot, off);
  if (l32 == 0) out[edge] = dot;
}

// ================= fallback path (small ws): atomic version =================
__global__ void fill_deg_k(float* __restrict__ deg, int n) {
  int i = blockIdx.x * blockDim.x + threadIdx.x;
  if (i < n) deg[i] = 1.0f;
}
__global__ void accum_deg_k(const int* __restrict__ dst, float* __restrict__ deg, int e) {
  int i = blockIdx.x * blockDim.x + threadIdx.x;
  if (i < e) atomicAdd(&deg[dst[i]], 1.0f);
}
__global__ void dinv_k(float* __restrict__ deg, int n) {
  int i = blockIdx.x * blockDim.x + threadIdx.x;
  if (i < n) deg[i] = rsqrtf(deg[i]);
}
__global__ void init_h_k(const float* __restrict__ xw, const float* __restrict__ bias,
                         const float* __restrict__ dinv, float* __restrict__ h, int n) {
  int gid = blockIdx.x * blockDim.x + threadIdx.x;
  int node = gid >> 5, c4 = gid & 31;
  if (node >= n) return;
  float di = dinv[node];
  float nm = di * di;
  float4 v = ((const float4*)(xw + (size_t)node * HH))[c4];
  float4 b = ((const float4*)bias)[c4];
  ((float4*)(h + (size_t)node * HH))[c4] =
      make_float4(b.x + nm * v.x, b.y + nm * v.y, b.z + nm * v.z, b.w + nm * v.w);
}
__global__ void scatter_k(const float* __restrict__ xw, float* __restrict__ h,
                          const float* __restrict__ dinv, const int* __restrict__ src,
                          const int* __restrict__ dst, int e) {
  int gid = blockIdx.x * blockDim.x + threadIdx.x;
  int edge = gid >> 5, lane = gid & 31;
  if (edge >= e) return;
  int s = src[edge], d = dst[edge];
  float norm = dinv[s] * dinv[d];
  float4 v = ((const float4*)(xw + (size_t)s * HH))[lane];
  float* o = h + (size_t)d * HH + lane * 4;
  atomicAdd(o + 0, norm * v.x);
  atomicAdd(o + 1, norm * v.y);
  atomicAdd(o + 2, norm * v.z);
  atomicAdd(o + 3, norm * v.w);
}
__global__ void relu_k(float4* __restrict__ h, int n4) {
  int i = blockIdx.x * blockDim.x + threadIdx.x;
  if (i < n4) {
    float4 v = h[i];
    v.x = fmaxf(v.x, 0.f); v.y = fmaxf(v.y, 0.f);
    v.z = fmaxf(v.z, 0.f); v.w = fmaxf(v.w, 0.f);
    h[i] = v;
  }
}
__global__ void pool_accum_k(const float* __restrict__ h, const int* __restrict__ dict,
                             float* __restrict__ z, float* __restrict__ cnt, int n) {
  int gid = blockIdx.x * blockDim.x + threadIdx.x;
  int node = gid >> 5, lane = gid & 31;
  if (node >= n) return;
  int d = dict[node];
  float4 v = ((const float4*)(h + (size_t)node * HH))[lane];
  float* o = z + (size_t)d * HH + lane * 4;
  atomicAdd(o + 0, v.x); atomicAdd(o + 1, v.y);
  atomicAdd(o + 2, v.z); atomicAdd(o + 3, v.w);
  if (lane == 0) atomicAdd(&cnt[d], 1.0f);
}
__global__ void pool_div_k(float* __restrict__ z, const float* __restrict__ cnt, int n) {
  int gid = blockIdx.x * blockDim.x + threadIdx.x;
  int node = gid >> 5, lane = gid & 31;
  if (node >= n) return;
  float inv = 1.0f / fmaxf(cnt[node], 1.0f);
  float4* p = (float4*)(z + (size_t)node * HH) + lane;
  float4 v = *p;
  v.x *= inv; v.y *= inv; v.z *= inv; v.w *= inv;
  *p = v;
}
__global__ void decode_k(const float* __restrict__ z, const int* __restrict__ pos,
                         const int* __restrict__ neg, float* __restrict__ out, int ep) {
  int gid = blockIdx.x * blockDim.x + threadIdx.x;
  int edge = gid >> 5, lane = gid & 31;
  if (edge >= 2 * ep) return;
  int a, b;
  if (edge < ep) { a = pos[edge];      b = pos[ep + edge]; }
  else           { a = neg[edge - ep]; b = neg[edge]; }
  const float4* za = (const float4*)(z + (size_t)a * HH);
  const float4* zb = (const float4*)(z + (size_t)b * HH);
  float4 va = za[lane], vb = zb[lane];
  float dot = va.x * vb.x + va.y * vb.y + va.z * vb.z + va.w * vb.w;
  #pragma unroll
  for (int off = 16; off > 0; off >>= 1) dot += __shfl_xor(dot, off);
  if (lane == 0) out[edge] = dot;
}

// ================= host launch =================
extern "C" void kernel_launch(void* const* d_in, const int* in_sizes, int n_in,
                              void* d_out, int out_size, void* d_ws, size_t ws_size,
                              hipStream_t stream) {
  const float* x  = (const float*)d_in[0];
  const float* W1 = (const float*)d_in[1];
  const float* b1 = (const float*)d_in[2];
  const float* W2 = (const float*)d_in[3];
  const float* b2 = (const float*)d_in[4];
  const int* ei   = (const int*)d_in[5];
  const int* dict = (const int*)d_in[6];
  const int* pe   = (const int*)d_in[7];
  const int* ne   = (const int*)d_in[8];

  const int n  = in_sizes[0] / HH;   // 100000
  const int e  = in_sizes[5] / 2;    // 1.6M
  const int ep = in_sizes[7] / 2;    // 200000
  const int* src = ei;
  const int* dst = ei + e;

  const size_t nf = (size_t)n * HH;
  const int nbkt = (n + 255) >> 8;                 // 391
  const int nblk = (e + PCHUNK - 1) / PCHUNK;      // 98

  // fast-path ws layout:
  //   bufF  : nf floats      (part alias -> h1 -> h2)
  //   xw16  : nf halves      (blkoff alias -> xw' conv1 -> xw' conv2)
  //   dinv[n], rowptr[n+1], tmp[n], esrc[e], bsum[256], gcnt[nbkt], bktbase[nbkt+1]
  float*  p0     = (float*)d_ws;
  float*  bufF   = p0;
  __half* xw16   = (__half*)(p0 + nf);
  float*  dinv   = p0 + nf + nf / 2;
  int*    rowptr = (int*)(dinv + n);
  int*    tmp    = rowptr + (n + 1);
  int*    esrc   = tmp + n;
  int*    bsum   = esrc + e;
  int*    gcnt   = bsum + 256;
  int*    bktbase = gcnt + nbkt;
  size_t need = (nf + nf / 2 + n) * sizeof(float) +
                (size_t)(3 * n + 1 + e + 256 + 2 * nbkt + 1) * sizeof(int);

  int2* part   = (int2*)bufF;       // e pairs (12.8 MB) <= nf floats
  int*  blkoff = (int*)xw16;        // nbkt*nblk ints (~153 KB) <= nf halves

  const int nb    = (n + 255) / 256;
  const int nb32  = (int)(((size_t)n * 32 + 255) / 256);
  const int nb64  = (int)(((size_t)n * 64 + 255) / 256);
  const int gemb  = (n + 63) / 64;
  const int NBS   = (n + SCAN_C - 1) / SCAN_C;
  const int deb   = (int)(((size_t)2 * ep * 32 + 255) / 256);

  bool fast = (ws_size >= need) && (nbkt <= 512) &&
              ((size_t)nbkt * nblk * 2 <= nf) && ((size_t)e * 2 <= nf);

  if (fast) {
    // ---- edge CSR (by dst) + dinv: bucketed 2-phase sort ----
    hipMemsetAsync(gcnt, 0, (size_t)nbkt * sizeof(int), stream);
    part_count_k<<<nblk, 256, 0, stream>>>(dst, e, nbkt, nblk, gcnt, blkoff);
    scan_bkt_k<<<1, 512, 0, stream>>>(gcnt, bktbase, nbkt, e);
    part_scatter_k<<<nblk, 256, 0, stream>>>(src, dst, e, nbkt, nblk, bktbase, blkoff, part);
    bucket_csr_k<<<nbkt, 256, 0, stream>>>(part, bktbase, rowptr, dinv, esrc, n, e, nbkt);

    // ---- conv1: xw16 = fp16(dinv * x@W1);  h1(fp32, bufF) ----
    gemm128_v3<true><<<gemb, 256, 0, stream>>>(x, W1, dinv, xw16, n);
    gather16_k<<<nb64, 256, 0, stream>>>(xw16, rowptr, esrc, dinv, b1, bufF, n);
    // ---- conv2: xw16 = fp16(dinv * h1@W2);  h2(fp32, bufF overwrite after read) ----
    gemm128_v3<true><<<gemb, 256, 0, stream>>>(bufF, W2, dinv, xw16, n);
    gather16_k<<<nb64, 256, 0, stream>>>(xw16, rowptr, esrc, dinv, b2, bufF, n);
    // bufF = h2 (relu'd, fp32)

    // ---- node CSR (by dict) for pooling ----
    hipMemsetAsync(tmp, 0, (size_t)n * sizeof(int), stream);
    hist_k<<<nb, 256, 0, stream>>>(dict, tmp, n);
    scan_pass1_k<<<NBS, SCAN_T, 0, stream>>>(tmp, bsum, n);
    scan_pass2_k<<<1, SCAN_T, 0, stream>>>(bsum, NBS, rowptr + n, n);
    scan_pass3_k<<<NBS, SCAN_T, 0, stream>>>(tmp, bsum, rowptr, nullptr, n);
    build_nodes_k<<<nb, 256, 0, stream>>>(dict, tmp, esrc, n);       // esrc = nodelist

    // ---- fused pool + decode ----
    decode_fused_k<<<deb, 256, 0, stream>>>(bufF, rowptr, esrc, pe, ne, (float*)d_out, ep);
  } else {
    // ---- fallback: atomic path (bufA, bufB, dinv2, cnt) ----
    float* bufA  = (float*)d_ws;
    float* bufB  = bufA + nf;
    float* dinv2 = bufB + nf;
    float* cnt   = dinv2 + n;
    fill_deg_k<<<nb, 256, 0, stream>>>(dinv2, n);
    accum_deg_k<<<(e + 255) / 256, 256, 0, stream>>>(dst, dinv2, e);
    dinv_k<<<nb, 256, 0, stream>>>(dinv2, n);

    gemm128_v3<false><<<gemb, 256, 0, stream>>>(x, W1, nullptr, bufA, n);
    init_h_k<<<nb32, 256, 0, stream>>>(bufA, b1, dinv2, bufB, n);
    scatter_k<<<(int)(((size_t)e * 32 + 255) / 256), 256, 0, stream>>>(bufA, bufB, dinv2, src, dst, e);
    relu_k<<<nb32, 256, 0, stream>>>((float4*)bufB, n * 32);

    gemm128_v3<false><<<gemb, 256, 0, stream>>>(bufB, W2, nullptr, bufA, n);
    init_h_k<<<nb32, 256, 0, stream>>>(bufA, b2, dinv2, bufB, n);
    scatter_k<<<(int)(((size_t)e * 32 + 255) / 256), 256, 0, stream>>>(bufA, bufB, dinv2, src, dst, e);
    relu_k<<<nb32, 256, 0, stream>>>((float4*)bufB, n * 32);

    hipMemsetAsync(bufA, 0, nf * sizeof(float), stream);
    hipMemsetAsync(cnt, 0, (size_t)n * sizeof(float), stream);
    pool_accum_k<<<nb32, 256, 0, stream>>>(bufB, dict, bufA, cnt, n);
    pool_div_k<<<nb32, 256, 0, stream>>>(bufA, cnt, n);
    decode_k<<<deb, 256, 0, stream>>>(bufA, pe, ne, (float*)d_out, ep);
  }
}

// Round 7
// 413.636 us; speedup vs baseline: 14.5179x; 1.0464x over previous
//
#include <hip/hip_runtime.h>
#include <hip/hip_fp16.h>

#define HH 128   // hidden size (both layers, and F_IN)
#define SCAN_T 256
#define SCAN_C 2048   // elements per scan block (256 threads x 8)
#define PCHUNK 16384  // edges per partition block

// ================= node-CSR build (for pooling): histogram / scan / fill =================

__global__ void hist_k(const int* __restrict__ key, int* __restrict__ hist, int e) {
  int i = blockIdx.x * blockDim.x + threadIdx.x;
  if (i < e) atomicAdd(&hist[key[i]], 1);
}

__global__ __launch_bounds__(SCAN_T) void scan_pass1_k(const int* __restrict__ hist,
                                                       int* __restrict__ bsum, int n) {
  __shared__ int lds[SCAN_T];
  int base = blockIdx.x * SCAN_C + threadIdx.x * 8;
  int s = 0;
  #pragma unroll
  for (int k = 0; k < 8; ++k) { int i = base + k; if (i < n) s += hist[i]; }
  lds[threadIdx.x] = s;
  __syncthreads();
  for (int off = 128; off > 0; off >>= 1) {
    if (threadIdx.x < off) lds[threadIdx.x] += lds[threadIdx.x + off];
    __syncthreads();
  }
  if (threadIdx.x == 0) bsum[blockIdx.x] = lds[0];
}

__global__ __launch_bounds__(SCAN_T) void scan_pass2_k(int* __restrict__ bsum, int nb,
                                                       int* __restrict__ rowptr_n, int total) {
  __shared__ int lds[SCAN_T];
  int v = (threadIdx.x < nb) ? bsum[threadIdx.x] : 0;
  lds[threadIdx.x] = v;
  __syncthreads();
  for (int off = 1; off < SCAN_T; off <<= 1) {
    int t = (threadIdx.x >= off) ? lds[threadIdx.x - off] : 0;
    __syncthreads();
    lds[threadIdx.x] += t;
    __syncthreads();
  }
  if (threadIdx.x < nb) bsum[threadIdx.x] = (threadIdx.x == 0) ? 0 : lds[threadIdx.x - 1];
  if (threadIdx.x == 0) *rowptr_n = total;
}

__global__ __launch_bounds__(SCAN_T) void scan_pass3_k(int* __restrict__ tmp,
                                                       const int* __restrict__ bsum,
                                                       int* __restrict__ rowptr,
                                                       float* __restrict__ dinv, int n) {
  __shared__ int lds[SCAN_T];
  int base = blockIdx.x * SCAN_C + threadIdx.x * 8;
  int v[8]; int s = 0;
  #pragma unroll
  for (int k = 0; k < 8; ++k) { int i = base + k; v[k] = (i < n) ? tmp[i] : 0; s += v[k]; }
  lds[threadIdx.x] = s;
  __syncthreads();
  for (int off = 1; off < SCAN_T; off <<= 1) {
    int t = (threadIdx.x >= off) ? lds[threadIdx.x - off] : 0;
    __syncthreads();
    lds[threadIdx.x] += t;
    __syncthreads();
  }
  int run = bsum[blockIdx.x] + ((threadIdx.x == 0) ? 0 : lds[threadIdx.x - 1]);
  #pragma unroll
  for (int k = 0; k < 8; ++k) {
    int i = base + k;
    if (i < n) {
      rowptr[i] = run;
      tmp[i] = run;
      if (dinv) dinv[i] = rsqrtf((float)v[k] + 1.0f);
      run += v[k];
    }
  }
}

__global__ void build_nodes_k(const int* __restrict__ dict, int* __restrict__ cursor,
                              int* __restrict__ nodelist, int n) {
  int i = blockIdx.x * blockDim.x + threadIdx.x;
  if (i < n) {
    int pos = atomicAdd(&cursor[dict[i]], 1);
    nodelist[pos] = i;
  }
}

// ================= edge-CSR build: bucketed 2-phase counting sort =================
// bucket = dst >> 8 (256 dst per bucket).  nbkt <= 512 required.

__global__ __launch_bounds__(256) void part_count_k(const int* __restrict__ dst, int e,
                                                    int nbkt, int nblk,
                                                    int* __restrict__ gcnt,
                                                    int* __restrict__ blkoff) {
  __shared__ int h[512];
  for (int i = threadIdx.x; i < nbkt; i += 256) h[i] = 0;
  __syncthreads();
  int start = blockIdx.x * PCHUNK;
  int cnt = e - start; if (cnt > PCHUNK) cnt = PCHUNK;
  for (int i = threadIdx.x; i < cnt; i += 256)
    atomicAdd(&h[dst[start + i] >> 8], 1);
  __syncthreads();
  for (int i = threadIdx.x; i < nbkt; i += 256) {
    int c = h[i];
    if (c) blkoff[(size_t)i * nblk + blockIdx.x] = atomicAdd(&gcnt[i], c);
  }
}

__global__ __launch_bounds__(512) void scan_bkt_k(const int* __restrict__ gcnt,
                                                  int* __restrict__ bktbase, int nbkt, int e) {
  __shared__ int sc[512];
  int tid = threadIdx.x;
  int v = (tid < nbkt) ? gcnt[tid] : 0;
  sc[tid] = v;
  __syncthreads();
  for (int off = 1; off < 512; off <<= 1) {
    int t = (tid >= off) ? sc[tid - off] : 0;
    __syncthreads();
    sc[tid] += t;
    __syncthreads();
  }
  if (tid < nbkt) bktbase[tid] = sc[tid] - v;
  if (tid == 0) bktbase[nbkt] = e;
}

__global__ __launch_bounds__(256) void part_scatter_k(const int* __restrict__ src,
                                                      const int* __restrict__ dst, int e,
                                                      int nbkt, int nblk,
                                                      const int* __restrict__ bktbase,
                                                      const int* __restrict__ blkoff,
                                                      int2* __restrict__ part) {
  __shared__ int cur[512];
  for (int i = threadIdx.x; i < nbkt; i += 256)
    cur[i] = bktbase[i] + blkoff[(size_t)i * nblk + blockIdx.x];
  __syncthreads();
  int start = blockIdx.x * PCHUNK;
  int cnt = e - start; if (cnt > PCHUNK) cnt = PCHUNK;
  for (int i = threadIdx.x; i < cnt; i += 256) {
    int d = dst[start + i], s = src[start + i];
    int pos = atomicAdd(&cur[d >> 8], 1);
    part[pos] = make_int2(s, d);
  }
}

__global__ __launch_bounds__(256) void bucket_csr_k(const int2* __restrict__ part,
                                                    const int* __restrict__ bktbase,
                                                    int* __restrict__ rowptr,
                                                    float* __restrict__ dinv,
                                                    int* __restrict__ esrc,
                                                    int n, int e, int nbkt) {
  __shared__ int hist[256];
  __shared__ int sc[256];
  __shared__ int cur[256];
  int tid = threadIdx.x;
  int b = blockIdx.x;
  int dstbase = b << 8;
  int nloc = n - dstbase; if (nloc > 256) nloc = 256;
  int beg = bktbase[b], bend = bktbase[b + 1];

  hist[tid] = 0;
  __syncthreads();
  for (int j = beg + tid; j < bend; j += 256)
    atomicAdd(&hist[part[j].y & 255], 1);
  __syncthreads();
  int v = hist[tid];
  sc[tid] = v;
  __syncthreads();
  for (int off = 1; off < 256; off <<= 1) {
    int t = (tid >= off) ? sc[tid - off] : 0;
    __syncthreads();
    sc[tid] += t;
    __syncthreads();
  }
  int excl = sc[tid] - v;
  if (tid < nloc) {
    rowptr[dstbase + tid] = beg + excl;
    cur[tid] = beg + excl;
    dinv[dstbase + tid] = rsqrtf((float)v + 1.0f);
  }
  __syncthreads();
  for (int j = beg + tid; j < bend; j += 256) {
    int2 p = part[j];
    int pos = atomicAdd(&cur[p.y & 255], 1);
    esrc[pos] = p.x;
  }
  if (b == nbkt - 1 && tid == 0) rowptr[n] = e;
}

// ========== GEMM v3: LDS-staged A tile (64 rows), thread = quarter row ==========
// OUT16: write scale(i)*(A@W) as fp16 (half2-packed); else fp32.
template <bool OUT16>
__global__ __launch_bounds__(256) void gemm128_v3(const float* __restrict__ A,
                                                  const float* __restrict__ W,
                                                  const float* __restrict__ dscale,
                                                  void* __restrict__ out, int n) {
  __shared__ float As[64][129];
  const int tid = threadIdx.x;
  const int rbase = blockIdx.x * 64;

  const int vrows = (n - rbase) < 64 ? (n - rbase) : 64;
  const int maxf4 = vrows * 32;
  const float4* Ag = (const float4*)(A + (size_t)rbase * HH);
  #pragma unroll
  for (int j = 0; j < 8; ++j) {
    int f = tid + 256 * j;
    int r = f >> 5, c4 = f & 31;
    float4 v = (f < maxf4) ? Ag[f] : make_float4(0.f, 0.f, 0.f, 0.f);
    As[r][c4 * 4 + 0] = v.x;
    As[r][c4 * 4 + 1] = v.y;
    As[r][c4 * 4 + 2] = v.z;
    As[r][c4 * 4 + 3] = v.w;
  }
  __syncthreads();

  const int r = tid & 63;
  const int q = __builtin_amdgcn_readfirstlane(tid >> 6);
  const float* Asr = &As[r][0];
  const float* Wq = W + q * 32;

  float4 acc[8];
  #pragma unroll
  for (int c = 0; c < 8; ++c) acc[c] = make_float4(0.f, 0.f, 0.f, 0.f);

  #pragma unroll 4
  for (int k = 0; k < HH; ++k) {
    float a = Asr[k];
    const float4* Wr = (const float4*)(Wq + (size_t)k * HH);
    #pragma unroll
    for (int c = 0; c < 8; ++c) {
      float4 w = Wr[c];
      acc[c].x += a * w.x; acc[c].y += a * w.y;
      acc[c].z += a * w.z; acc[c].w += a * w.w;
    }
  }

  int row = rbase + r;
  if (row < n) {
    float s = dscale ? dscale[row] : 1.0f;
    if (OUT16) {
      uint2* o = (uint2*)((__half*)out + (size_t)row * HH) + q * 8;
      #pragma unroll
      for (int c = 0; c < 8; ++c) {
        __half2 h0 = __float22half2_rn(make_float2(acc[c].x * s, acc[c].y * s));
        __half2 h1 = __float22half2_rn(make_float2(acc[c].z * s, acc[c].w * s));
        uint2 u;
        u.x = *reinterpret_cast<unsigned*>(&h0);
        u.y = *reinterpret_cast<unsigned*>(&h1);
        o[c] = u;
      }
    } else {
      float4* o = (float4*)((float*)out + (size_t)row * HH + q * 32);
      #pragma unroll
      for (int c = 0; c < 8; ++c) {
        acc[c].x *= s; acc[c].y *= s; acc[c].z *= s; acc[c].w *= s;
        o[c] = acc[c];
      }
    }
  }
}

// ==== gather conv (fp16 messages): h[d]=relu(b+dinv[d]*(self'+sum xw16[s])), h fp32 ====
__global__ __launch_bounds__(256) void gather16_k(const __half* __restrict__ xw16,
                                                  const int* __restrict__ rowptr,
                                                  const int* __restrict__ esrc,
                                                  const float* __restrict__ dinv,
                                                  const float* __restrict__ bias,
                                                  float* __restrict__ h, int n) {
  int wid = (int)((blockIdx.x * (size_t)blockDim.x + threadIdx.x) >> 6);
  int lane = threadIdx.x & 63;
  if (wid >= n) return;
  int beg = rowptr[wid], end = rowptr[wid + 1];
  int half = lane >> 5, l32 = lane & 31;
  const uint2* base = (const uint2*)xw16 + l32;   // row = 32 uint2
  float4 acc = make_float4(0.f, 0.f, 0.f, 0.f);

  for (int j0 = beg; j0 < end; j0 += 64) {
    int myj = j0 + lane;
    int sv = (myj < end) ? esrc[myj] : 0;
    int cnt = end - j0; if (cnt > 64) cnt = 64;
    int k = 0;
    for (; k + 8 <= cnt; k += 8) {
      #pragma unroll
      for (int p = 0; p < 4; ++p) {
        int sa = __builtin_amdgcn_readlane(sv, k + 2 * p);
        int sb = __builtin_amdgcn_readlane(sv, k + 2 * p + 1);
        unsigned off = (unsigned)(half ? sb : sa) << 5;
        uint2 u = base[off];
        float2 f0 = __half22float2(*reinterpret_cast<__half2*>(&u.x));
        float2 f1 = __half22float2(*reinterpret_cast<__half2*>(&u.y));
        acc.x += f0.x; acc.y += f0.y; acc.z += f1.x; acc.w += f1.y;
      }
    }
    for (; k + 2 <= cnt; k += 2) {
      int sa = __builtin_amdgcn_readlane(sv, k);
      int sb = __builtin_amdgcn_readlane(sv, k + 1);
      unsigned off = (unsigned)(half ? sb : sa) << 5;
      uint2 u = base[off];
      float2 f0 = __half22float2(*reinterpret_cast<__half2*>(&u.x));
      float2 f1 = __half22float2(*reinterpret_cast<__half2*>(&u.y));
      acc.x += f0.x; acc.y += f0.y; acc.z += f1.x; acc.w += f1.y;
    }
    if (k < cnt) {
      int sa = __builtin_amdgcn_readlane(sv, k);
      if (half == 0) {
        uint2 u = base[(unsigned)sa << 5];
        float2 f0 = __half22float2(*reinterpret_cast<__half2*>(&u.x));
        float2 f1 = __half22float2(*reinterpret_cast<__half2*>(&u.y));
        acc.x += f0.x; acc.y += f0.y; acc.z += f1.x; acc.w += f1.y;
      }
    }
  }
  acc.x += __shfl_xor(acc.x, 32);
  acc.y += __shfl_xor(acc.y, 32);
  acc.z += __shfl_xor(acc.z, 32);
  acc.w += __shfl_xor(acc.w, 32);
  if (half == 0) {
    uint2 u = base[(unsigned)wid << 5];
    float2 s0 = __half22float2(*reinterpret_cast<__half2*>(&u.x));
    float2 s1 = __half22float2(*reinterpret_cast<__half2*>(&u.y));
    float di = dinv[wid];
    float4 bb = ((const float4*)bias)[l32];
    float4 o;
    o.x = fmaxf(bb.x + di * (acc.x + s0.x), 0.f);
    o.y = fmaxf(bb.y + di * (acc.y + s0.y), 0.f);
    o.z = fmaxf(bb.z + di * (acc.z + s1.x), 0.f);
    o.w = fmaxf(bb.w + di * (acc.w + s1.y), 0.f);
    ((float4*)h)[((size_t)wid << 5) + l32] = o;
  }
}

// ====== fused pool+decode v2: wave = 2 edges = 4 endpoint-quarters (16 lanes each) ======
// quarter qq: edge = 2*wv + (qq>>1), side = qq&1. Each lane holds 2 float4 (8 cols).
__global__ __launch_bounds__(256) void decode_fused2_k(const float* __restrict__ h2,
                                                       const int* __restrict__ rowptr,
                                                       const int* __restrict__ nodelist,
                                                       const int* __restrict__ pos,
                                                       const int* __restrict__ neg,
                                                       float* __restrict__ out, int ep) {
  int wv = (int)((blockIdx.x * (size_t)blockDim.x + threadIdx.x) >> 6);
  int lane = threadIdx.x & 63;
  int qq = lane >> 4, l16 = lane & 15;
  int e0 = wv * 2;
  if (e0 >= 2 * ep) return;
  int edge = e0 + (qq >> 1);
  int side = qq & 1;
  bool live = edge < 2 * ep;
  int eL = live ? edge : 2 * ep - 1;
  int node;
  if (eL < ep) node = side ? pos[ep + eL] : pos[eL];
  else { int t = eL - ep; node = side ? neg[ep + t] : neg[t]; }

  int beg = rowptr[node], end = rowptr[node + 1];
  const float4* h4 = (const float4*)h2;
  float4 a0 = make_float4(0.f, 0.f, 0.f, 0.f);
  float4 a1 = make_float4(0.f, 0.f, 0.f, 0.f);

  int m = (beg < end) ? nodelist[beg] : 0;
  for (int j = beg; j < end; ++j) {
    int mn = (j + 1 < end) ? nodelist[j + 1] : 0;   // prefetch next index
    const float4* r = h4 + ((size_t)m << 5);
    float4 v0 = r[l16], v1 = r[l16 + 16];
    a0.x += v0.x; a0.y += v0.y; a0.z += v0.z; a0.w += v0.w;
    a1.x += v1.x; a1.y += v1.y; a1.z += v1.z; a1.w += v1.w;
    m = mn;
  }
  float inv = 1.0f / fmaxf((float)(end - beg), 1.0f);
  a0.x *= inv; a0.y *= inv; a0.z *= inv; a0.w *= inv;
  a1.x *= inv; a1.y *= inv; a1.z *= inv; a1.w *= inv;

  // exchange with partner side (lane ^ 16), then per-lane partial dot
  float4 b0, b1;
  b0.x = __shfl_xor(a0.x, 16); b0.y = __shfl_xor(a0.y, 16);
  b0.z = __shfl_xor(a0.z, 16); b0.w = __shfl_xor(a0.w, 16);
  b1.x = __shfl_xor(a1.x, 16); b1.y = __shfl_xor(a1.y, 16);
  b1.z = __shfl_xor(a1.z, 16); b1.w = __shfl_xor(a1.w, 16);
  float p = a0.x * b0.x + a0.y * b0.y + a0.z * b0.z + a0.w * b0.w
          + a1.x * b1.x + a1.y * b1.y + a1.z * b1.z + a1.w * b1.w;
  #pragma unroll
  for (int off = 8; off > 0; off >>= 1) p += __shfl_xor(p, off);
  if (live && side == 0 && l16 == 0) out[edge] = p;
}

// ================= fallback path (small ws): atomic version =================
__global__ void fill_deg_k(float* __restrict__ deg, int n) {
  int i = blockIdx.x * blockDim.x + threadIdx.x;
  if (i < n) deg[i] = 1.0f;
}
__global__ void accum_deg_k(const int* __restrict__ dst, float* __restrict__ deg, int e) {
  int i = blockIdx.x * blockDim.x + threadIdx.x;
  if (i < e) atomicAdd(&deg[dst[i]], 1.0f);
}
__global__ void dinv_k(float* __restrict__ deg, int n) {
  int i = blockIdx.x * blockDim.x + threadIdx.x;
  if (i < n) deg[i] = rsqrtf(deg[i]);
}
__global__ void init_h_k(const float* __restrict__ xw, const float* __restrict__ bias,
                         const float* __restrict__ dinv, float* __restrict__ h, int n) {
  int gid = blockIdx.x * blockDim.x + threadIdx.x;
  int node = gid >> 5, c4 = gid & 31;
  if (node >= n) return;
  float di = dinv[node];
  float nm = di * di;
  float4 v = ((const float4*)(xw + (size_t)node * HH))[c4];
  float4 b = ((const float4*)bias)[c4];
  ((float4*)(h + (size_t)node * HH))[c4] =
      make_float4(b.x + nm * v.x, b.y + nm * v.y, b.z + nm * v.z, b.w + nm * v.w);
}
__global__ void scatter_k(const float* __restrict__ xw, float* __restrict__ h,
                          const float* __restrict__ dinv, const int* __restrict__ src,
                          const int* __restrict__ dst, int e) {
  int gid = blockIdx.x * blockDim.x + threadIdx.x;
  int edge = gid >> 5, lane = gid & 31;
  if (edge >= e) return;
  int s = src[edge], d = dst[edge];
  float norm = dinv[s] * dinv[d];
  float4 v = ((const float4*)(xw + (size_t)s * HH))[lane];
  float* o = h + (size_t)d * HH + lane * 4;
  atomicAdd(o + 0, norm * v.x);
  atomicAdd(o + 1, norm * v.y);
  atomicAdd(o + 2, norm * v.z);
  atomicAdd(o + 3, norm * v.w);
}
__global__ void relu_k(float4* __restrict__ h, int n4) {
  int i = blockIdx.x * blockDim.x + threadIdx.x;
  if (i < n4) {
    float4 v = h[i];
    v.x = fmaxf(v.x, 0.f); v.y = fmaxf(v.y, 0.f);
    v.z = fmaxf(v.z, 0.f); v.w = fmaxf(v.w, 0.f);
    h[i] = v;
  }
}
__global__ void pool_accum_k(const float* __restrict__ h, const int* __restrict__ dict,
                             float* __restrict__ z, float* __restrict__ cnt, int n) {
  int gid = blockIdx.x * blockDim.x + threadIdx.x;
  int node = gid >> 5, lane = gid & 31;
  if (node >= n) return;
  int d = dict[node];
  float4 v = ((const float4*)(h + (size_t)node * HH))[lane];
  float* o = z + (size_t)d * HH + lane * 4;
  atomicAdd(o + 0, v.x); atomicAdd(o + 1, v.y);
  atomicAdd(o + 2, v.z); atomicAdd(o + 3, v.w);
  if (lane == 0) atomicAdd(&cnt[d], 1.0f);
}
__global__ void pool_div_k(float* __restrict__ z, const float* __restrict__ cnt, int n) {
  int gid = blockIdx.x * blockDim.x + threadIdx.x;
  int node = gid >> 5, lane = gid & 31;
  if (node >= n) return;
  float inv = 1.0f / fmaxf(cnt[node], 1.0f);
  float4* p = (float4*)(z + (size_t)node * HH) + lane;
  float4 v = *p;
  v.x *= inv; v.y *= inv; v.z *= inv; v.w *= inv;
  *p = v;
}
__global__ void decode_k(const float* __restrict__ z, const int* __restrict__ pos,
                         const int* __restrict__ neg, float* __restrict__ out, int ep) {
  int gid = blockIdx.x * blockDim.x + threadIdx.x;
  int edge = gid >> 5, lane = gid & 31;
  if (edge >= 2 * ep) return;
  int a, b;
  if (edge < ep) { a = pos[edge];      b = pos[ep + edge]; }
  else           { a = neg[edge - ep]; b = neg[edge]; }
  const float4* za = (const float4*)(z + (size_t)a * HH);
  const float4* zb = (const float4*)(z + (size_t)b * HH);
  float4 va = za[lane], vb = zb[lane];
  float dot = va.x * vb.x + va.y * vb.y + va.z * vb.z + va.w * vb.w;
  #pragma unroll
  for (int off = 16; off > 0; off >>= 1) dot += __shfl_xor(dot, off);
  if (lane == 0) out[edge] = dot;
}

// ================= host launch =================
extern "C" void kernel_launch(void* const* d_in, const int* in_sizes, int n_in,
                              void* d_out, int out_size, void* d_ws, size_t ws_size,
                              hipStream_t stream) {
  const float* x  = (const float*)d_in[0];
  const float* W1 = (const float*)d_in[1];
  const float* b1 = (const float*)d_in[2];
  const float* W2 = (const float*)d_in[3];
  const float* b2 = (const float*)d_in[4];
  const int* ei   = (const int*)d_in[5];
  const int* dict = (const int*)d_in[6];
  const int* pe   = (const int*)d_in[7];
  const int* ne   = (const int*)d_in[8];

  const int n  = in_sizes[0] / HH;   // 100000
  const int e  = in_sizes[5] / 2;    // 1.6M
  const int ep = in_sizes[7] / 2;    // 200000
  const int* src = ei;
  const int* dst = ei + e;

  const size_t nf = (size_t)n * HH;
  const int nbkt = (n + 255) >> 8;                 // 391
  const int nblk = (e + PCHUNK - 1) / PCHUNK;      // 98

  // fast-path ws layout:
  //   bufF  : nf floats      (part alias -> h1 -> h2)
  //   xw16  : nf halves      (blkoff alias -> xw' conv1 -> xw' conv2)
  //   dinv[n], rowptr[n+1], tmp[n], esrc[e], bsum[256], gcnt[nbkt], bktbase[nbkt+1]
  float*  p0     = (float*)d_ws;
  float*  bufF   = p0;
  __half* xw16   = (__half*)(p0 + nf);
  float*  dinv   = p0 + nf + nf / 2;
  int*    rowptr = (int*)(dinv + n);
  int*    tmp    = rowptr + (n + 1);
  int*    esrc   = tmp + n;
  int*    bsum   = esrc + e;
  int*    gcnt   = bsum + 256;
  int*    bktbase = gcnt + nbkt;
  size_t need = (nf + nf / 2 + n) * sizeof(float) +
                (size_t)(3 * n + 1 + e + 256 + 2 * nbkt + 1) * sizeof(int);

  int2* part   = (int2*)bufF;       // e pairs (12.8 MB) <= nf floats
  int*  blkoff = (int*)xw16;        // nbkt*nblk ints (~153 KB) <= nf halves

  const int nb    = (n + 255) / 256;
  const int nb32  = (int)(((size_t)n * 32 + 255) / 256);
  const int nb64  = (int)(((size_t)n * 64 + 255) / 256);
  const int gemb  = (n + 63) / 64;
  const int NBS   = (n + SCAN_C - 1) / SCAN_C;
  const int deb2  = (int)(((size_t)ep * 64 + 255) / 256);   // ep waves (2 edges/wave)

  bool fast = (ws_size >= need) && (nbkt <= 512) &&
              ((size_t)nbkt * nblk * 2 <= nf) && ((size_t)e * 2 <= nf);

  if (fast) {
    // ---- edge CSR (by dst) + dinv: bucketed 2-phase sort ----
    hipMemsetAsync(gcnt, 0, (size_t)nbkt * sizeof(int), stream);
    part_count_k<<<nblk, 256, 0, stream>>>(dst, e, nbkt, nblk, gcnt, blkoff);
    scan_bkt_k<<<1, 512, 0, stream>>>(gcnt, bktbase, nbkt, e);
    part_scatter_k<<<nblk, 256, 0, stream>>>(src, dst, e, nbkt, nblk, bktbase, blkoff, part);
    bucket_csr_k<<<nbkt, 256, 0, stream>>>(part, bktbase, rowptr, dinv, esrc, n, e, nbkt);

    // ---- conv1: xw16 = fp16(dinv * x@W1);  h1(fp32, bufF) ----
    gemm128_v3<true><<<gemb, 256, 0, stream>>>(x, W1, dinv, xw16, n);
    gather16_k<<<nb64, 256, 0, stream>>>(xw16, rowptr, esrc, dinv, b1, bufF, n);
    // ---- conv2: xw16 = fp16(dinv * h1@W2);  h2(fp32, bufF overwrite after read) ----
    gemm128_v3<true><<<gemb, 256, 0, stream>>>(bufF, W2, dinv, xw16, n);
    gather16_k<<<nb64, 256, 0, stream>>>(xw16, rowptr, esrc, dinv, b2, bufF, n);
    // bufF = h2 (relu'd, fp32)

    // ---- node CSR (by dict) for pooling ----
    hipMemsetAsync(tmp, 0, (size_t)n * sizeof(int), stream);
    hist_k<<<nb, 256, 0, stream>>>(dict, tmp, n);
    scan_pass1_k<<<NBS, SCAN_T, 0, stream>>>(tmp, bsum, n);
    scan_pass2_k<<<1, SCAN_T, 0, stream>>>(bsum, NBS, rowptr + n, n);
    scan_pass3_k<<<NBS, SCAN_T, 0, stream>>>(tmp, bsum, rowptr, nullptr, n);
    build_nodes_k<<<nb, 256, 0, stream>>>(dict, tmp, esrc, n);       // esrc = nodelist

    // ---- fused pool + decode (4 endpoint-quarters per wave) ----
    decode_fused2_k<<<deb2, 256, 0, stream>>>(bufF, rowptr, esrc, pe, ne, (float*)d_out, ep);
  } else {
    // ---- fallback: atomic path (bufA, bufB, dinv2, cnt) ----
    float* bufA  = (float*)d_ws;
    float* bufB  = bufA + nf;
    float* dinv2 = bufB + nf;
    float* cnt   = dinv2 + n;
    fill_deg_k<<<nb, 256, 0, stream>>>(dinv2, n);
    accum_deg_k<<<(e + 255) / 256, 256, 0, stream>>>(dst, dinv2, e);
    dinv_k<<<nb, 256, 0, stream>>>(dinv2, n);

    gemm128_v3<false><<<gemb, 256, 0, stream>>>(x, W1, nullptr, bufA, n);
    init_h_k<<<nb32, 256, 0, stream>>>(bufA, b1, dinv2, bufB, n);
    scatter_k<<<(int)(((size_t)e * 32 + 255) / 256), 256, 0, stream>>>(bufA, bufB, dinv2, src, dst, e);
    relu_k<<<nb32, 256, 0, stream>>>((float4*)bufB, n * 32);

    gemm128_v3<false><<<gemb, 256, 0, stream>>>(bufB, W2, nullptr, bufA, n);
    init_h_k<<<nb32, 256, 0, stream>>>(bufA, b2, dinv2, bufB, n);
    scatter_k<<<(int)(((size_t)e * 32 + 255) / 256), 256, 0, stream>>>(bufA, bufB, dinv2, src, dst, e);
    relu_k<<<nb32, 256, 0, stream>>>((float4*)bufB, n * 32);

    hipMemsetAsync(bufA, 0, nf * sizeof(float), stream);
    hipMemsetAsync(cnt, 0, (size_t)n * sizeof(float), stream);
    pool_accum_k<<<nb32, 256, 0, stream>>>(bufB, dict, bufA, cnt, n);
    pool_div_k<<<nb32, 256, 0, stream>>>(bufA, cnt, n);
    decode_k<<<(int)(((size_t)2 * ep * 32 + 255) / 256), 256, 0, stream>>>(
        bufA, pe, ne, (float*)d_out, ep);
  }
}

// Round 8
// 406.859 us; speedup vs baseline: 14.7597x; 1.0167x over previous
//
#include <hip/hip_runtime.h>
#include <hip/hip_fp16.h>

#define HH 128   // hidden size (both layers, and F_IN)
#define PCHUNK 16384  // items per partition block

// ================= bucketed 2-phase counting sort (edge CSR + node CSR) =================
// bucket = key >> 8 (256 keys per bucket).  nbkt <= 512 required.

__global__ __launch_bounds__(256) void part_count_k(const int* __restrict__ key, int e,
                                                    int nbkt, int nblk,
                                                    int* __restrict__ gcnt,
                                                    int* __restrict__ blkoff) {
  __shared__ int h[512];
  for (int i = threadIdx.x; i < nbkt; i += 256) h[i] = 0;
  __syncthreads();
  int start = blockIdx.x * PCHUNK;
  int cnt = e - start; if (cnt > PCHUNK) cnt = PCHUNK;
  for (int i = threadIdx.x; i < cnt; i += 256)
    atomicAdd(&h[key[start + i] >> 8], 1);
  __syncthreads();
  for (int i = threadIdx.x; i < nbkt; i += 256) {
    int c = h[i];
    if (c) blkoff[(size_t)i * nblk + blockIdx.x] = atomicAdd(&gcnt[i], c);
  }
}

__global__ __launch_bounds__(512) void scan_bkt_k(const int* __restrict__ gcnt,
                                                  int* __restrict__ bktbase, int nbkt, int e) {
  __shared__ int sc[512];
  int tid = threadIdx.x;
  int v = (tid < nbkt) ? gcnt[tid] : 0;
  sc[tid] = v;
  __syncthreads();
  for (int off = 1; off < 512; off <<= 1) {
    int t = (tid >= off) ? sc[tid - off] : 0;
    __syncthreads();
    sc[tid] += t;
    __syncthreads();
  }
  if (tid < nbkt) bktbase[tid] = sc[tid] - v;
  if (tid == 0) bktbase[nbkt] = e;
}

// payload = src[i] (edge version)
__global__ __launch_bounds__(256) void part_scatter_k(const int* __restrict__ src,
                                                      const int* __restrict__ key, int e,
                                                      int nbkt, int nblk,
                                                      const int* __restrict__ bktbase,
                                                      const int* __restrict__ blkoff,
                                                      int2* __restrict__ part) {
  __shared__ int cur[512];
  for (int i = threadIdx.x; i < nbkt; i += 256)
    cur[i] = bktbase[i] + blkoff[(size_t)i * nblk + blockIdx.x];
  __syncthreads();
  int start = blockIdx.x * PCHUNK;
  int cnt = e - start; if (cnt > PCHUNK) cnt = PCHUNK;
  for (int i = threadIdx.x; i < cnt; i += 256) {
    int d = key[start + i], s = src[start + i];
    int pos = atomicAdd(&cur[d >> 8], 1);
    part[pos] = make_int2(s, d);
  }
}

// payload = global index i (node version)
__global__ __launch_bounds__(256) void part_scatter_idx_k(const int* __restrict__ key, int e,
                                                          int nbkt, int nblk,
                                                          const int* __restrict__ bktbase,
                                                          const int* __restrict__ blkoff,
                                                          int2* __restrict__ part) {
  __shared__ int cur[512];
  for (int i = threadIdx.x; i < nbkt; i += 256)
    cur[i] = bktbase[i] + blkoff[(size_t)i * nblk + blockIdx.x];
  __syncthreads();
  int start = blockIdx.x * PCHUNK;
  int cnt = e - start; if (cnt > PCHUNK) cnt = PCHUNK;
  for (int i = threadIdx.x; i < cnt; i += 256) {
    int d = key[start + i];
    int pos = atomicAdd(&cur[d >> 8], 1);
    part[pos] = make_int2(start + i, d);
  }
}

// Per bucket (256 keys): LDS hist + scan -> rowptr, optional dinv, payload list.
__global__ __launch_bounds__(256) void bucket_csr_k(const int2* __restrict__ part,
                                                    const int* __restrict__ bktbase,
                                                    int* __restrict__ rowptr,
                                                    float* __restrict__ dinv,
                                                    int* __restrict__ esrc,
                                                    int n, int e, int nbkt) {
  __shared__ int hist[256];
  __shared__ int sc[256];
  __shared__ int cur[256];
  int tid = threadIdx.x;
  int b = blockIdx.x;
  int dstbase = b << 8;
  int nloc = n - dstbase; if (nloc > 256) nloc = 256;
  int beg = bktbase[b], bend = bktbase[b + 1];

  hist[tid] = 0;
  __syncthreads();
  for (int j = beg + tid; j < bend; j += 256)
    atomicAdd(&hist[part[j].y & 255], 1);
  __syncthreads();
  int v = hist[tid];
  sc[tid] = v;
  __syncthreads();
  for (int off = 1; off < 256; off <<= 1) {
    int t = (tid >= off) ? sc[tid - off] : 0;
    __syncthreads();
    sc[tid] += t;
    __syncthreads();
  }
  int excl = sc[tid] - v;
  if (tid < nloc) {
    rowptr[dstbase + tid] = beg + excl;
    cur[tid] = beg + excl;
    if (dinv) dinv[dstbase + tid] = rsqrtf((float)v + 1.0f);
  }
  __syncthreads();
  for (int j = beg + tid; j < bend; j += 256) {
    int2 p = part[j];
    int pos = atomicAdd(&cur[p.y & 255], 1);
    esrc[pos] = p.x;
  }
  if (b == nbkt - 1 && tid == 0) rowptr[n] = e;
}

// ========== GEMM v4: 2-phase K staging (16.6 KB LDS -> 8 blocks/CU), quarter-row threads ==========
// OUT16: write scale(i)*(A@W) as fp16 (half2-packed); else fp32.
template <bool OUT16>
__global__ __launch_bounds__(256) void gemm128_v4(const float* __restrict__ A,
                                                  const float* __restrict__ W,
                                                  const float* __restrict__ dscale,
                                                  void* __restrict__ out, int n) {
  __shared__ float As[64][65];   // 65: (r*65+k)%32 = (r+k)%32 -> 2-way reads (free)
  const int tid = threadIdx.x;
  const int rbase = blockIdx.x * 64;
  const int vrows = (n - rbase) < 64 ? (n - rbase) : 64;

  const int r = tid & 63;
  const int q = __builtin_amdgcn_readfirstlane(tid >> 6);  // wave-uniform quarter
  const float* Wq = W + q * 32;

  float4 acc[8];
  #pragma unroll
  for (int c = 0; c < 8; ++c) acc[c] = make_float4(0.f, 0.f, 0.f, 0.f);

  #pragma unroll
  for (int ph = 0; ph < 2; ++ph) {
    if (ph) __syncthreads();   // protect previous phase reads
    // stage 64 rows x 64 cols (cols [ph*64, ph*64+64)), 1024 float4, 4 per thread
    #pragma unroll
    for (int j = 0; j < 4; ++j) {
      int f = tid + 256 * j;
      int rr = f >> 4, c4 = f & 15;
      float4 v = (rr < vrows)
          ? ((const float4*)(A + (size_t)(rbase + rr) * HH + ph * 64))[c4]
          : make_float4(0.f, 0.f, 0.f, 0.f);
      As[rr][c4 * 4 + 0] = v.x;
      As[rr][c4 * 4 + 1] = v.y;
      As[rr][c4 * 4 + 2] = v.z;
      As[rr][c4 * 4 + 3] = v.w;
    }
    __syncthreads();

    #pragma unroll 4
    for (int kk = 0; kk < 64; ++kk) {
      float a = As[r][kk];
      const float4* Wr = (const float4*)(Wq + (size_t)(ph * 64 + kk) * HH);
      #pragma unroll
      for (int c = 0; c < 8; ++c) {
        float4 w = Wr[c];
        acc[c].x += a * w.x; acc[c].y += a * w.y;
        acc[c].z += a * w.z; acc[c].w += a * w.w;
      }
    }
  }

  int row = rbase + r;
  if (row < n) {
    float s = dscale ? dscale[row] : 1.0f;
    if (OUT16) {
      uint2* o = (uint2*)((__half*)out + (size_t)row * HH) + q * 8;
      #pragma unroll
      for (int c = 0; c < 8; ++c) {
        __half2 h0 = __float22half2_rn(make_float2(acc[c].x * s, acc[c].y * s));
        __half2 h1 = __float22half2_rn(make_float2(acc[c].z * s, acc[c].w * s));
        uint2 u;
        u.x = *reinterpret_cast<unsigned*>(&h0);
        u.y = *reinterpret_cast<unsigned*>(&h1);
        o[c] = u;
      }
    } else {
      float4* o = (float4*)((float*)out + (size_t)row * HH + q * 32);
      #pragma unroll
      for (int c = 0; c < 8; ++c) {
        acc[c].x *= s; acc[c].y *= s; acc[c].z *= s; acc[c].w *= s;
        o[c] = acc[c];
      }
    }
  }
}

// ==== gather conv (fp16 messages): h[d]=relu(b+dinv[d]*(self'+sum xw16[s])), h fp32 ====
__global__ __launch_bounds__(256) void gather16_k(const __half* __restrict__ xw16,
                                                  const int* __restrict__ rowptr,
                                                  const int* __restrict__ esrc,
                                                  const float* __restrict__ dinv,
                                                  const float* __restrict__ bias,
                                                  float* __restrict__ h, int n) {
  int wid = (int)((blockIdx.x * (size_t)blockDim.x + threadIdx.x) >> 6);
  int lane = threadIdx.x & 63;
  if (wid >= n) return;
  int beg = rowptr[wid], end = rowptr[wid + 1];
  int half = lane >> 5, l32 = lane & 31;
  const uint2* base = (const uint2*)xw16 + l32;   // row = 32 uint2
  float4 acc = make_float4(0.f, 0.f, 0.f, 0.f);

  for (int j0 = beg; j0 < end; j0 += 64) {
    int myj = j0 + lane;
    int sv = (myj < end) ? esrc[myj] : 0;
    int cnt = end - j0; if (cnt > 64) cnt = 64;
    int k = 0;
    for (; k + 8 <= cnt; k += 8) {
      #pragma unroll
      for (int p = 0; p < 4; ++p) {
        int sa = __builtin_amdgcn_readlane(sv, k + 2 * p);
        int sb = __builtin_amdgcn_readlane(sv, k + 2 * p + 1);
        unsigned off = (unsigned)(half ? sb : sa) << 5;
        uint2 u = base[off];
        float2 f0 = __half22float2(*reinterpret_cast<__half2*>(&u.x));
        float2 f1 = __half22float2(*reinterpret_cast<__half2*>(&u.y));
        acc.x += f0.x; acc.y += f0.y; acc.z += f1.x; acc.w += f1.y;
      }
    }
    for (; k + 2 <= cnt; k += 2) {
      int sa = __builtin_amdgcn_readlane(sv, k);
      int sb = __builtin_amdgcn_readlane(sv, k + 1);
      unsigned off = (unsigned)(half ? sb : sa) << 5;
      uint2 u = base[off];
      float2 f0 = __half22float2(*reinterpret_cast<__half2*>(&u.x));
      float2 f1 = __half22float2(*reinterpret_cast<__half2*>(&u.y));
      acc.x += f0.x; acc.y += f0.y; acc.z += f1.x; acc.w += f1.y;
    }
    if (k < cnt) {
      int sa = __builtin_amdgcn_readlane(sv, k);
      if (half == 0) {
        uint2 u = base[(unsigned)sa << 5];
        float2 f0 = __half22float2(*reinterpret_cast<__half2*>(&u.x));
        float2 f1 = __half22float2(*reinterpret_cast<__half2*>(&u.y));
        acc.x += f0.x; acc.y += f0.y; acc.z += f1.x; acc.w += f1.y;
      }
    }
  }
  acc.x += __shfl_xor(acc.x, 32);
  acc.y += __shfl_xor(acc.y, 32);
  acc.z += __shfl_xor(acc.z, 32);
  acc.w += __shfl_xor(acc.w, 32);
  if (half == 0) {
    uint2 u = base[(unsigned)wid << 5];
    float2 s0 = __half22float2(*reinterpret_cast<__half2*>(&u.x));
    float2 s1 = __half22float2(*reinterpret_cast<__half2*>(&u.y));
    float di = dinv[wid];
    float4 bb = ((const float4*)bias)[l32];
    float4 o;
    o.x = fmaxf(bb.x + di * (acc.x + s0.x), 0.f);
    o.y = fmaxf(bb.y + di * (acc.y + s0.y), 0.f);
    o.z = fmaxf(bb.z + di * (acc.z + s1.x), 0.f);
    o.w = fmaxf(bb.w + di * (acc.w + s1.y), 0.f);
    ((float4*)h)[((size_t)wid << 5) + l32] = o;
  }
}

// ====== fused pool+decode v3: wave = 2 edges = 4 endpoint-quarters, member walk unroll x2 ======
__global__ __launch_bounds__(256) void decode_fused3_k(const float* __restrict__ h2,
                                                       const int* __restrict__ rowptr,
                                                       const int* __restrict__ nodelist,
                                                       const int* __restrict__ pos,
                                                       const int* __restrict__ neg,
                                                       float* __restrict__ out, int ep) {
  int wv = (int)((blockIdx.x * (size_t)blockDim.x + threadIdx.x) >> 6);
  int lane = threadIdx.x & 63;
  int qq = lane >> 4, l16 = lane & 15;
  int e0 = wv * 2;
  if (e0 >= 2 * ep) return;
  int edge = e0 + (qq >> 1);
  int side = qq & 1;
  bool live = edge < 2 * ep;
  int eL = live ? edge : 2 * ep - 1;
  int node;
  if (eL < ep) node = side ? pos[ep + eL] : pos[eL];
  else { int t = eL - ep; node = side ? neg[ep + t] : neg[t]; }

  int beg = rowptr[node], end = rowptr[node + 1];
  const float4* h4 = (const float4*)h2;
  float4 a0 = make_float4(0.f, 0.f, 0.f, 0.f);
  float4 a1 = make_float4(0.f, 0.f, 0.f, 0.f);
  float4 c0 = make_float4(0.f, 0.f, 0.f, 0.f);
  float4 c1 = make_float4(0.f, 0.f, 0.f, 0.f);

  for (int j = beg; j < end; j += 2) {
    bool two = (j + 1) < end;
    int m0 = nodelist[j];
    int m1 = two ? nodelist[j + 1] : m0;
    const float4* r0 = h4 + ((size_t)m0 << 5);
    const float4* r1 = h4 + ((size_t)m1 << 5);
    float4 u0 = r0[l16], u1 = r0[l16 + 16];
    float4 v0 = r1[l16], v1 = r1[l16 + 16];
    a0.x += u0.x; a0.y += u0.y; a0.z += u0.z; a0.w += u0.w;
    a1.x += u1.x; a1.y += u1.y; a1.z += u1.z; a1.w += u1.w;
    if (two) {
      c0.x += v0.x; c0.y += v0.y; c0.z += v0.z; c0.w += v0.w;
      c1.x += v1.x; c1.y += v1.y; c1.z += v1.z; c1.w += v1.w;
    }
  }
  a0.x += c0.x; a0.y += c0.y; a0.z += c0.z; a0.w += c0.w;
  a1.x += c1.x; a1.y += c1.y; a1.z += c1.z; a1.w += c1.w;

  float inv = 1.0f / fmaxf((float)(end - beg), 1.0f);
  a0.x *= inv; a0.y *= inv; a0.z *= inv; a0.w *= inv;
  a1.x *= inv; a1.y *= inv; a1.z *= inv; a1.w *= inv;

  // exchange with partner side (lane ^ 16), then per-lane partial dot
  float4 b0, b1;
  b0.x = __shfl_xor(a0.x, 16); b0.y = __shfl_xor(a0.y, 16);
  b0.z = __shfl_xor(a0.z, 16); b0.w = __shfl_xor(a0.w, 16);
  b1.x = __shfl_xor(a1.x, 16); b1.y = __shfl_xor(a1.y, 16);
  b1.z = __shfl_xor(a1.z, 16); b1.w = __shfl_xor(a1.w, 16);
  float p = a0.x * b0.x + a0.y * b0.y + a0.z * b0.z + a0.w * b0.w
          + a1.x * b1.x + a1.y * b1.y + a1.z * b1.z + a1.w * b1.w;
  #pragma unroll
  for (int off = 8; off > 0; off >>= 1) p += __shfl_xor(p, off);
  if (live && side == 0 && l16 == 0) out[edge] = p;
}

// ================= fallback path (small ws): atomic version =================
__global__ void fill_deg_k(float* __restrict__ deg, int n) {
  int i = blockIdx.x * blockDim.x + threadIdx.x;
  if (i < n) deg[i] = 1.0f;
}
__global__ void accum_deg_k(const int* __restrict__ dst, float* __restrict__ deg, int e) {
  int i = blockIdx.x * blockDim.x + threadIdx.x;
  if (i < e) atomicAdd(&deg[dst[i]], 1.0f);
}
__global__ void dinv_k(float* __restrict__ deg, int n) {
  int i = blockIdx.x * blockDim.x + threadIdx.x;
  if (i < n) deg[i] = rsqrtf(deg[i]);
}
__global__ void init_h_k(const float* __restrict__ xw, const float* __restrict__ bias,
                         const float* __restrict__ dinv, float* __restrict__ h, int n) {
  int gid = blockIdx.x * blockDim.x + threadIdx.x;
  int node = gid >> 5, c4 = gid & 31;
  if (node >= n) return;
  float di = dinv[node];
  float nm = di * di;
  float4 v = ((const float4*)(xw + (size_t)node * HH))[c4];
  float4 b = ((const float4*)bias)[c4];
  ((float4*)(h + (size_t)node * HH))[c4] =
      make_float4(b.x + nm * v.x, b.y + nm * v.y, b.z + nm * v.z, b.w + nm * v.w);
}
__global__ void scatter_k(const float* __restrict__ xw, float* __restrict__ h,
                          const float* __restrict__ dinv, const int* __restrict__ src,
                          const int* __restrict__ dst, int e) {
  int gid = blockIdx.x * blockDim.x + threadIdx.x;
  int edge = gid >> 5, lane = gid & 31;
  if (edge >= e) return;
  int s = src[edge], d = dst[edge];
  float norm = dinv[s] * dinv[d];
  float4 v = ((const float4*)(xw + (size_t)s * HH))[lane];
  float* o = h + (size_t)d * HH + lane * 4;
  atomicAdd(o + 0, norm * v.x);
  atomicAdd(o + 1, norm * v.y);
  atomicAdd(o + 2, norm * v.z);
  atomicAdd(o + 3, norm * v.w);
}
__global__ void relu_k(float4* __restrict__ h, int n4) {
  int i = blockIdx.x * blockDim.x + threadIdx.x;
  if (i < n4) {
    float4 v = h[i];
    v.x = fmaxf(v.x, 0.f); v.y = fmaxf(v.y, 0.f);
    v.z = fmaxf(v.z, 0.f); v.w = fmaxf(v.w, 0.f);
    h[i] = v;
  }
}
__global__ void pool_accum_k(const float* __restrict__ h, const int* __restrict__ dict,
                             float* __restrict__ z, float* __restrict__ cnt, int n) {
  int gid = blockIdx.x * blockDim.x + threadIdx.x;
  int node = gid >> 5, lane = gid & 31;
  if (node >= n) return;
  int d = dict[node];
  float4 v = ((const float4*)(h + (size_t)node * HH))[lane];
  float* o = z + (size_t)d * HH + lane * 4;
  atomicAdd(o + 0, v.x); atomicAdd(o + 1, v.y);
  atomicAdd(o + 2, v.z); atomicAdd(o + 3, v.w);
  if (lane == 0) atomicAdd(&cnt[d], 1.0f);
}
__global__ void pool_div_k(float* __restrict__ z, const float* __restrict__ cnt, int n) {
  int gid = blockIdx.x * blockDim.x + threadIdx.x;
  int node = gid >> 5, lane = gid & 31;
  if (node >= n) return;
  float inv = 1.0f / fmaxf(cnt[node], 1.0f);
  float4* p = (float4*)(z + (size_t)node * HH) + lane;
  float4 v = *p;
  v.x *= inv; v.y *= inv; v.z *= inv; v.w *= inv;
  *p = v;
}
__global__ void decode_k(const float* __restrict__ z, const int* __restrict__ pos,
                         const int* __restrict__ neg, float* __restrict__ out, int ep) {
  int gid = blockIdx.x * blockDim.x + threadIdx.x;
  int edge = gid >> 5, lane = gid & 31;
  if (edge >= 2 * ep) return;
  int a, b;
  if (edge < ep) { a = pos[edge];      b = pos[ep + edge]; }
  else           { a = neg[edge - ep]; b = neg[edge]; }
  const float4* za = (const float4*)(z + (size_t)a * HH);
  const float4* zb = (const float4*)(z + (size_t)b * HH);
  float4 va = za[lane], vb = zb[lane];
  float dot = va.x * vb.x + va.y * vb.y + va.z * vb.z + va.w * vb.w;
  #pragma unroll
  for (int off = 16; off > 0; off >>= 1) dot += __shfl_xor(dot, off);
  if (lane == 0) out[edge] = dot;
}

// ================= host launch =================
extern "C" void kernel_launch(void* const* d_in, const int* in_sizes, int n_in,
                              void* d_out, int out_size, void* d_ws, size_t ws_size,
                              hipStream_t stream) {
  const float* x  = (const float*)d_in[0];
  const float* W1 = (const float*)d_in[1];
  const float* b1 = (const float*)d_in[2];
  const float* W2 = (const float*)d_in[3];
  const float* b2 = (const float*)d_in[4];
  const int* ei   = (const int*)d_in[5];
  const int* dict = (const int*)d_in[6];
  const int* pe   = (const int*)d_in[7];
  const int* ne   = (const int*)d_in[8];

  const int n  = in_sizes[0] / HH;   // 100000
  const int e  = in_sizes[5] / 2;    // 1.6M
  const int ep = in_sizes[7] / 2;    // 200000
  const int* src = ei;
  const int* dst = ei + e;

  const size_t nf = (size_t)n * HH;
  const int nbkt  = (n + 255) >> 8;                 // 391
  const int nblkE = (e + PCHUNK - 1) / PCHUNK;      // 98
  const int nblkN = (n + PCHUNK - 1) / PCHUNK;      // 7

  // fast-path ws layout:
  //   bufF  : nf floats      (edge part alias -> h1 -> h2)
  //   xw16  : nf halves      (edge blkoff alias -> xw' -> node part+blkoff alias)
  //   dinv[n], rowptr[n+1], tmp[n], esrc[e], bsum[256], gcnt[nbkt], bktbase[nbkt+1]
  float*  p0     = (float*)d_ws;
  float*  bufF   = p0;
  __half* xw16   = (__half*)(p0 + nf);
  float*  dinv   = p0 + nf + nf / 2;
  int*    rowptr = (int*)(dinv + n);
  int*    tmp    = rowptr + (n + 1);
  int*    esrc   = tmp + n;
  int*    bsum   = esrc + e;
  int*    gcnt   = bsum + 256;
  int*    bktbase = gcnt + nbkt;
  size_t need = (nf + nf / 2 + n) * sizeof(float) +
                (size_t)(3 * n + 1 + e + 256 + 2 * nbkt + 1) * sizeof(int);

  int2* partE   = (int2*)bufF;            // e pairs (12.8 MB) <= nf floats
  int*  blkoffE = (int*)xw16;             // nbkt*nblkE ints (~153 KB) <= nf halves
  int2* partN   = (int2*)xw16;            // n pairs (800 KB), xw16 dead after conv2 gather
  int*  blkoffN = (int*)(partN + n);      // nbkt*nblkN ints (~11 KB)

  const int nb    = (n + 255) / 256;
  const int nb32  = (int)(((size_t)n * 32 + 255) / 256);
  const int nb64  = (int)(((size_t)n * 64 + 255) / 256);
  const int gemb  = (n + 63) / 64;
  const int deb2  = (int)(((size_t)ep * 64 + 255) / 256);   // ep waves (2 edges/wave)

  bool fast = (ws_size >= need) && (nbkt <= 512) &&
              ((size_t)nbkt * nblkE * 2 <= nf) && ((size_t)e * 2 <= nf);

  if (fast) {
    // ---- edge CSR (by dst) + dinv: bucketed 2-phase sort ----
    hipMemsetAsync(gcnt, 0, (size_t)nbkt * sizeof(int), stream);
    part_count_k<<<nblkE, 256, 0, stream>>>(dst, e, nbkt, nblkE, gcnt, blkoffE);
    scan_bkt_k<<<1, 512, 0, stream>>>(gcnt, bktbase, nbkt, e);
    part_scatter_k<<<nblkE, 256, 0, stream>>>(src, dst, e, nbkt, nblkE, bktbase, blkoffE, partE);
    bucket_csr_k<<<nbkt, 256, 0, stream>>>(partE, bktbase, rowptr, dinv, esrc, n, e, nbkt);

    // ---- conv1: xw16 = fp16(dinv * x@W1);  h1(fp32, bufF) ----
    gemm128_v4<true><<<gemb, 256, 0, stream>>>(x, W1, dinv, xw16, n);
    gather16_k<<<nb64, 256, 0, stream>>>(xw16, rowptr, esrc, dinv, b1, bufF, n);
    // ---- conv2: xw16 = fp16(dinv * h1@W2);  h2(fp32, bufF) ----
    gemm128_v4<true><<<gemb, 256, 0, stream>>>(bufF, W2, dinv, xw16, n);
    gather16_k<<<nb64, 256, 0, stream>>>(xw16, rowptr, esrc, dinv, b2, bufF, n);
    // bufF = h2 (relu'd, fp32); xw16 now dead -> reuse for node part

    // ---- node CSR (by dict) for pooling: bucketed sort ----
    hipMemsetAsync(gcnt, 0, (size_t)nbkt * sizeof(int), stream);
    part_count_k<<<nblkN, 256, 0, stream>>>(dict, n, nbkt, nblkN, gcnt, blkoffN);
    scan_bkt_k<<<1, 512, 0, stream>>>(gcnt, bktbase, nbkt, n);
    part_scatter_idx_k<<<nblkN, 256, 0, stream>>>(dict, n, nbkt, nblkN, bktbase, blkoffN, partN);
    bucket_csr_k<<<nbkt, 256, 0, stream>>>(partN, bktbase, rowptr, nullptr, esrc, n, n, nbkt);
    // rowptr = group rowptr, esrc = nodelist

    // ---- fused pool + decode ----
    decode_fused3_k<<<deb2, 256, 0, stream>>>(bufF, rowptr, esrc, pe, ne, (float*)d_out, ep);
  } else {
    // ---- fallback: atomic path (bufA, bufB, dinv2, cnt) ----
    float* bufA  = (float*)d_ws;
    float* bufB  = bufA + nf;
    float* dinv2 = bufB + nf;
    float* cnt   = dinv2 + n;
    fill_deg_k<<<nb, 256, 0, stream>>>(dinv2, n);
    accum_deg_k<<<(e + 255) / 256, 256, 0, stream>>>(dst, dinv2, e);
    dinv_k<<<nb, 256, 0, stream>>>(dinv2, n);

    gemm128_v4<false><<<gemb, 256, 0, stream>>>(x, W1, nullptr, bufA, n);
    init_h_k<<<nb32, 256, 0, stream>>>(bufA, b1, dinv2, bufB, n);
    scatter_k<<<(int)(((size_t)e * 32 + 255) / 256), 256, 0, stream>>>(bufA, bufB, dinv2, src, dst, e);
    relu_k<<<nb32, 256, 0, stream>>>((float4*)bufB, n * 32);

    gemm128_v4<false><<<gemb, 256, 0, stream>>>(bufB, W2, nullptr, bufA, n);
    init_h_k<<<nb32, 256, 0, stream>>>(bufA, b2, dinv2, bufB, n);
    scatter_k<<<(int)(((size_t)e * 32 + 255) / 256), 256, 0, stream>>>(bufA, bufB, dinv2, src, dst, e);
    relu_k<<<nb32, 256, 0, stream>>>((float4*)bufB, n * 32);

    hipMemsetAsync(bufA, 0, nf * sizeof(float), stream);
    hipMemsetAsync(cnt, 0, (size_t)n * sizeof(float), stream);
    pool_accum_k<<<nb32, 256, 0, stream>>>(bufB, dict, bufA, cnt, n);
    pool_div_k<<<nb32, 256, 0, stream>>>(bufA, cnt, n);
    decode_k<<<(int)(((size_t)2 * ep * 32 + 255) / 256), 256, 0, stream>>>(
        bufA, pe, ne, (float*)d_out, ep);
  }
}

// Round 9
// 398.118 us; speedup vs baseline: 15.0838x; 1.0220x over previous
//
#include <hip/hip_runtime.h>
#include <hip/hip_fp16.h>

#define HH 128   // hidden size (both layers, and F_IN)
#define PCHUNK 16384  // items per partition block

// ================= bucketed 2-phase counting sort (edge CSR + node CSR) =================
// bucket = key >> 8 (256 keys per bucket).  nbkt <= 512, payload < 2^23 required.
// part record: (payload << 8) | (key & 255)   -- 4 bytes

__global__ __launch_bounds__(256) void part_count_k(const int* __restrict__ key, int e,
                                                    int nbkt, int nblk,
                                                    int* __restrict__ gcnt,
                                                    int* __restrict__ blkoff) {
  __shared__ int h[512];
  for (int i = threadIdx.x; i < nbkt; i += 256) h[i] = 0;
  __syncthreads();
  int start = blockIdx.x * PCHUNK;
  int cnt = e - start; if (cnt > PCHUNK) cnt = PCHUNK;
  for (int i = threadIdx.x; i < cnt; i += 256)
    atomicAdd(&h[key[start + i] >> 8], 1);
  __syncthreads();
  for (int i = threadIdx.x; i < nbkt; i += 256) {
    int c = h[i];
    if (c) blkoff[(size_t)i * nblk + blockIdx.x] = atomicAdd(&gcnt[i], c);
  }
}

__global__ __launch_bounds__(512) void scan_bkt_k(const int* __restrict__ gcnt,
                                                  int* __restrict__ bktbase, int nbkt, int e) {
  __shared__ int sc[512];
  int tid = threadIdx.x;
  int v = (tid < nbkt) ? gcnt[tid] : 0;
  sc[tid] = v;
  __syncthreads();
  for (int off = 1; off < 512; off <<= 1) {
    int t = (tid >= off) ? sc[tid - off] : 0;
    __syncthreads();
    sc[tid] += t;
    __syncthreads();
  }
  if (tid < nbkt) bktbase[tid] = sc[tid] - v;
  if (tid == 0) bktbase[nbkt] = e;
}

// payload = src[i] (edge version)
__global__ __launch_bounds__(256) void part_scatter_k(const int* __restrict__ src,
                                                      const int* __restrict__ key, int e,
                                                      int nbkt, int nblk,
                                                      const int* __restrict__ bktbase,
                                                      const int* __restrict__ blkoff,
                                                      int* __restrict__ part) {
  __shared__ int cur[512];
  for (int i = threadIdx.x; i < nbkt; i += 256)
    cur[i] = bktbase[i] + blkoff[(size_t)i * nblk + blockIdx.x];
  __syncthreads();
  int start = blockIdx.x * PCHUNK;
  int cnt = e - start; if (cnt > PCHUNK) cnt = PCHUNK;
  for (int i = threadIdx.x; i < cnt; i += 256) {
    int d = key[start + i], s = src[start + i];
    int pos = atomicAdd(&cur[d >> 8], 1);
    part[pos] = (s << 8) | (d & 255);
  }
}

// payload = global index i (node version)
__global__ __launch_bounds__(256) void part_scatter_idx_k(const int* __restrict__ key, int e,
                                                          int nbkt, int nblk,
                                                          const int* __restrict__ bktbase,
                                                          const int* __restrict__ blkoff,
                                                          int* __restrict__ part) {
  __shared__ int cur[512];
  for (int i = threadIdx.x; i < nbkt; i += 256)
    cur[i] = bktbase[i] + blkoff[(size_t)i * nblk + blockIdx.x];
  __syncthreads();
  int start = blockIdx.x * PCHUNK;
  int cnt = e - start; if (cnt > PCHUNK) cnt = PCHUNK;
  for (int i = threadIdx.x; i < cnt; i += 256) {
    int d = key[start + i];
    int pos = atomicAdd(&cur[d >> 8], 1);
    part[pos] = ((start + i) << 8) | (d & 255);
  }
}

// Per bucket (256 keys): LDS hist + scan -> rowptr, optional dinv, payload list.
__global__ __launch_bounds__(256) void bucket_csr_k(const int* __restrict__ part,
                                                    const int* __restrict__ bktbase,
                                                    int* __restrict__ rowptr,
                                                    float* __restrict__ dinv,
                                                    int* __restrict__ esrc,
                                                    int n, int e, int nbkt) {
  __shared__ int hist[256];
  __shared__ int sc[256];
  __shared__ int cur[256];
  int tid = threadIdx.x;
  int b = blockIdx.x;
  int dstbase = b << 8;
  int nloc = n - dstbase; if (nloc > 256) nloc = 256;
  int beg = bktbase[b], bend = bktbase[b + 1];

  hist[tid] = 0;
  __syncthreads();
  for (int j = beg + tid; j < bend; j += 256)
    atomicAdd(&hist[part[j] & 255], 1);
  __syncthreads();
  int v = hist[tid];
  sc[tid] = v;
  __syncthreads();
  for (int off = 1; off < 256; off <<= 1) {
    int t = (tid >= off) ? sc[tid - off] : 0;
    __syncthreads();
    sc[tid] += t;
    __syncthreads();
  }
  int excl = sc[tid] - v;
  if (tid < nloc) {
    rowptr[dstbase + tid] = beg + excl;
    cur[tid] = beg + excl;
    if (dinv) dinv[dstbase + tid] = rsqrtf((float)v + 1.0f);
  }
  __syncthreads();
  for (int j = beg + tid; j < bend; j += 256) {
    int p = part[j];
    int pos = atomicAdd(&cur[p & 255], 1);
    esrc[pos] = p >> 8;
  }
  if (b == nbkt - 1 && tid == 0) rowptr[n] = e;
}

// ========== GEMM v4: 2-phase K staging (16.6 KB LDS -> 8 blocks/CU), quarter-row threads ==========
// OUT16: write scale(i)*(A@W) as fp16 (half2-packed); else fp32.
template <bool OUT16>
__global__ __launch_bounds__(256) void gemm128_v4(const float* __restrict__ A,
                                                  const float* __restrict__ W,
                                                  const float* __restrict__ dscale,
                                                  void* __restrict__ out, int n) {
  __shared__ float As[64][65];
  const int tid = threadIdx.x;
  const int rbase = blockIdx.x * 64;
  const int vrows = (n - rbase) < 64 ? (n - rbase) : 64;

  const int r = tid & 63;
  const int q = __builtin_amdgcn_readfirstlane(tid >> 6);
  const float* Wq = W + q * 32;

  float4 acc[8];
  #pragma unroll
  for (int c = 0; c < 8; ++c) acc[c] = make_float4(0.f, 0.f, 0.f, 0.f);

  #pragma unroll
  for (int ph = 0; ph < 2; ++ph) {
    if (ph) __syncthreads();
    #pragma unroll
    for (int j = 0; j < 4; ++j) {
      int f = tid + 256 * j;
      int rr = f >> 4, c4 = f & 15;
      float4 v = (rr < vrows)
          ? ((const float4*)(A + (size_t)(rbase + rr) * HH + ph * 64))[c4]
          : make_float4(0.f, 0.f, 0.f, 0.f);
      As[rr][c4 * 4 + 0] = v.x;
      As[rr][c4 * 4 + 1] = v.y;
      As[rr][c4 * 4 + 2] = v.z;
      As[rr][c4 * 4 + 3] = v.w;
    }
    __syncthreads();

    #pragma unroll 4
    for (int kk = 0; kk < 64; ++kk) {
      float a = As[r][kk];
      const float4* Wr = (const float4*)(Wq + (size_t)(ph * 64 + kk) * HH);
      #pragma unroll
      for (int c = 0; c < 8; ++c) {
        float4 w = Wr[c];
        acc[c].x += a * w.x; acc[c].y += a * w.y;
        acc[c].z += a * w.z; acc[c].w += a * w.w;
      }
    }
  }

  int row = rbase + r;
  if (row < n) {
    float s = dscale ? dscale[row] : 1.0f;
    if (OUT16) {
      uint2* o = (uint2*)((__half*)out + (size_t)row * HH) + q * 8;
      #pragma unroll
      for (int c = 0; c < 8; ++c) {
        __half2 h0 = __float22half2_rn(make_float2(acc[c].x * s, acc[c].y * s));
        __half2 h1 = __float22half2_rn(make_float2(acc[c].z * s, acc[c].w * s));
        uint2 u;
        u.x = *reinterpret_cast<unsigned*>(&h0);
        u.y = *reinterpret_cast<unsigned*>(&h1);
        o[c] = u;
      }
    } else {
      float4* o = (float4*)((float*)out + (size_t)row * HH + q * 32);
      #pragma unroll
      for (int c = 0; c < 8; ++c) {
        acc[c].x *= s; acc[c].y *= s; acc[c].z *= s; acc[c].w *= s;
        o[c] = acc[c];
      }
    }
  }
}

// ==== gather conv (fp16 messages): h[d]=relu(b+dinv[d]*(self'+sum xw16[s])) ====
// HOUT16: write h as fp16 (for conv2, decode-only consumer); else fp32.
template <bool HOUT16>
__global__ __launch_bounds__(256) void gather16_k(const __half* __restrict__ xw16,
                                                  const int* __restrict__ rowptr,
                                                  const int* __restrict__ esrc,
                                                  const float* __restrict__ dinv,
                                                  const float* __restrict__ bias,
                                                  void* __restrict__ h, int n) {
  int wid = (int)((blockIdx.x * (size_t)blockDim.x + threadIdx.x) >> 6);
  int lane = threadIdx.x & 63;
  if (wid >= n) return;
  int beg = rowptr[wid], end = rowptr[wid + 1];
  int half = lane >> 5, l32 = lane & 31;
  const uint2* base = (const uint2*)xw16 + l32;   // row = 32 uint2
  float4 acc = make_float4(0.f, 0.f, 0.f, 0.f);

  for (int j0 = beg; j0 < end; j0 += 64) {
    int myj = j0 + lane;
    int sv = (myj < end) ? esrc[myj] : 0;
    int cnt = end - j0; if (cnt > 64) cnt = 64;
    int k = 0;
    for (; k + 8 <= cnt; k += 8) {
      #pragma unroll
      for (int p = 0; p < 4; ++p) {
        int sa = __builtin_amdgcn_readlane(sv, k + 2 * p);
        int sb = __builtin_amdgcn_readlane(sv, k + 2 * p + 1);
        unsigned off = (unsigned)(half ? sb : sa) << 5;
        uint2 u = base[off];
        float2 f0 = __half22float2(*reinterpret_cast<__half2*>(&u.x));
        float2 f1 = __half22float2(*reinterpret_cast<__half2*>(&u.y));
        acc.x += f0.x; acc.y += f0.y; acc.z += f1.x; acc.w += f1.y;
      }
    }
    for (; k + 2 <= cnt; k += 2) {
      int sa = __builtin_amdgcn_readlane(sv, k);
      int sb = __builtin_amdgcn_readlane(sv, k + 1);
      unsigned off = (unsigned)(half ? sb : sa) << 5;
      uint2 u = base[off];
      float2 f0 = __half22float2(*reinterpret_cast<__half2*>(&u.x));
      float2 f1 = __half22float2(*reinterpret_cast<__half2*>(&u.y));
      acc.x += f0.x; acc.y += f0.y; acc.z += f1.x; acc.w += f1.y;
    }
    if (k < cnt) {
      int sa = __builtin_amdgcn_readlane(sv, k);
      if (half == 0) {
        uint2 u = base[(unsigned)sa << 5];
        float2 f0 = __half22float2(*reinterpret_cast<__half2*>(&u.x));
        float2 f1 = __half22float2(*reinterpret_cast<__half2*>(&u.y));
        acc.x += f0.x; acc.y += f0.y; acc.z += f1.x; acc.w += f1.y;
      }
    }
  }
  acc.x += __shfl_xor(acc.x, 32);
  acc.y += __shfl_xor(acc.y, 32);
  acc.z += __shfl_xor(acc.z, 32);
  acc.w += __shfl_xor(acc.w, 32);
  if (half == 0) {
    uint2 u = base[(unsigned)wid << 5];
    float2 s0 = __half22float2(*reinterpret_cast<__half2*>(&u.x));
    float2 s1 = __half22float2(*reinterpret_cast<__half2*>(&u.y));
    float di = dinv[wid];
    float4 bb = ((const float4*)bias)[l32];
    float4 o;
    o.x = fmaxf(bb.x + di * (acc.x + s0.x), 0.f);
    o.y = fmaxf(bb.y + di * (acc.y + s0.y), 0.f);
    o.z = fmaxf(bb.z + di * (acc.z + s1.x), 0.f);
    o.w = fmaxf(bb.w + di * (acc.w + s1.y), 0.f);
    if (HOUT16) {
      __half2 p0 = __float22half2_rn(make_float2(o.x, o.y));
      __half2 p1 = __float22half2_rn(make_float2(o.z, o.w));
      uint2 w;
      w.x = *reinterpret_cast<unsigned*>(&p0);
      w.y = *reinterpret_cast<unsigned*>(&p1);
      ((uint2*)h)[((size_t)wid << 5) + l32] = w;
    } else {
      ((float4*)h)[((size_t)wid << 5) + l32] = o;
    }
  }
}

// ====== fused pool+decode v4 (fp16 h2): wave = 2 edges = 4 endpoint-quarters ======
__global__ __launch_bounds__(256) void decode_fused4_k(const __half* __restrict__ h2,
                                                       const int* __restrict__ rowptr,
                                                       const int* __restrict__ nodelist,
                                                       const int* __restrict__ pos,
                                                       const int* __restrict__ neg,
                                                       float* __restrict__ out, int ep) {
  int wv = (int)((blockIdx.x * (size_t)blockDim.x + threadIdx.x) >> 6);
  int lane = threadIdx.x & 63;
  int qq = lane >> 4, l16 = lane & 15;
  int e0 = wv * 2;
  if (e0 >= 2 * ep) return;
  int edge = e0 + (qq >> 1);
  int side = qq & 1;
  bool live = edge < 2 * ep;
  int eL = live ? edge : 2 * ep - 1;
  int node;
  if (eL < ep) node = side ? pos[ep + eL] : pos[eL];
  else { int t = eL - ep; node = side ? neg[ep + t] : neg[t]; }

  int beg = rowptr[node], end = rowptr[node + 1];
  const uint2* h4 = (const uint2*)h2;   // row = 32 uint2 (128 halves)
  float4 a0 = make_float4(0.f, 0.f, 0.f, 0.f);
  float4 a1 = make_float4(0.f, 0.f, 0.f, 0.f);
  float4 c0 = make_float4(0.f, 0.f, 0.f, 0.f);
  float4 c1 = make_float4(0.f, 0.f, 0.f, 0.f);

  for (int j = beg; j < end; j += 2) {
    bool two = (j + 1) < end;
    int m0 = nodelist[j];
    int m1 = two ? nodelist[j + 1] : m0;
    const uint2* r0 = h4 + ((size_t)m0 << 5);
    const uint2* r1 = h4 + ((size_t)m1 << 5);
    uint2 u0 = r0[l16], u1 = r0[l16 + 16];
    uint2 v0 = r1[l16], v1 = r1[l16 + 16];
    float2 f;
    f = __half22float2(*reinterpret_cast<__half2*>(&u0.x)); a0.x += f.x; a0.y += f.y;
    f = __half22float2(*reinterpret_cast<__half2*>(&u0.y)); a0.z += f.x; a0.w += f.y;
    f = __half22float2(*reinterpret_cast<__half2*>(&u1.x)); a1.x += f.x; a1.y += f.y;
    f = __half22float2(*reinterpret_cast<__half2*>(&u1.y)); a1.z += f.x; a1.w += f.y;
    if (two) {
      f = __half22float2(*reinterpret_cast<__half2*>(&v0.x)); c0.x += f.x; c0.y += f.y;
      f = __half22float2(*reinterpret_cast<__half2*>(&v0.y)); c0.z += f.x; c0.w += f.y;
      f = __half22float2(*reinterpret_cast<__half2*>(&v1.x)); c1.x += f.x; c1.y += f.y;
      f = __half22float2(*reinterpret_cast<__half2*>(&v1.y)); c1.z += f.x; c1.w += f.y;
    }
  }
  a0.x += c0.x; a0.y += c0.y; a0.z += c0.z; a0.w += c0.w;
  a1.x += c1.x; a1.y += c1.y; a1.z += c1.z; a1.w += c1.w;

  float inv = 1.0f / fmaxf((float)(end - beg), 1.0f);
  a0.x *= inv; a0.y *= inv; a0.z *= inv; a0.w *= inv;
  a1.x *= inv; a1.y *= inv; a1.z *= inv; a1.w *= inv;

  float4 b0, b1;
  b0.x = __shfl_xor(a0.x, 16); b0.y = __shfl_xor(a0.y, 16);
  b0.z = __shfl_xor(a0.z, 16); b0.w = __shfl_xor(a0.w, 16);
  b1.x = __shfl_xor(a1.x, 16); b1.y = __shfl_xor(a1.y, 16);
  b1.z = __shfl_xor(a1.z, 16); b1.w = __shfl_xor(a1.w, 16);
  float p = a0.x * b0.x + a0.y * b0.y + a0.z * b0.z + a0.w * b0.w
          + a1.x * b1.x + a1.y * b1.y + a1.z * b1.z + a1.w * b1.w;
  #pragma unroll
  for (int off = 8; off > 0; off >>= 1) p += __shfl_xor(p, off);
  if (live && side == 0 && l16 == 0) out[edge] = p;
}

// ================= fallback path (small ws): atomic version =================
__global__ void fill_deg_k(float* __restrict__ deg, int n) {
  int i = blockIdx.x * blockDim.x + threadIdx.x;
  if (i < n) deg[i] = 1.0f;
}
__global__ void accum_deg_k(const int* __restrict__ dst, float* __restrict__ deg, int e) {
  int i = blockIdx.x * blockDim.x + threadIdx.x;
  if (i < e) atomicAdd(&deg[dst[i]], 1.0f);
}
__global__ void dinv_k(float* __restrict__ deg, int n) {
  int i = blockIdx.x * blockDim.x + threadIdx.x;
  if (i < n) deg[i] = rsqrtf(deg[i]);
}
__global__ void init_h_k(const float* __restrict__ xw, const float* __restrict__ bias,
                         const float* __restrict__ dinv, float* __restrict__ h, int n) {
  int gid = blockIdx.x * blockDim.x + threadIdx.x;
  int node = gid >> 5, c4 = gid & 31;
  if (node >= n) return;
  float di = dinv[node];
  float nm = di * di;
  float4 v = ((const float4*)(xw + (size_t)node * HH))[c4];
  float4 b = ((const float4*)bias)[c4];
  ((float4*)(h + (size_t)node * HH))[c4] =
      make_float4(b.x + nm * v.x, b.y + nm * v.y, b.z + nm * v.z, b.w + nm * v.w);
}
__global__ void scatter_k(const float* __restrict__ xw, float* __restrict__ h,
                          const float* __restrict__ dinv, const int* __restrict__ src,
                          const int* __restrict__ dst, int e) {
  int gid = blockIdx.x * blockDim.x + threadIdx.x;
  int edge = gid >> 5, lane = gid & 31;
  if (edge >= e) return;
  int s = src[edge], d = dst[edge];
  float norm = dinv[s] * dinv[d];
  float4 v = ((const float4*)(xw + (size_t)s * HH))[lane];
  float* o = h + (size_t)d * HH + lane * 4;
  atomicAdd(o + 0, norm * v.x);
  atomicAdd(o + 1, norm * v.y);
  atomicAdd(o + 2, norm * v.z);
  atomicAdd(o + 3, norm * v.w);
}
__global__ void relu_k(float4* __restrict__ h, int n4) {
  int i = blockIdx.x * blockDim.x + threadIdx.x;
  if (i < n4) {
    float4 v = h[i];
    v.x = fmaxf(v.x, 0.f); v.y = fmaxf(v.y, 0.f);
    v.z = fmaxf(v.z, 0.f); v.w = fmaxf(v.w, 0.f);
    h[i] = v;
  }
}
__global__ void pool_accum_k(const float* __restrict__ h, const int* __restrict__ dict,
                             float* __restrict__ z, float* __restrict__ cnt, int n) {
  int gid = blockIdx.x * blockDim.x + threadIdx.x;
  int node = gid >> 5, lane = gid & 31;
  if (node >= n) return;
  int d = dict[node];
  float4 v = ((const float4*)(h + (size_t)node * HH))[lane];
  float* o = z + (size_t)d * HH + lane * 4;
  atomicAdd(o + 0, v.x); atomicAdd(o + 1, v.y);
  atomicAdd(o + 2, v.z); atomicAdd(o + 3, v.w);
  if (lane == 0) atomicAdd(&cnt[d], 1.0f);
}
__global__ void pool_div_k(float* __restrict__ z, const float* __restrict__ cnt, int n) {
  int gid = blockIdx.x * blockDim.x + threadIdx.x;
  int node = gid >> 5, lane = gid & 31;
  if (node >= n) return;
  float inv = 1.0f / fmaxf(cnt[node], 1.0f);
  float4* p = (float4*)(z + (size_t)node * HH) + lane;
  float4 v = *p;
  v.x *= inv; v.y *= inv; v.z *= inv; v.w *= inv;
  *p = v;
}
__global__ void decode_k(const float* __restrict__ z, const int* __restrict__ pos,
                         const int* __restrict__ neg, float* __restrict__ out, int ep) {
  int gid = blockIdx.x * blockDim.x + threadIdx.x;
  int edge = gid >> 5, lane = gid & 31;
  if (edge >= 2 * ep) return;
  int a, b;
  if (edge < ep) { a = pos[edge];      b = pos[ep + edge]; }
  else           { a = neg[edge - ep]; b = neg[edge]; }
  const float4* za = (const float4*)(z + (size_t)a * HH);
  const float4* zb = (const float4*)(z + (size_t)b * HH);
  float4 va = za[lane], vb = zb[lane];
  float dot = va.x * vb.x + va.y * vb.y + va.z * vb.z + va.w * vb.w;
  #pragma unroll
  for (int off = 16; off > 0; off >>= 1) dot += __shfl_xor(dot, off);
  if (lane == 0) out[edge] = dot;
}

// ================= host launch =================
extern "C" void kernel_launch(void* const* d_in, const int* in_sizes, int n_in,
                              void* d_out, int out_size, void* d_ws, size_t ws_size,
                              hipStream_t stream) {
  const float* x  = (const float*)d_in[0];
  const float* W1 = (const float*)d_in[1];
  const float* b1 = (const float*)d_in[2];
  const float* W2 = (const float*)d_in[3];
  const float* b2 = (const float*)d_in[4];
  const int* ei   = (const int*)d_in[5];
  const int* dict = (const int*)d_in[6];
  const int* pe   = (const int*)d_in[7];
  const int* ne   = (const int*)d_in[8];

  const int n  = in_sizes[0] / HH;   // 100000
  const int e  = in_sizes[5] / 2;    // 1.6M
  const int ep = in_sizes[7] / 2;    // 200000
  const int* src = ei;
  const int* dst = ei + e;

  const size_t nf = (size_t)n * HH;
  const int nbkt  = (n + 255) >> 8;                 // 391
  const int nblkE = (e + PCHUNK - 1) / PCHUNK;      // 98
  const int nblkN = (n + PCHUNK - 1) / PCHUNK;      // 7

  // fast-path ws layout:
  //   bufF  : nf floats      (edge part alias -> h1(fp32) -> h2(fp16))
  //   xw16  : nf halves      (edge blkoff alias -> xw' -> node part+blkoff alias)
  //   dinv[n], rowptr[n+1], tmp[n], esrc[e], bsum[256], gcnt[nbkt], bktbase[nbkt+1]
  float*  p0     = (float*)d_ws;
  float*  bufF   = p0;
  __half* xw16   = (__half*)(p0 + nf);
  float*  dinv   = p0 + nf + nf / 2;
  int*    rowptr = (int*)(dinv + n);
  int*    tmp    = rowptr + (n + 1);
  int*    esrc   = tmp + n;
  int*    bsum   = esrc + e;
  int*    gcnt   = bsum + 256;
  int*    bktbase = gcnt + nbkt;
  size_t need = (nf + nf / 2 + n) * sizeof(float) +
                (size_t)(3 * n + 1 + e + 256 + 2 * nbkt + 1) * sizeof(int);

  int* partE   = (int*)bufF;             // e ints (6.4 MB) <= nf floats
  int* blkoffE = (int*)xw16;             // nbkt*nblkE ints (~153 KB) <= nf halves
  int* partN   = (int*)xw16;             // n ints (400 KB), xw16 dead after conv2 gather
  int* blkoffN = partN + n;              // nbkt*nblkN ints (~11 KB)

  const int nb    = (n + 255) / 256;
  const int nb32  = (int)(((size_t)n * 32 + 255) / 256);
  const int nb64  = (int)(((size_t)n * 64 + 255) / 256);
  const int gemb  = (n + 63) / 64;
  const int deb2  = (int)(((size_t)ep * 64 + 255) / 256);   // ep waves (2 edges/wave)

  bool fast = (ws_size >= need) && (nbkt <= 512) && (n < (1 << 23)) &&
              ((size_t)e <= nf) && ((size_t)nbkt * nblkE * 2 <= nf);

  if (fast) {
    // ---- edge CSR (by dst) + dinv: bucketed 2-phase sort (packed records) ----
    hipMemsetAsync(gcnt, 0, (size_t)nbkt * sizeof(int), stream);
    part_count_k<<<nblkE, 256, 0, stream>>>(dst, e, nbkt, nblkE, gcnt, blkoffE);
    scan_bkt_k<<<1, 512, 0, stream>>>(gcnt, bktbase, nbkt, e);
    part_scatter_k<<<nblkE, 256, 0, stream>>>(src, dst, e, nbkt, nblkE, bktbase, blkoffE, partE);
    bucket_csr_k<<<nbkt, 256, 0, stream>>>(partE, bktbase, rowptr, dinv, esrc, n, e, nbkt);

    // ---- conv1: xw16 = fp16(dinv * x@W1);  h1 fp32 in bufF ----
    gemm128_v4<true><<<gemb, 256, 0, stream>>>(x, W1, dinv, xw16, n);
    gather16_k<false><<<nb64, 256, 0, stream>>>(xw16, rowptr, esrc, dinv, b1, bufF, n);
    // ---- conv2: xw16 = fp16(dinv * h1@W2);  h2 fp16 overwrites bufF region ----
    gemm128_v4<true><<<gemb, 256, 0, stream>>>(bufF, W2, dinv, xw16, n);
    __half* h2_16 = (__half*)bufF;
    gather16_k<true><<<nb64, 256, 0, stream>>>(xw16, rowptr, esrc, dinv, b2, h2_16, n);
    // xw16 now dead -> reuse for node part

    // ---- node CSR (by dict): bucketed sort (packed records) ----
    hipMemsetAsync(gcnt, 0, (size_t)nbkt * sizeof(int), stream);
    part_count_k<<<nblkN, 256, 0, stream>>>(dict, n, nbkt, nblkN, gcnt, blkoffN);
    scan_bkt_k<<<1, 512, 0, stream>>>(gcnt, bktbase, nbkt, n);
    part_scatter_idx_k<<<nblkN, 256, 0, stream>>>(dict, n, nbkt, nblkN, bktbase, blkoffN, partN);
    bucket_csr_k<<<nbkt, 256, 0, stream>>>(partN, bktbase, rowptr, nullptr, esrc, n, n, nbkt);
    // rowptr = group rowptr, esrc = nodelist

    // ---- fused pool + decode (fp16 h2) ----
    decode_fused4_k<<<deb2, 256, 0, stream>>>(h2_16, rowptr, esrc, pe, ne, (float*)d_out, ep);
  } else {
    // ---- fallback: atomic path (bufA, bufB, dinv2, cnt), all fp32 ----
    float* bufA  = (float*)d_ws;
    float* bufB  = bufA + nf;
    float* dinv2 = bufB + nf;
    float* cnt   = dinv2 + n;
    fill_deg_k<<<nb, 256, 0, stream>>>(dinv2, n);
    accum_deg_k<<<(e + 255) / 256, 256, 0, stream>>>(dst, dinv2, e);
    dinv_k<<<nb, 256, 0, stream>>>(dinv2, n);

    gemm128_v4<false><<<gemb, 256, 0, stream>>>(x, W1, nullptr, bufA, n);
    init_h_k<<<nb32, 256, 0, stream>>>(bufA, b1, dinv2, bufB, n);
    scatter_k<<<(int)(((size_t)e * 32 + 255) / 256), 256, 0, stream>>>(bufA, bufB, dinv2, src, dst, e);
    relu_k<<<nb32, 256, 0, stream>>>((float4*)bufB, n * 32);

    gemm128_v4<false><<<gemb, 256, 0, stream>>>(bufB, W2, nullptr, bufA, n);
    init_h_k<<<nb32, 256, 0, stream>>>(bufA, b2, dinv2, bufB, n);
    scatter_k<<<(int)(((size_t)e * 32 + 255) / 256), 256, 0, stream>>>(bufA, bufB, dinv2, src, dst, e);
    relu_k<<<nb32, 256, 0, stream>>>((float4*)bufB, n * 32);

    hipMemsetAsync(bufA, 0, nf * sizeof(float), stream);
    hipMemsetAsync(cnt, 0, (size_t)n * sizeof(float), stream);
    pool_accum_k<<<nb32, 256, 0, stream>>>(bufB, dict, bufA, cnt, n);
    pool_div_k<<<nb32, 256, 0, stream>>>(bufA, cnt, n);
    decode_k<<<(int)(((size_t)2 * ep * 32 + 255) / 256), 256, 0, stream>>>(
        bufA, pe, ne, (float*)d_out, ep);
  }
}

// Round 10
// 380.939 us; speedup vs baseline: 15.7640x; 1.0451x over previous
//
#include <hip/hip_runtime.h>
#include <hip/hip_fp16.h>

#define HH 128   // hidden size (both layers, and F_IN)
#define PCHUNK 16384  // items per partition block

// ================= bucketed 2-phase counting sort (edge CSR + node CSR) =================
// bucket = key >> 8 (256 keys per bucket).  nbkt <= 512, payload < 2^23 required.
// part record: (payload << 8) | (key & 255)   -- 4 bytes

__global__ __launch_bounds__(256) void part_count_k(const int* __restrict__ key, int e,
                                                    int nbkt, int nblk,
                                                    int* __restrict__ gcnt,
                                                    int* __restrict__ blkoff) {
  __shared__ int h[512];
  for (int i = threadIdx.x; i < nbkt; i += 256) h[i] = 0;
  __syncthreads();
  int start = blockIdx.x * PCHUNK;
  int cnt = e - start; if (cnt > PCHUNK) cnt = PCHUNK;
  for (int i = threadIdx.x; i < cnt; i += 256)
    atomicAdd(&h[key[start + i] >> 8], 1);
  __syncthreads();
  for (int i = threadIdx.x; i < nbkt; i += 256) {
    int c = h[i];
    if (c) blkoff[(size_t)i * nblk + blockIdx.x] = atomicAdd(&gcnt[i], c);
  }
}

__global__ __launch_bounds__(512) void scan_bkt_k(const int* __restrict__ gcnt,
                                                  int* __restrict__ bktbase, int nbkt, int e) {
  __shared__ int sc[512];
  int tid = threadIdx.x;
  int v = (tid < nbkt) ? gcnt[tid] : 0;
  sc[tid] = v;
  __syncthreads();
  for (int off = 1; off < 512; off <<= 1) {
    int t = (tid >= off) ? sc[tid - off] : 0;
    __syncthreads();
    sc[tid] += t;
    __syncthreads();
  }
  if (tid < nbkt) bktbase[tid] = sc[tid] - v;
  if (tid == 0) bktbase[nbkt] = e;
}

// payload = src[i] (edge version)
__global__ __launch_bounds__(256) void part_scatter_k(const int* __restrict__ src,
                                                      const int* __restrict__ key, int e,
                                                      int nbkt, int nblk,
                                                      const int* __restrict__ bktbase,
                                                      const int* __restrict__ blkoff,
                                                      int* __restrict__ part) {
  __shared__ int cur[512];
  for (int i = threadIdx.x; i < nbkt; i += 256)
    cur[i] = bktbase[i] + blkoff[(size_t)i * nblk + blockIdx.x];
  __syncthreads();
  int start = blockIdx.x * PCHUNK;
  int cnt = e - start; if (cnt > PCHUNK) cnt = PCHUNK;
  for (int i = threadIdx.x; i < cnt; i += 256) {
    int d = key[start + i], s = src[start + i];
    int pos = atomicAdd(&cur[d >> 8], 1);
    part[pos] = (s << 8) | (d & 255);
  }
}

// payload = global index i (node version)
__global__ __launch_bounds__(256) void part_scatter_idx_k(const int* __restrict__ key, int e,
                                                          int nbkt, int nblk,
                                                          const int* __restrict__ bktbase,
                                                          const int* __restrict__ blkoff,
                                                          int* __restrict__ part) {
  __shared__ int cur[512];
  for (int i = threadIdx.x; i < nbkt; i += 256)
    cur[i] = bktbase[i] + blkoff[(size_t)i * nblk + blockIdx.x];
  __syncthreads();
  int start = blockIdx.x * PCHUNK;
  int cnt = e - start; if (cnt > PCHUNK) cnt = PCHUNK;
  for (int i = threadIdx.x; i < cnt; i += 256) {
    int d = key[start + i];
    int pos = atomicAdd(&cur[d >> 8], 1);
    part[pos] = ((start + i) << 8) | (d & 255);
  }
}

// Per bucket (256 keys): LDS hist + scan -> rowptr, optional dinv, payload list.
__global__ __launch_bounds__(256) void bucket_csr_k(const int* __restrict__ part,
                                                    const int* __restrict__ bktbase,
                                                    int* __restrict__ rowptr,
                                                    float* __restrict__ dinv,
                                                    int* __restrict__ esrc,
                                                    int n, int e, int nbkt) {
  __shared__ int hist[256];
  __shared__ int sc[256];
  __shared__ int cur[256];
  int tid = threadIdx.x;
  int b = blockIdx.x;
  int dstbase = b << 8;
  int nloc = n - dstbase; if (nloc > 256) nloc = 256;
  int beg = bktbase[b], bend = bktbase[b + 1];

  hist[tid] = 0;
  __syncthreads();
  for (int j = beg + tid; j < bend; j += 256)
    atomicAdd(&hist[part[j] & 255], 1);
  __syncthreads();
  int v = hist[tid];
  sc[tid] = v;
  __syncthreads();
  for (int off = 1; off < 256; off <<= 1) {
    int t = (tid >= off) ? sc[tid - off] : 0;
    __syncthreads();
    sc[tid] += t;
    __syncthreads();
  }
  int excl = sc[tid] - v;
  if (tid < nloc) {
    rowptr[dstbase + tid] = beg + excl;
    cur[tid] = beg + excl;
    if (dinv) dinv[dstbase + tid] = rsqrtf((float)v + 1.0f);
  }
  __syncthreads();
  for (int j = beg + tid; j < bend; j += 256) {
    int p = part[j];
    int pos = atomicAdd(&cur[p & 255], 1);
    esrc[pos] = p >> 8;
  }
  if (b == nbkt - 1 && tid == 0) rowptr[n] = e;
}

// ========== GEMM v4: 2-phase K staging (16.6 KB LDS -> 8 blocks/CU), quarter-row threads ==========
// OUT16: write scale(i)*(A@W) as fp16 (half2-packed); else fp32.
template <bool OUT16>
__global__ __launch_bounds__(256) void gemm128_v4(const float* __restrict__ A,
                                                  const float* __restrict__ W,
                                                  const float* __restrict__ dscale,
                                                  void* __restrict__ out, int n) {
  __shared__ float As[64][65];
  const int tid = threadIdx.x;
  const int rbase = blockIdx.x * 64;
  const int vrows = (n - rbase) < 64 ? (n - rbase) : 64;

  const int r = tid & 63;
  const int q = __builtin_amdgcn_readfirstlane(tid >> 6);
  const float* Wq = W + q * 32;

  float4 acc[8];
  #pragma unroll
  for (int c = 0; c < 8; ++c) acc[c] = make_float4(0.f, 0.f, 0.f, 0.f);

  #pragma unroll
  for (int ph = 0; ph < 2; ++ph) {
    if (ph) __syncthreads();
    #pragma unroll
    for (int j = 0; j < 4; ++j) {
      int f = tid + 256 * j;
      int rr = f >> 4, c4 = f & 15;
      float4 v = (rr < vrows)
          ? ((const float4*)(A + (size_t)(rbase + rr) * HH + ph * 64))[c4]
          : make_float4(0.f, 0.f, 0.f, 0.f);
      As[rr][c4 * 4 + 0] = v.x;
      As[rr][c4 * 4 + 1] = v.y;
      As[rr][c4 * 4 + 2] = v.z;
      As[rr][c4 * 4 + 3] = v.w;
    }
    __syncthreads();

    #pragma unroll 4
    for (int kk = 0; kk < 64; ++kk) {
      float a = As[r][kk];
      const float4* Wr = (const float4*)(Wq + (size_t)(ph * 64 + kk) * HH);
      #pragma unroll
      for (int c = 0; c < 8; ++c) {
        float4 w = Wr[c];
        acc[c].x += a * w.x; acc[c].y += a * w.y;
        acc[c].z += a * w.z; acc[c].w += a * w.w;
      }
    }
  }

  int row = rbase + r;
  if (row < n) {
    float s = dscale ? dscale[row] : 1.0f;
    if (OUT16) {
      uint2* o = (uint2*)((__half*)out + (size_t)row * HH) + q * 8;
      #pragma unroll
      for (int c = 0; c < 8; ++c) {
        __half2 h0 = __float22half2_rn(make_float2(acc[c].x * s, acc[c].y * s));
        __half2 h1 = __float22half2_rn(make_float2(acc[c].z * s, acc[c].w * s));
        uint2 u;
        u.x = *reinterpret_cast<unsigned*>(&h0);
        u.y = *reinterpret_cast<unsigned*>(&h1);
        o[c] = u;
      }
    } else {
      float4* o = (float4*)((float*)out + (size_t)row * HH + q * 32);
      #pragma unroll
      for (int c = 0; c < 8; ++c) {
        acc[c].x *= s; acc[c].y *= s; acc[c].z *= s; acc[c].w *= s;
        o[c] = acc[c];
      }
    }
  }
}

// ==== gather conv (fp16 messages): h[d]=relu(b+dinv[d]*(self'+sum xw16[s])) ====
// HOUT16: write h as fp16 (for conv2, decode-only consumer); else fp32.
template <bool HOUT16>
__global__ __launch_bounds__(256) void gather16_k(const __half* __restrict__ xw16,
                                                  const int* __restrict__ rowptr,
                                                  const int* __restrict__ esrc,
                                                  const float* __restrict__ dinv,
                                                  const float* __restrict__ bias,
                                                  void* __restrict__ h, int n) {
  int wid = (int)((blockIdx.x * (size_t)blockDim.x + threadIdx.x) >> 6);
  int lane = threadIdx.x & 63;
  if (wid >= n) return;
  int beg = rowptr[wid], end = rowptr[wid + 1];
  int half = lane >> 5, l32 = lane & 31;
  const uint2* base = (const uint2*)xw16 + l32;   // row = 32 uint2
  float4 acc = make_float4(0.f, 0.f, 0.f, 0.f);

  for (int j0 = beg; j0 < end; j0 += 64) {
    int myj = j0 + lane;
    int sv = (myj < end) ? esrc[myj] : 0;
    int cnt = end - j0; if (cnt > 64) cnt = 64;
    int k = 0;
    for (; k + 8 <= cnt; k += 8) {
      #pragma unroll
      for (int p = 0; p < 4; ++p) {
        int sa = __builtin_amdgcn_readlane(sv, k + 2 * p);
        int sb = __builtin_amdgcn_readlane(sv, k + 2 * p + 1);
        unsigned off = (unsigned)(half ? sb : sa) << 5;
        uint2 u = base[off];
        float2 f0 = __half22float2(*reinterpret_cast<__half2*>(&u.x));
        float2 f1 = __half22float2(*reinterpret_cast<__half2*>(&u.y));
        acc.x += f0.x; acc.y += f0.y; acc.z += f1.x; acc.w += f1.y;
      }
    }
    for (; k + 2 <= cnt; k += 2) {
      int sa = __builtin_amdgcn_readlane(sv, k);
      int sb = __builtin_amdgcn_readlane(sv, k + 1);
      unsigned off = (unsigned)(half ? sb : sa) << 5;
      uint2 u = base[off];
      float2 f0 = __half22float2(*reinterpret_cast<__half2*>(&u.x));
      float2 f1 = __half22float2(*reinterpret_cast<__half2*>(&u.y));
      acc.x += f0.x; acc.y += f0.y; acc.z += f1.x; acc.w += f1.y;
    }
    if (k < cnt) {
      int sa = __builtin_amdgcn_readlane(sv, k);
      if (half == 0) {
        uint2 u = base[(unsigned)sa << 5];
        float2 f0 = __half22float2(*reinterpret_cast<__half2*>(&u.x));
        float2 f1 = __half22float2(*reinterpret_cast<__half2*>(&u.y));
        acc.x += f0.x; acc.y += f0.y; acc.z += f1.x; acc.w += f1.y;
      }
    }
  }
  acc.x += __shfl_xor(acc.x, 32);
  acc.y += __shfl_xor(acc.y, 32);
  acc.z += __shfl_xor(acc.z, 32);
  acc.w += __shfl_xor(acc.w, 32);
  if (half == 0) {
    uint2 u = base[(unsigned)wid << 5];
    float2 s0 = __half22float2(*reinterpret_cast<__half2*>(&u.x));
    float2 s1 = __half22float2(*reinterpret_cast<__half2*>(&u.y));
    float di = dinv[wid];
    float4 bb = ((const float4*)bias)[l32];
    float4 o;
    o.x = fmaxf(bb.x + di * (acc.x + s0.x), 0.f);
    o.y = fmaxf(bb.y + di * (acc.y + s0.y), 0.f);
    o.z = fmaxf(bb.z + di * (acc.z + s1.x), 0.f);
    o.w = fmaxf(bb.w + di * (acc.w + s1.y), 0.f);
    if (HOUT16) {
      __half2 p0 = __float22half2_rn(make_float2(o.x, o.y));
      __half2 p1 = __float22half2_rn(make_float2(o.z, o.w));
      uint2 w;
      w.x = *reinterpret_cast<unsigned*>(&p0);
      w.y = *reinterpret_cast<unsigned*>(&p1);
      ((uint2*)h)[((size_t)wid << 5) + l32] = w;
    } else {
      ((float4*)h)[((size_t)wid << 5) + l32] = o;
    }
  }
}

// ====== pool (fp16 -> fp16): z[g] = mean over members of h2, 32-lane subgroup per group ======
__global__ __launch_bounds__(256) void pool16_k(const __half* __restrict__ h2,
                                                const int* __restrict__ rowptr,
                                                const int* __restrict__ nodelist,
                                                __half* __restrict__ z, int n) {
  int gid = blockIdx.x * blockDim.x + threadIdx.x;
  int g = gid >> 5, l32 = gid & 31;
  if (g >= n) return;
  int beg = rowptr[g], end = rowptr[g + 1];
  const uint2* h4 = (const uint2*)h2;
  float4 a = make_float4(0.f, 0.f, 0.f, 0.f);
  for (int j = beg; j < end; ++j) {
    int m = nodelist[j];
    uint2 u = h4[((size_t)m << 5) + l32];
    float2 f0 = __half22float2(*reinterpret_cast<__half2*>(&u.x));
    float2 f1 = __half22float2(*reinterpret_cast<__half2*>(&u.y));
    a.x += f0.x; a.y += f0.y; a.z += f1.x; a.w += f1.y;
  }
  float inv = 1.0f / fmaxf((float)(end - beg), 1.0f);
  __half2 p0 = __float22half2_rn(make_float2(a.x * inv, a.y * inv));
  __half2 p1 = __float22half2_rn(make_float2(a.z * inv, a.w * inv));
  uint2 w;
  w.x = *reinterpret_cast<unsigned*>(&p0);
  w.y = *reinterpret_cast<unsigned*>(&p1);
  ((uint2*)z)[((size_t)g << 5) + l32] = w;
}

// ====== decode (fp16 z): logits[e] = dot(z[a], z[b]); 32 lanes per edge ======
__global__ __launch_bounds__(256) void decode16_k(const __half* __restrict__ z,
                                                  const int* __restrict__ pos,
                                                  const int* __restrict__ neg,
                                                  float* __restrict__ out, int ep) {
  int gid = blockIdx.x * blockDim.x + threadIdx.x;
  int edge = gid >> 5, l32 = gid & 31;
  if (edge >= 2 * ep) return;
  int a, b;
  if (edge < ep) { a = pos[edge];      b = pos[ep + edge]; }
  else           { int t = edge - ep; a = neg[t]; b = neg[ep + t]; }
  const uint2* z4 = (const uint2*)z;
  uint2 ua = z4[((size_t)a << 5) + l32];
  uint2 ub = z4[((size_t)b << 5) + l32];
  float2 fa0 = __half22float2(*reinterpret_cast<__half2*>(&ua.x));
  float2 fa1 = __half22float2(*reinterpret_cast<__half2*>(&ua.y));
  float2 fb0 = __half22float2(*reinterpret_cast<__half2*>(&ub.x));
  float2 fb1 = __half22float2(*reinterpret_cast<__half2*>(&ub.y));
  float dot = fa0.x * fb0.x + fa0.y * fb0.y + fa1.x * fb1.x + fa1.y * fb1.y;
  #pragma unroll
  for (int off = 16; off > 0; off >>= 1) dot += __shfl_xor(dot, off);
  if (l32 == 0) out[edge] = dot;
}

// ================= fallback path (small ws): atomic version =================
__global__ void fill_deg_k(float* __restrict__ deg, int n) {
  int i = blockIdx.x * blockDim.x + threadIdx.x;
  if (i < n) deg[i] = 1.0f;
}
__global__ void accum_deg_k(const int* __restrict__ dst, float* __restrict__ deg, int e) {
  int i = blockIdx.x * blockDim.x + threadIdx.x;
  if (i < e) atomicAdd(&deg[dst[i]], 1.0f);
}
__global__ void dinv_k(float* __restrict__ deg, int n) {
  int i = blockIdx.x * blockDim.x + threadIdx.x;
  if (i < n) deg[i] = rsqrtf(deg[i]);
}
__global__ void init_h_k(const float* __restrict__ xw, const float* __restrict__ bias,
                         const float* __restrict__ dinv, float* __restrict__ h, int n) {
  int gid = blockIdx.x * blockDim.x + threadIdx.x;
  int node = gid >> 5, c4 = gid & 31;
  if (node >= n) return;
  float di = dinv[node];
  float nm = di * di;
  float4 v = ((const float4*)(xw + (size_t)node * HH))[c4];
  float4 b = ((const float4*)bias)[c4];
  ((float4*)(h + (size_t)node * HH))[c4] =
      make_float4(b.x + nm * v.x, b.y + nm * v.y, b.z + nm * v.z, b.w + nm * v.w);
}
__global__ void scatter_k(const float* __restrict__ xw, float* __restrict__ h,
                          const float* __restrict__ dinv, const int* __restrict__ src,
                          const int* __restrict__ dst, int e) {
  int gid = blockIdx.x * blockDim.x + threadIdx.x;
  int edge = gid >> 5, lane = gid & 31;
  if (edge >= e) return;
  int s = src[edge], d = dst[edge];
  float norm = dinv[s] * dinv[d];
  float4 v = ((const float4*)(xw + (size_t)s * HH))[lane];
  float* o = h + (size_t)d * HH + lane * 4;
  atomicAdd(o + 0, norm * v.x);
  atomicAdd(o + 1, norm * v.y);
  atomicAdd(o + 2, norm * v.z);
  atomicAdd(o + 3, norm * v.w);
}
__global__ void relu_k(float4* __restrict__ h, int n4) {
  int i = blockIdx.x * blockDim.x + threadIdx.x;
  if (i < n4) {
    float4 v = h[i];
    v.x = fmaxf(v.x, 0.f); v.y = fmaxf(v.y, 0.f);
    v.z = fmaxf(v.z, 0.f); v.w = fmaxf(v.w, 0.f);
    h[i] = v;
  }
}
__global__ void pool_accum_k(const float* __restrict__ h, const int* __restrict__ dict,
                             float* __restrict__ z, float* __restrict__ cnt, int n) {
  int gid = blockIdx.x * blockDim.x + threadIdx.x;
  int node = gid >> 5, lane = gid & 31;
  if (node >= n) return;
  int d = dict[node];
  float4 v = ((const float4*)(h + (size_t)node * HH))[lane];
  float* o = z + (size_t)d * HH + lane * 4;
  atomicAdd(o + 0, v.x); atomicAdd(o + 1, v.y);
  atomicAdd(o + 2, v.z); atomicAdd(o + 3, v.w);
  if (lane == 0) atomicAdd(&cnt[d], 1.0f);
}
__global__ void pool_div_k(float* __restrict__ z, const float* __restrict__ cnt, int n) {
  int gid = blockIdx.x * blockDim.x + threadIdx.x;
  int node = gid >> 5, lane = gid & 31;
  if (node >= n) return;
  float inv = 1.0f / fmaxf(cnt[node], 1.0f);
  float4* p = (float4*)(z + (size_t)node * HH) + lane;
  float4 v = *p;
  v.x *= inv; v.y *= inv; v.z *= inv; v.w *= inv;
  *p = v;
}
__global__ void decode_k(const float* __restrict__ z, const int* __restrict__ pos,
                         const int* __restrict__ neg, float* __restrict__ out, int ep) {
  int gid = blockIdx.x * blockDim.x + threadIdx.x;
  int edge = gid >> 5, lane = gid & 31;
  if (edge >= 2 * ep) return;
  int a, b;
  if (edge < ep) { a = pos[edge];      b = pos[ep + edge]; }
  else           { a = neg[edge - ep]; b = neg[edge]; }
  const float4* za = (const float4*)(z + (size_t)a * HH);
  const float4* zb = (const float4*)(z + (size_t)b * HH);
  float4 va = za[lane], vb = zb[lane];
  float dot = va.x * vb.x + va.y * vb.y + va.z * vb.z + va.w * vb.w;
  #pragma unroll
  for (int off = 16; off > 0; off >>= 1) dot += __shfl_xor(dot, off);
  if (lane == 0) out[edge] = dot;
}

// ================= host launch =================
extern "C" void kernel_launch(void* const* d_in, const int* in_sizes, int n_in,
                              void* d_out, int out_size, void* d_ws, size_t ws_size,
                              hipStream_t stream) {
  const float* x  = (const float*)d_in[0];
  const float* W1 = (const float*)d_in[1];
  const float* b1 = (const float*)d_in[2];
  const float* W2 = (const float*)d_in[3];
  const float* b2 = (const float*)d_in[4];
  const int* ei   = (const int*)d_in[5];
  const int* dict = (const int*)d_in[6];
  const int* pe   = (const int*)d_in[7];
  const int* ne   = (const int*)d_in[8];

  const int n  = in_sizes[0] / HH;   // 100000
  const int e  = in_sizes[5] / 2;    // 1.6M
  const int ep = in_sizes[7] / 2;    // 200000
  const int* src = ei;
  const int* dst = ei + e;

  const size_t nf = (size_t)n * HH;
  const int nbkt  = (n + 255) >> 8;                 // 391
  const int nblkE = (e + PCHUNK - 1) / PCHUNK;      // 98
  const int nblkN = (n + PCHUNK - 1) / PCHUNK;      // 7

  // fast-path ws layout:
  //   bufF  : nf floats      (edge part alias -> h1(fp32) -> h2(fp16) [lower half]
  //                                              + node part/blkoff [upper half])
  //   xw16  : nf halves      (edge blkoff alias -> xw' -> z(fp16))
  //   dinv[n], rowptr[n+1], tmp[n], esrc[e], bsum[256], gcnt[nbkt], bktbase[nbkt+1]
  float*  p0     = (float*)d_ws;
  float*  bufF   = p0;
  __half* xw16   = (__half*)(p0 + nf);
  float*  dinv   = p0 + nf + nf / 2;
  int*    rowptr = (int*)(dinv + n);
  int*    tmp    = rowptr + (n + 1);
  int*    esrc   = tmp + n;
  int*    bsum   = esrc + e;
  int*    gcnt   = bsum + 256;
  int*    bktbase = gcnt + nbkt;
  size_t need = (nf + nf / 2 + n) * sizeof(float) +
                (size_t)(3 * n + 1 + e + 256 + 2 * nbkt + 1) * sizeof(int);

  int* partE   = (int*)bufF;               // e ints (6.4 MB) <= nf floats
  int* blkoffE = (int*)xw16;               // nbkt*nblkE ints (~153 KB) <= nf halves
  int* partN   = (int*)(bufF + nf / 2);    // n ints (400 KB), upper half of bufF (dead after conv2)
  int* blkoffN = partN + n;                // nbkt*nblkN ints (~11 KB)

  const int nb    = (n + 255) / 256;
  const int nb32  = (int)(((size_t)n * 32 + 255) / 256);
  const int nb64  = (int)(((size_t)n * 64 + 255) / 256);
  const int gemb  = (n + 63) / 64;
  const int deb   = (int)(((size_t)2 * ep * 32 + 255) / 256);

  bool fast = (ws_size >= need) && (nbkt <= 512) && (n < (1 << 23)) &&
              ((size_t)e <= nf) && ((size_t)nbkt * nblkE * 2 <= nf) &&
              ((size_t)(n + nbkt * nblkN) * 2 <= nf);

  if (fast) {
    // ---- edge CSR (by dst) + dinv: bucketed 2-phase sort (packed records) ----
    hipMemsetAsync(gcnt, 0, (size_t)nbkt * sizeof(int), stream);
    part_count_k<<<nblkE, 256, 0, stream>>>(dst, e, nbkt, nblkE, gcnt, blkoffE);
    scan_bkt_k<<<1, 512, 0, stream>>>(gcnt, bktbase, nbkt, e);
    part_scatter_k<<<nblkE, 256, 0, stream>>>(src, dst, e, nbkt, nblkE, bktbase, blkoffE, partE);
    bucket_csr_k<<<nbkt, 256, 0, stream>>>(partE, bktbase, rowptr, dinv, esrc, n, e, nbkt);

    // ---- conv1: xw16 = fp16(dinv * x@W1);  h1 fp32 in bufF ----
    gemm128_v4<true><<<gemb, 256, 0, stream>>>(x, W1, dinv, xw16, n);
    gather16_k<false><<<nb64, 256, 0, stream>>>(xw16, rowptr, esrc, dinv, b1, bufF, n);
    // ---- conv2: xw16 = fp16(dinv * h1@W2);  h2 fp16 in lower half of bufF ----
    gemm128_v4<true><<<gemb, 256, 0, stream>>>(bufF, W2, dinv, xw16, n);
    __half* h2_16 = (__half*)bufF;
    gather16_k<true><<<nb64, 256, 0, stream>>>(xw16, rowptr, esrc, dinv, b2, h2_16, n);
    // xw16 dead -> becomes z; upper half of bufF free -> partN

    // ---- node CSR (by dict): bucketed sort (packed records) ----
    hipMemsetAsync(gcnt, 0, (size_t)nbkt * sizeof(int), stream);
    part_count_k<<<nblkN, 256, 0, stream>>>(dict, n, nbkt, nblkN, gcnt, blkoffN);
    scan_bkt_k<<<1, 512, 0, stream>>>(gcnt, bktbase, nbkt, n);
    part_scatter_idx_k<<<nblkN, 256, 0, stream>>>(dict, n, nbkt, nblkN, bktbase, blkoffN, partN);
    bucket_csr_k<<<nbkt, 256, 0, stream>>>(partN, bktbase, rowptr, nullptr, esrc, n, n, nbkt);
    // rowptr = group rowptr, esrc = nodelist

    // ---- pool (fp16 z, one pass over groups) then plain dot decode ----
    __half* z16 = xw16;
    pool16_k<<<nb32, 256, 0, stream>>>(h2_16, rowptr, esrc, z16, n);
    decode16_k<<<deb, 256, 0, stream>>>(z16, pe, ne, (float*)d_out, ep);
  } else {
    // ---- fallback: atomic path (bufA, bufB, dinv2, cnt), all fp32 ----
    float* bufA  = (float*)d_ws;
    float* bufB  = bufA + nf;
    float* dinv2 = bufB + nf;
    float* cnt   = dinv2 + n;
    fill_deg_k<<<nb, 256, 0, stream>>>(dinv2, n);
    accum_deg_k<<<(e + 255) / 256, 256, 0, stream>>>(dst, dinv2, e);
    dinv_k<<<nb, 256, 0, stream>>>(dinv2, n);

    gemm128_v4<false><<<gemb, 256, 0, stream>>>(x, W1, nullptr, bufA, n);
    init_h_k<<<nb32, 256, 0, stream>>>(bufA, b1, dinv2, bufB, n);
    scatter_k<<<(int)(((size_t)e * 32 + 255) / 256), 256, 0, stream>>>(bufA, bufB, dinv2, src, dst, e);
    relu_k<<<nb32, 256, 0, stream>>>((float4*)bufB, n * 32);

    gemm128_v4<false><<<gemb, 256, 0, stream>>>(bufB, W2, nullptr, bufA, n);
    init_h_k<<<nb32, 256, 0, stream>>>(bufA, b2, dinv2, bufB, n);
    scatter_k<<<(int)(((size_t)e * 32 + 255) / 256), 256, 0, stream>>>(bufA, bufB, dinv2, src, dst, e);
    relu_k<<<nb32, 256, 0, stream>>>((float4*)bufB, n * 32);

    hipMemsetAsync(bufA, 0, nf * sizeof(float), stream);
    hipMemsetAsync(cnt, 0, (size_t)n * sizeof(float), stream);
    pool_accum_k<<<nb32, 256, 0, stream>>>(bufB, dict, bufA, cnt, n);
    pool_div_k<<<nb32, 256, 0, stream>>>(bufA, cnt, n);
    decode_k<<<(int)(((size_t)2 * ep * 32 + 255) / 256), 256, 0, stream>>>(
        bufA, pe, ne, (float*)d_out, ep);
  }
}

// Round 11
// 333.255 us; speedup vs baseline: 18.0196x; 1.1431x over previous
//
#include <hip/hip_runtime.h>
#include <hip/hip_fp16.h>
#include <type_traits>

#define HH 128   // hidden size (both layers, and F_IN)

// ================= bucketed 2-phase counting sort (edge CSR + node CSR) =================
// bucket = key >> 8 (256 keys per bucket).  nbkt <= 512, payload < 2^23 required.
// part record: (payload << 8) | (key & 255)   -- 4 bytes

__global__ __launch_bounds__(256) void part_count_k(const int* __restrict__ key, int e,
                                                    int chunk, int nbkt, int nblk,
                                                    int* __restrict__ gcnt,
                                                    int* __restrict__ blkoff) {
  __shared__ int h[512];
  for (int i = threadIdx.x; i < nbkt; i += 256) h[i] = 0;
  __syncthreads();
  int start = blockIdx.x * chunk;
  int cnt = e - start; if (cnt > chunk) cnt = chunk;
  for (int i = threadIdx.x; i < cnt; i += 256)
    atomicAdd(&h[key[start + i] >> 8], 1);
  __syncthreads();
  for (int i = threadIdx.x; i < nbkt; i += 256) {
    int c = h[i];
    if (c) blkoff[(size_t)i * nblk + blockIdx.x] = atomicAdd(&gcnt[i], c);
  }
}

__global__ __launch_bounds__(512) void scan_bkt_k(const int* __restrict__ gcnt,
                                                  int* __restrict__ bktbase, int nbkt, int e) {
  __shared__ int sc[512];
  int tid = threadIdx.x;
  int v = (tid < nbkt) ? gcnt[tid] : 0;
  sc[tid] = v;
  __syncthreads();
  for (int off = 1; off < 512; off <<= 1) {
    int t = (tid >= off) ? sc[tid - off] : 0;
    __syncthreads();
    sc[tid] += t;
    __syncthreads();
  }
  if (tid < nbkt) bktbase[tid] = sc[tid] - v;
  if (tid == 0) bktbase[nbkt] = e;
}

// payload = src[i] (edge version)
__global__ __launch_bounds__(256) void part_scatter_k(const int* __restrict__ src,
                                                      const int* __restrict__ key, int e,
                                                      int chunk, int nbkt, int nblk,
                                                      const int* __restrict__ bktbase,
                                                      const int* __restrict__ blkoff,
                                                      int* __restrict__ part) {
  __shared__ int cur[512];
  for (int i = threadIdx.x; i < nbkt; i += 256)
    cur[i] = bktbase[i] + blkoff[(size_t)i * nblk + blockIdx.x];
  __syncthreads();
  int start = blockIdx.x * chunk;
  int cnt = e - start; if (cnt > chunk) cnt = chunk;
  for (int i = threadIdx.x; i < cnt; i += 256) {
    int d = key[start + i], s = src[start + i];
    int pos = atomicAdd(&cur[d >> 8], 1);
    part[pos] = (s << 8) | (d & 255);
  }
}

// payload = global index i (node version)
__global__ __launch_bounds__(256) void part_scatter_idx_k(const int* __restrict__ key, int e,
                                                          int chunk, int nbkt, int nblk,
                                                          const int* __restrict__ bktbase,
                                                          const int* __restrict__ blkoff,
                                                          int* __restrict__ part) {
  __shared__ int cur[512];
  for (int i = threadIdx.x; i < nbkt; i += 256)
    cur[i] = bktbase[i] + blkoff[(size_t)i * nblk + blockIdx.x];
  __syncthreads();
  int start = blockIdx.x * chunk;
  int cnt = e - start; if (cnt > chunk) cnt = chunk;
  for (int i = threadIdx.x; i < cnt; i += 256) {
    int d = key[start + i];
    int pos = atomicAdd(&cur[d >> 8], 1);
    part[pos] = ((start + i) << 8) | (d & 255);
  }
}

// Per bucket (256 keys): LDS hist + scan -> rowptr, optional dinv, payload list.
__global__ __launch_bounds__(256) void bucket_csr_k(const int* __restrict__ part,
                                                    const int* __restrict__ bktbase,
                                                    int* __restrict__ rowptr,
                                                    float* __restrict__ dinv,
                                                    int* __restrict__ esrc,
                                                    int n, int e, int nbkt) {
  __shared__ int hist[256];
  __shared__ int sc[256];
  __shared__ int cur[256];
  int tid = threadIdx.x;
  int b = blockIdx.x;
  int dstbase = b << 8;
  int nloc = n - dstbase; if (nloc > 256) nloc = 256;
  int beg = bktbase[b], bend = bktbase[b + 1];

  hist[tid] = 0;
  __syncthreads();
  for (int j = beg + tid; j < bend; j += 256)
    atomicAdd(&hist[part[j] & 255], 1);
  __syncthreads();
  int v = hist[tid];
  sc[tid] = v;
  __syncthreads();
  for (int off = 1; off < 256; off <<= 1) {
    int t = (tid >= off) ? sc[tid - off] : 0;
    __syncthreads();
    sc[tid] += t;
    __syncthreads();
  }
  int excl = sc[tid] - v;
  if (tid < nloc) {
    rowptr[dstbase + tid] = beg + excl;
    cur[tid] = beg + excl;
    if (dinv) dinv[dstbase + tid] = rsqrtf((float)v + 1.0f);
  }
  __syncthreads();
  for (int j = beg + tid; j < bend; j += 256) {
    int p = part[j];
    int pos = atomicAdd(&cur[p & 255], 1);
    esrc[pos] = p >> 8;
  }
  if (b == nbkt - 1 && tid == 0) rowptr[n] = e;
}

// ========== GEMM v5: 2-phase K staging, quarter-row threads; input fp32 or fp16 ==========
// OUT16: write scale(i)*(A@W) as fp16 (half2-packed); else fp32.
template <typename TIN, bool OUT16>
__global__ __launch_bounds__(256) void gemm128_v5(const TIN* __restrict__ A,
                                                  const float* __restrict__ W,
                                                  const float* __restrict__ dscale,
                                                  void* __restrict__ out, int n) {
  __shared__ float As[64][65];
  const int tid = threadIdx.x;
  const int rbase = blockIdx.x * 64;
  const int vrows = (n - rbase) < 64 ? (n - rbase) : 64;

  const int r = tid & 63;
  const int q = __builtin_amdgcn_readfirstlane(tid >> 6);
  const float* Wq = W + q * 32;

  float4 acc[8];
  #pragma unroll
  for (int c = 0; c < 8; ++c) acc[c] = make_float4(0.f, 0.f, 0.f, 0.f);

  #pragma unroll
  for (int ph = 0; ph < 2; ++ph) {
    if (ph) __syncthreads();
    if (std::is_same<TIN, __half>::value) {
      // 64 rows x 64 halves per phase = 512 uint4; 2 per thread
      #pragma unroll
      for (int j = 0; j < 2; ++j) {
        int f = tid + 256 * j;
        int rr = f >> 3, c8 = f & 7;
        uint4 u = make_uint4(0u, 0u, 0u, 0u);
        if (rr < vrows)
          u = ((const uint4*)((const __half*)A + (size_t)(rbase + rr) * HH + ph * 64))[c8];
        __half2* hp = (__half2*)&u;
        #pragma unroll
        for (int t = 0; t < 4; ++t) {
          float2 f2 = __half22float2(hp[t]);
          As[rr][c8 * 8 + 2 * t + 0] = f2.x;
          As[rr][c8 * 8 + 2 * t + 1] = f2.y;
        }
      }
    } else {
      // 64 rows x 64 floats per phase = 1024 float4; 4 per thread
      #pragma unroll
      for (int j = 0; j < 4; ++j) {
        int f = tid + 256 * j;
        int rr = f >> 4, c4 = f & 15;
        float4 v = (rr < vrows)
            ? ((const float4*)((const float*)A + (size_t)(rbase + rr) * HH + ph * 64))[c4]
            : make_float4(0.f, 0.f, 0.f, 0.f);
        As[rr][c4 * 4 + 0] = v.x;
        As[rr][c4 * 4 + 1] = v.y;
        As[rr][c4 * 4 + 2] = v.z;
        As[rr][c4 * 4 + 3] = v.w;
      }
    }
    __syncthreads();

    #pragma unroll 4
    for (int kk = 0; kk < 64; ++kk) {
      float a = As[r][kk];
      const float4* Wr = (const float4*)(Wq + (size_t)(ph * 64 + kk) * HH);
      #pragma unroll
      for (int c = 0; c < 8; ++c) {
        float4 w = Wr[c];
        acc[c].x += a * w.x; acc[c].y += a * w.y;
        acc[c].z += a * w.z; acc[c].w += a * w.w;
      }
    }
  }

  int row = rbase + r;
  if (row < n) {
    float s = dscale ? dscale[row] : 1.0f;
    if (OUT16) {
      uint2* o = (uint2*)((__half*)out + (size_t)row * HH) + q * 8;
      #pragma unroll
      for (int c = 0; c < 8; ++c) {
        __half2 h0 = __float22half2_rn(make_float2(acc[c].x * s, acc[c].y * s));
        __half2 h1 = __float22half2_rn(make_float2(acc[c].z * s, acc[c].w * s));
        uint2 u;
        u.x = *reinterpret_cast<unsigned*>(&h0);
        u.y = *reinterpret_cast<unsigned*>(&h1);
        o[c] = u;
      }
    } else {
      float4* o = (float4*)((float*)out + (size_t)row * HH + q * 32);
      #pragma unroll
      for (int c = 0; c < 8; ++c) {
        acc[c].x *= s; acc[c].y *= s; acc[c].z *= s; acc[c].w *= s;
        o[c] = acc[c];
      }
    }
  }
}

// ==== gather conv (fp16 messages): h[d]=relu(b+dinv[d]*(self'+sum xw16[s])) ====
// HOUT16: write h as fp16; else fp32.
template <bool HOUT16>
__global__ __launch_bounds__(256) void gather16_k(const __half* __restrict__ xw16,
                                                  const int* __restrict__ rowptr,
                                                  const int* __restrict__ esrc,
                                                  const float* __restrict__ dinv,
                                                  const float* __restrict__ bias,
                                                  void* __restrict__ h, int n) {
  int wid = (int)((blockIdx.x * (size_t)blockDim.x + threadIdx.x) >> 6);
  int lane = threadIdx.x & 63;
  if (wid >= n) return;
  int beg = rowptr[wid], end = rowptr[wid + 1];
  int half = lane >> 5, l32 = lane & 31;
  const uint2* base = (const uint2*)xw16 + l32;   // row = 32 uint2
  float4 acc = make_float4(0.f, 0.f, 0.f, 0.f);

  for (int j0 = beg; j0 < end; j0 += 64) {
    int myj = j0 + lane;
    int sv = (myj < end) ? esrc[myj] : 0;
    int cnt = end - j0; if (cnt > 64) cnt = 64;
    int k = 0;
    for (; k + 8 <= cnt; k += 8) {
      #pragma unroll
      for (int p = 0; p < 4; ++p) {
        int sa = __builtin_amdgcn_readlane(sv, k + 2 * p);
        int sb = __builtin_amdgcn_readlane(sv, k + 2 * p + 1);
        unsigned off = (unsigned)(half ? sb : sa) << 5;
        uint2 u = base[off];
        float2 f0 = __half22float2(*reinterpret_cast<__half2*>(&u.x));
        float2 f1 = __half22float2(*reinterpret_cast<__half2*>(&u.y));
        acc.x += f0.x; acc.y += f0.y; acc.z += f1.x; acc.w += f1.y;
      }
    }
    for (; k + 2 <= cnt; k += 2) {
      int sa = __builtin_amdgcn_readlane(sv, k);
      int sb = __builtin_amdgcn_readlane(sv, k + 1);
      unsigned off = (unsigned)(half ? sb : sa) << 5;
      uint2 u = base[off];
      float2 f0 = __half22float2(*reinterpret_cast<__half2*>(&u.x));
      float2 f1 = __half22float2(*reinterpret_cast<__half2*>(&u.y));
      acc.x += f0.x; acc.y += f0.y; acc.z += f1.x; acc.w += f1.y;
    }
    if (k < cnt) {
      int sa = __builtin_amdgcn_readlane(sv, k);
      if (half == 0) {
        uint2 u = base[(unsigned)sa << 5];
        float2 f0 = __half22float2(*reinterpret_cast<__half2*>(&u.x));
        float2 f1 = __half22float2(*reinterpret_cast<__half2*>(&u.y));
        acc.x += f0.x; acc.y += f0.y; acc.z += f1.x; acc.w += f1.y;
      }
    }
  }
  acc.x += __shfl_xor(acc.x, 32);
  acc.y += __shfl_xor(acc.y, 32);
  acc.z += __shfl_xor(acc.z, 32);
  acc.w += __shfl_xor(acc.w, 32);
  if (half == 0) {
    uint2 u = base[(unsigned)wid << 5];
    float2 s0 = __half22float2(*reinterpret_cast<__half2*>(&u.x));
    float2 s1 = __half22float2(*reinterpret_cast<__half2*>(&u.y));
    float di = dinv[wid];
    float4 bb = ((const float4*)bias)[l32];
    float4 o;
    o.x = fmaxf(bb.x + di * (acc.x + s0.x), 0.f);
    o.y = fmaxf(bb.y + di * (acc.y + s0.y), 0.f);
    o.z = fmaxf(bb.z + di * (acc.z + s1.x), 0.f);
    o.w = fmaxf(bb.w + di * (acc.w + s1.y), 0.f);
    if (HOUT16) {
      __half2 p0 = __float22half2_rn(make_float2(o.x, o.y));
      __half2 p1 = __float22half2_rn(make_float2(o.z, o.w));
      uint2 w;
      w.x = *reinterpret_cast<unsigned*>(&p0);
      w.y = *reinterpret_cast<unsigned*>(&p1);
      ((uint2*)h)[((size_t)wid << 5) + l32] = w;
    } else {
      ((float4*)h)[((size_t)wid << 5) + l32] = o;
    }
  }
}

// ====== pool (fp16 -> fp16): z[g] = mean over members; 16-lane subgroup, uint4/lane ======
__global__ __launch_bounds__(256) void pool16_k(const __half* __restrict__ h2,
                                                const int* __restrict__ rowptr,
                                                const int* __restrict__ nodelist,
                                                __half* __restrict__ z, int n) {
  int gid = blockIdx.x * blockDim.x + threadIdx.x;
  int g = gid >> 4, l16 = gid & 15;
  if (g >= n) return;
  int beg = rowptr[g], end = rowptr[g + 1];
  const uint4* h4 = (const uint4*)h2;   // row = 16 uint4
  float a[8];
  #pragma unroll
  for (int t = 0; t < 8; ++t) a[t] = 0.f;
  for (int j = beg; j < end; ++j) {
    int m = nodelist[j];
    uint4 u = h4[((size_t)m << 4) + l16];
    __half2* hp = (__half2*)&u;
    #pragma unroll
    for (int t = 0; t < 4; ++t) {
      float2 f2 = __half22float2(hp[t]);
      a[2 * t + 0] += f2.x;
      a[2 * t + 1] += f2.y;
    }
  }
  float inv = 1.0f / fmaxf((float)(end - beg), 1.0f);
  uint4 w;
  __half2* wp = (__half2*)&w;
  #pragma unroll
  for (int t = 0; t < 4; ++t)
    wp[t] = __float22half2_rn(make_float2(a[2 * t] * inv, a[2 * t + 1] * inv));
  ((uint4*)z)[((size_t)g << 4) + l16] = w;
}

// ====== decode (fp16 z): logits[e] = dot(z[a], z[b]); 16 lanes per edge, uint4/lane ======
__global__ __launch_bounds__(256) void decode16_k(const __half* __restrict__ z,
                                                  const int* __restrict__ pos,
                                                  const int* __restrict__ neg,
                                                  float* __restrict__ out, int ep) {
  int gid = blockIdx.x * blockDim.x + threadIdx.x;
  int edge = gid >> 4, l16 = gid & 15;
  if (edge >= 2 * ep) return;
  int a, b;
  if (edge < ep) { a = pos[edge];      b = pos[ep + edge]; }
  else           { int t = edge - ep; a = neg[t]; b = neg[ep + t]; }
  const uint4* z4 = (const uint4*)z;
  uint4 ua = z4[((size_t)a << 4) + l16];
  uint4 ub = z4[((size_t)b << 4) + l16];
  __half2* ha = (__half2*)&ua;
  __half2* hb = (__half2*)&ub;
  float dot = 0.f;
  #pragma unroll
  for (int t = 0; t < 4; ++t) {
    float2 fa = __half22float2(ha[t]);
    float2 fb = __half22float2(hb[t]);
    dot += fa.x * fb.x + fa.y * fb.y;
  }
  #pragma unroll
  for (int off = 8; off > 0; off >>= 1) dot += __shfl_xor(dot, off);
  if (l16 == 0) out[edge] = dot;
}

// ================= fallback path (small ws): atomic version =================
__global__ void fill_deg_k(float* __restrict__ deg, int n) {
  int i = blockIdx.x * blockDim.x + threadIdx.x;
  if (i < n) deg[i] = 1.0f;
}
__global__ void accum_deg_k(const int* __restrict__ dst, float* __restrict__ deg, int e) {
  int i = blockIdx.x * blockDim.x + threadIdx.x;
  if (i < e) atomicAdd(&deg[dst[i]], 1.0f);
}
__global__ void dinv_k(float* __restrict__ deg, int n) {
  int i = blockIdx.x * blockDim.x + threadIdx.x;
  if (i < n) deg[i] = rsqrtf(deg[i]);
}
__global__ void init_h_k(const float* __restrict__ xw, const float* __restrict__ bias,
                         const float* __restrict__ dinv, float* __restrict__ h, int n) {
  int gid = blockIdx.x * blockDim.x + threadIdx.x;
  int node = gid >> 5, c4 = gid & 31;
  if (node >= n) return;
  float di = dinv[node];
  float nm = di * di;
  float4 v = ((const float4*)(xw + (size_t)node * HH))[c4];
  float4 b = ((const float4*)bias)[c4];
  ((float4*)(h + (size_t)node * HH))[c4] =
      make_float4(b.x + nm * v.x, b.y + nm * v.y, b.z + nm * v.z, b.w + nm * v.w);
}
__global__ void scatter_k(const float* __restrict__ xw, float* __restrict__ h,
                          const float* __restrict__ dinv, const int* __restrict__ src,
                          const int* __restrict__ dst, int e) {
  int gid = blockIdx.x * blockDim.x + threadIdx.x;
  int edge = gid >> 5, lane = gid & 31;
  if (edge >= e) return;
  int s = src[edge], d = dst[edge];
  float norm = dinv[s] * dinv[d];
  float4 v = ((const float4*)(xw + (size_t)s * HH))[lane];
  float* o = h + (size_t)d * HH + lane * 4;
  atomicAdd(o + 0, norm * v.x);
  atomicAdd(o + 1, norm * v.y);
  atomicAdd(o + 2, norm * v.z);
  atomicAdd(o + 3, norm * v.w);
}
__global__ void relu_k(float4* __restrict__ h, int n4) {
  int i = blockIdx.x * blockDim.x + threadIdx.x;
  if (i < n4) {
    float4 v = h[i];
    v.x = fmaxf(v.x, 0.f); v.y = fmaxf(v.y, 0.f);
    v.z = fmaxf(v.z, 0.f); v.w = fmaxf(v.w, 0.f);
    h[i] = v;
  }
}
__global__ void pool_accum_k(const float* __restrict__ h, const int* __restrict__ dict,
                             float* __restrict__ z, float* __restrict__ cnt, int n) {
  int gid = blockIdx.x * blockDim.x + threadIdx.x;
  int node = gid >> 5, lane = gid & 31;
  if (node >= n) return;
  int d = dict[node];
  float4 v = ((const float4*)(h + (size_t)node * HH))[lane];
  float* o = z + (size_t)d * HH + lane * 4;
  atomicAdd(o + 0, v.x); atomicAdd(o + 1, v.y);
  atomicAdd(o + 2, v.z); atomicAdd(o + 3, v.w);
  if (lane == 0) atomicAdd(&cnt[d], 1.0f);
}
__global__ void pool_div_k(float* __restrict__ z, const float* __restrict__ cnt, int n) {
  int gid = blockIdx.x * blockDim.x + threadIdx.x;
  int node = gid >> 5, lane = gid & 31;
  if (node >= n) return;
  float inv = 1.0f / fmaxf(cnt[node], 1.0f);
  float4* p = (float4*)(z + (size_t)node * HH) + lane;
  float4 v = *p;
  v.x *= inv; v.y *= inv; v.z *= inv; v.w *= inv;
  *p = v;
}
__global__ void decode_k(const float* __restrict__ z, const int* __restrict__ pos,
                         const int* __restrict__ neg, float* __restrict__ out, int ep) {
  int gid = blockIdx.x * blockDim.x + threadIdx.x;
  int edge = gid >> 5, lane = gid & 31;
  if (edge >= 2 * ep) return;
  int a, b;
  if (edge < ep) { a = pos[edge];      b = pos[ep + edge]; }
  else           { a = neg[edge - ep]; b = neg[edge]; }
  const float4* za = (const float4*)(z + (size_t)a * HH);
  const float4* zb = (const float4*)(z + (size_t)b * HH);
  float4 va = za[lane], vb = zb[lane];
  float dot = va.x * vb.x + va.y * vb.y + va.z * vb.z + va.w * vb.w;
  #pragma unroll
  for (int off = 16; off > 0; off >>= 1) dot += __shfl_xor(dot, off);
  if (lane == 0) out[edge] = dot;
}

// ================= host launch =================
extern "C" void kernel_launch(void* const* d_in, const int* in_sizes, int n_in,
                              void* d_out, int out_size, void* d_ws, size_t ws_size,
                              hipStream_t stream) {
  const float* x  = (const float*)d_in[0];
  const float* W1 = (const float*)d_in[1];
  const float* b1 = (const float*)d_in[2];
  const float* W2 = (const float*)d_in[3];
  const float* b2 = (const float*)d_in[4];
  const int* ei   = (const int*)d_in[5];
  const int* dict = (const int*)d_in[6];
  const int* pe   = (const int*)d_in[7];
  const int* ne   = (const int*)d_in[8];

  const int n  = in_sizes[0] / HH;   // 100000
  const int e  = in_sizes[5] / 2;    // 1.6M
  const int ep = in_sizes[7] / 2;    // 200000
  const int* src = ei;
  const int* dst = ei + e;

  const size_t nf = (size_t)n * HH;
  const int nbkt  = (n + 255) >> 8;                 // 391
  const int CHE   = 16384, CHN = 2048;
  const int nblkE = (e + CHE - 1) / CHE;            // 98
  const int nblkN = (n + CHN - 1) / CHN;            // 49

  // fast-path ws layout:
  //   bufF  : nf floats   (edge part alias -> h1(fp16, lower) -> h2(fp16, lower)
  //                                           + node part/blkoff (upper half))
  //   xw16  : nf halves   (edge blkoff alias -> xw' -> z(fp16))
  //   dinv[n], rowptr[n+1], tmp[n], esrc[e], bsum[256], gcnt[nbkt], bktbase[nbkt+1]
  float*  p0     = (float*)d_ws;
  float*  bufF   = p0;
  __half* xw16   = (__half*)(p0 + nf);
  float*  dinv   = p0 + nf + nf / 2;
  int*    rowptr = (int*)(dinv + n);
  int*    tmp    = rowptr + (n + 1);
  int*    esrc   = tmp + n;
  int*    bsum   = esrc + e;
  int*    gcnt   = bsum + 256;
  int*    bktbase = gcnt + nbkt;
  size_t need = (nf + nf / 2 + n) * sizeof(float) +
                (size_t)(3 * n + 1 + e + 256 + 2 * nbkt + 1) * sizeof(int);

  int* partE   = (int*)bufF;               // e ints (6.4 MB) <= nf floats
  int* blkoffE = (int*)xw16;               // nbkt*nblkE ints <= nf halves
  int* partN   = (int*)(bufF + nf / 2);    // n ints, upper half of bufF
  int* blkoffN = partN + n;                // nbkt*nblkN ints

  const int nb    = (n + 255) / 256;
  const int nb16  = (int)(((size_t)n * 16 + 255) / 256);
  const int nb32  = (int)(((size_t)n * 32 + 255) / 256);
  const int nb64  = (int)(((size_t)n * 64 + 255) / 256);
  const int gemb  = (n + 63) / 64;
  const int deb16 = (int)(((size_t)2 * ep * 16 + 255) / 256);

  bool fast = (ws_size >= need) && (nbkt <= 512) && (n < (1 << 23)) &&
              ((size_t)e <= nf) && ((size_t)nbkt * nblkE * 2 <= nf) &&
              ((size_t)(n + (size_t)nbkt * nblkN) * 2 <= nf);

  if (fast) {
    // ---- edge CSR (by dst) + dinv: bucketed 2-phase sort (packed records) ----
    hipMemsetAsync(gcnt, 0, (size_t)nbkt * sizeof(int), stream);
    part_count_k<<<nblkE, 256, 0, stream>>>(dst, e, CHE, nbkt, nblkE, gcnt, blkoffE);
    scan_bkt_k<<<1, 512, 0, stream>>>(gcnt, bktbase, nbkt, e);
    part_scatter_k<<<nblkE, 256, 0, stream>>>(src, dst, e, CHE, nbkt, nblkE, bktbase, blkoffE, partE);
    bucket_csr_k<<<nbkt, 256, 0, stream>>>(partE, bktbase, rowptr, dinv, esrc, n, e, nbkt);

    // ---- conv1: xw16 = fp16(dinv * x@W1);  h1 fp16 in lower bufF ----
    gemm128_v5<float, true><<<gemb, 256, 0, stream>>>(x, W1, dinv, xw16, n);
    __half* h1_16 = (__half*)bufF;
    gather16_k<true><<<nb64, 256, 0, stream>>>(xw16, rowptr, esrc, dinv, b1, h1_16, n);
    // ---- conv2: xw16 = fp16(dinv * h1@W2);  h2 fp16 overwrites h1 region ----
    gemm128_v5<__half, true><<<gemb, 256, 0, stream>>>(h1_16, W2, dinv, xw16, n);
    __half* h2_16 = (__half*)bufF;
    gather16_k<true><<<nb64, 256, 0, stream>>>(xw16, rowptr, esrc, dinv, b2, h2_16, n);
    // xw16 dead -> becomes z; upper half of bufF free -> partN

    // ---- node CSR (by dict): bucketed sort (packed records, chunk=2048) ----
    hipMemsetAsync(gcnt, 0, (size_t)nbkt * sizeof(int), stream);
    part_count_k<<<nblkN, 256, 0, stream>>>(dict, n, CHN, nbkt, nblkN, gcnt, blkoffN);
    scan_bkt_k<<<1, 512, 0, stream>>>(gcnt, bktbase, nbkt, n);
    part_scatter_idx_k<<<nblkN, 256, 0, stream>>>(dict, n, CHN, nbkt, nblkN, bktbase, blkoffN, partN);
    bucket_csr_k<<<nbkt, 256, 0, stream>>>(partN, bktbase, rowptr, nullptr, esrc, n, n, nbkt);
    // rowptr = group rowptr, esrc = nodelist

    // ---- pool (fp16 z) then plain dot decode ----
    __half* z16 = xw16;
    pool16_k<<<nb16, 256, 0, stream>>>(h2_16, rowptr, esrc, z16, n);
    decode16_k<<<deb16, 256, 0, stream>>>(z16, pe, ne, (float*)d_out, ep);
  } else {
    // ---- fallback: atomic path (bufA, bufB, dinv2, cnt), all fp32 ----
    float* bufA  = (float*)d_ws;
    float* bufB  = bufA + nf;
    float* dinv2 = bufB + nf;
    float* cnt   = dinv2 + n;
    fill_deg_k<<<nb, 256, 0, stream>>>(dinv2, n);
    accum_deg_k<<<(e + 255) / 256, 256, 0, stream>>>(dst, dinv2, e);
    dinv_k<<<nb, 256, 0, stream>>>(dinv2, n);

    gemm128_v5<float, false><<<gemb, 256, 0, stream>>>(x, W1, nullptr, bufA, n);
    init_h_k<<<nb32, 256, 0, stream>>>(bufA, b1, dinv2, bufB, n);
    scatter_k<<<(int)(((size_t)e * 32 + 255) / 256), 256, 0, stream>>>(bufA, bufB, dinv2, src, dst, e);
    relu_k<<<nb32, 256, 0, stream>>>((float4*)bufB, n * 32);

    gemm128_v5<float, false><<<gemb, 256, 0, stream>>>(bufB, W2, nullptr, bufA, n);
    init_h_k<<<nb32, 256, 0, stream>>>(bufA, b2, dinv2, bufB, n);
    scatter_k<<<(int)(((size_t)e * 32 + 255) / 256), 256, 0, stream>>>(bufA, bufB, dinv2, src, dst, e);
    relu_k<<<nb32, 256, 0, stream>>>((float4*)bufB, n * 32);

    hipMemsetAsync(bufA, 0, nf * sizeof(float), stream);
    hipMemsetAsync(cnt, 0, (size_t)n * sizeof(float), stream);
    pool_accum_k<<<nb32, 256, 0, stream>>>(bufB, dict, bufA, cnt, n);
    pool_div_k<<<nb32, 256, 0, stream>>>(bufA, cnt, n);
    decode_k<<<(int)(((size_t)2 * ep * 32 + 255) / 256), 256, 0, stream>>>(
        bufA, pe, ne, (float*)d_out, ep);
  }
}